// Round 2
// baseline (2518.332 us; speedup 1.0000x reference)
//
#include <hip/hip_runtime.h>

// ---------- types ----------
typedef __bf16 bf16x8 __attribute__((ext_vector_type(8)));
typedef float f32x4 __attribute__((ext_vector_type(4)));

#define EPS 1e-5f

__device__ __forceinline__ unsigned short f2bu(float f) {
  union { float f; unsigned u; } x; x.f = f;
  unsigned r = x.u + 0x7fffu + ((x.u >> 16) & 1u);  // RNE
  return (unsigned short)(r >> 16);
}
__device__ __forceinline__ float bu2f(unsigned short u) {
  union { unsigned u; float f; } x; x.u = ((unsigned)u) << 16;
  return x.f;
}

__device__ __forceinline__ void gld16(const void* g, void* l) {
  __builtin_amdgcn_global_load_lds((const __attribute__((address_space(1))) void*)g,
                                   (__attribute__((address_space(3))) void*)l, 16, 0, 0);
}

// ---------- generic f32 -> bf16 convert ----------
__global__ __launch_bounds__(256) void k_f2b(const float* __restrict__ in,
                                             unsigned short* __restrict__ out, int n) {
  int i = blockIdx.x * 256 + threadIdx.x;
  if (i < n) out[i] = f2bu(in[i]);
}

// ---------- conv weight repack (CO,CI,3,3) f32 -> (CO,9,CI) bf16 ----------
template <int CI>
__global__ __launch_bounds__(256) void k_repack(const float* __restrict__ w,
                                                unsigned short* __restrict__ out, int n) {
  int id = blockIdx.x * 256 + threadIdx.x;
  if (id >= n) return;
  int ci = id % CI;
  int tap = (id / CI) % 9;
  int co = id / (9 * CI);
  out[id] = f2bu(w[(co * CI + ci) * 9 + tap]);
}

// ---------- conv1 pass A: 3x3 s2 p1, NCHW f32 in -> NHWC bf16 (BN+ReLU fused) ----------
__global__ __launch_bounds__(256) void k_conv1a(
    const float* __restrict__ x, const float* __restrict__ w,
    const float* __restrict__ cb, const float* __restrict__ g,
    const float* __restrict__ bb, const float* __restrict__ bm_,
    const float* __restrict__ bv, unsigned short* __restrict__ out) {
  int id = blockIdx.x * 256 + threadIdx.x;  // ((b*112+oy)*112+ox)*64 + c
  int c = id & 63;
  int t = id >> 6;
  int ox = t % 112; t /= 112;
  int oy = t % 112;
  int b = t / 112;
  float alpha = g[c] * rsqrtf(bv[c] + EPS);
  float beta = (cb[c] - bm_[c]) * alpha + bb[c];
  const float* xb = x + (size_t)b * 3 * 224 * 224;
  const float* wc = w + c * 27;
  float acc = 0.f;
#pragma unroll
  for (int ci = 0; ci < 3; ++ci)
#pragma unroll
    for (int ky = 0; ky < 3; ++ky) {
      int iy = oy * 2 - 1 + ky;
      bool vy = (unsigned)iy < 224u;
#pragma unroll
      for (int kx = 0; kx < 3; ++kx) {
        int ix = ox * 2 - 1 + kx;
        float v = (vy && (unsigned)ix < 224u) ? xb[(ci * 224 + iy) * 224 + ix] : 0.f;
        acc = fmaf(v, wc[ci * 9 + ky * 3 + kx], acc);
      }
    }
  out[id] = f2bu(fmaxf(acc * alpha + beta, 0.f));
}

// ---------- conv1 pass B: 3x3 s2 p1 maxpool on NHWC bf16 (values >= 0) ----------
__global__ __launch_bounds__(256) void k_pool3(const unsigned short* __restrict__ in,
                                               unsigned short* __restrict__ out) {
  int id = blockIdx.x * 256 + threadIdx.x;  // ((b*56+py)*56+px)*64 + c
  int c = id & 63;
  int t = id >> 6;
  int px = t % 56; t /= 56;
  int py = t % 56;
  int b = t / 56;
  float m = 0.f;  // inputs are post-ReLU (>= 0)
#pragma unroll
  for (int ky = 0; ky < 3; ++ky) {
    int iy = py * 2 - 1 + ky;
    if ((unsigned)iy >= 112u) continue;
#pragma unroll
    for (int kx = 0; kx < 3; ++kx) {
      int ix = px * 2 - 1 + kx;
      if ((unsigned)ix >= 112u) continue;
      m = fmaxf(m, bu2f(in[(((size_t)(b * 112 + iy) * 112) + ix) * 64 + c]));
    }
  }
  out[id] = f2bu(m);
}

// ---------- implicit-GEMM 3x3 s1 p1 conv, NHWC bf16 in/out, BN+ReLU epilogue ----------
template <int H, int Wd, int CI, int CO>
__global__ __launch_bounds__(256) void k_convgemm(
    const unsigned short* __restrict__ In, const unsigned short* __restrict__ Wt,
    const float* __restrict__ cb, const float* __restrict__ g,
    const float* __restrict__ bb, const float* __restrict__ bm_,
    const float* __restrict__ bv, unsigned short* __restrict__ Out) {
  constexpr int K = 9 * CI;
  constexpr int NTN = CO / 64;
  int bm = blockIdx.x / NTN, bn = blockIdx.x - bm * NTN;
  int lane = threadIdx.x & 63, wid = threadIdx.x >> 6;
  int wr = wid >> 1, wc = wid & 1;
  int r0 = bm * 64 + wr * 32 + (lane & 15);
  int r1 = r0 + 16;
  int c0 = bn * 64 + wc * 32 + (lane & 15);
  int koff = (lane >> 4) << 3;
  int ox0 = r0 % Wd; int t0 = r0 / Wd; int oy0 = t0 % H; int b0 = t0 / H;
  int ox1 = r1 % Wd; int t1 = r1 / Wd; int oy1 = t1 % H; int b1 = t1 / H;
  const unsigned short* pb0 = Wt + (size_t)c0 * K + koff;
  const unsigned short* pb1 = Wt + (size_t)(c0 + 16) * K + koff;
  f32x4 acc[2][2] = {};
  for (int k0 = 0; k0 < K; k0 += 32) {
    int k = k0 + koff;
    int tap = k / CI;
    int ci = k - tap * CI;
    int ky = tap / 3, kx = tap - ky * 3;
    int iy0 = oy0 + ky - 1, ix0 = ox0 + kx - 1;
    int iy1 = oy1 + ky - 1, ix1 = ox1 + kx - 1;
    bf16x8 a0 = {};
    bf16x8 a1 = {};
    if ((unsigned)iy0 < (unsigned)H && (unsigned)ix0 < (unsigned)Wd)
      a0 = *(const bf16x8*)(In + ((size_t)((b0 * H + iy0) * Wd + ix0)) * CI + ci);
    if ((unsigned)iy1 < (unsigned)H && (unsigned)ix1 < (unsigned)Wd)
      a1 = *(const bf16x8*)(In + ((size_t)((b1 * H + iy1) * Wd + ix1)) * CI + ci);
    bf16x8 w0 = *(const bf16x8*)(pb0 + k0);
    bf16x8 w1 = *(const bf16x8*)(pb1 + k0);
    acc[0][0] = __builtin_amdgcn_mfma_f32_16x16x32_bf16(a0, w0, acc[0][0], 0, 0, 0);
    acc[0][1] = __builtin_amdgcn_mfma_f32_16x16x32_bf16(a0, w1, acc[0][1], 0, 0, 0);
    acc[1][0] = __builtin_amdgcn_mfma_f32_16x16x32_bf16(a1, w0, acc[1][0], 0, 0, 0);
    acc[1][1] = __builtin_amdgcn_mfma_f32_16x16x32_bf16(a1, w1, acc[1][1], 0, 0, 0);
  }
  int rr = (lane >> 4) * 4, rc = lane & 15;
#pragma unroll
  for (int tj = 0; tj < 2; ++tj) {
    int col = bn * 64 + wc * 32 + tj * 16 + rc;
    float alpha = g[col] * rsqrtf(bv[col] + EPS);
    float beta = (cb[col] - bm_[col]) * alpha + bb[col];
#pragma unroll
    for (int ti = 0; ti < 2; ++ti) {
      int row = bm * 64 + wr * 32 + ti * 16 + rr;
#pragma unroll
      for (int r = 0; r < 4; ++r) {
        float v = fmaxf(acc[ti][tj][r] * alpha + beta, 0.f);
        Out[(size_t)(row + r) * CO + col] = f2bu(v);
      }
    }
  }
}

// ---------- NHWC 2x2/2 maxpool, bf16 in, bf16 or f32 out ----------
template <int H, int Wd, int C, bool OUTF>
__global__ __launch_bounds__(256) void k_pool(const unsigned short* __restrict__ in,
                                              void* __restrict__ outv) {
  constexpr int OH = H / 2, OW = Wd / 2;
  int id = blockIdx.x * 256 + threadIdx.x;  // 32*OH*OW*C exact
  int c = id % C;
  int t = id / C;
  int px = t % OW; t /= OW;
  int py = t % OH;
  int b = t / OH;
  const unsigned short* p = in + (((size_t)(b * H + py * 2) * Wd) + px * 2) * C + c;
  float m0 = bu2f(p[0]), m1 = bu2f(p[C]);
  float m2 = bu2f(p[(size_t)Wd * C]), m3 = bu2f(p[(size_t)Wd * C + C]);
  float m = fmaxf(fmaxf(m0, m1), fmaxf(m2, m3));
  if (OUTF) ((float*)outv)[id] = m;
  else ((unsigned short*)outv)[id] = f2bu(m);
}

// ---------- LayerNorm over 256, f32 in -> bf16 out ----------
__global__ __launch_bounds__(256) void k_ln(const float* __restrict__ h,
                                            const float* __restrict__ g,
                                            const float* __restrict__ b2,
                                            unsigned short* __restrict__ out) {
  int lane = threadIdx.x & 63, wid = threadIdx.x >> 6;
  int t = blockIdx.x * 4 + wid;
  float4 v = *(const float4*)(h + (size_t)t * 256 + lane * 4);
  float s = v.x + v.y + v.z + v.w;
  float q = v.x * v.x + v.y * v.y + v.z * v.z + v.w * v.w;
#pragma unroll
  for (int off = 32; off; off >>= 1) {
    s += __shfl_xor(s, off);
    q += __shfl_xor(q, off);
  }
  float mu = s * (1.f / 256.f);
  float var = q * (1.f / 256.f) - mu * mu;
  float rs = rsqrtf(var + EPS);
  float4 gg = *(const float4*)(g + lane * 4);
  float4 bb = *(const float4*)(b2 + lane * 4);
  ushort4 o;
  o.x = f2bu((v.x - mu) * rs * gg.x + bb.x);
  o.y = f2bu((v.y - mu) * rs * gg.y + bb.y);
  o.z = f2bu((v.z - mu) * rs * gg.z + bb.z);
  o.w = f2bu((v.w - mu) * rs * gg.w + bb.w);
  *(ushort4*)(out + (size_t)t * 256 + lane * 4) = o;
}

// ---------- LDS-staged bf16 GEMM (m97 structure): C[M,N] = A[M,K] @ W[N,K]^T ----------
// wave grid 2x2; wave computes (BM/2)x(BN/2); BK=64; K = KSTEPS*64 compile-time.
template <int BM, int BN, int KSTEPS, bool ADD>
__global__ __launch_bounds__(256) void k_sgemm(const unsigned short* __restrict__ A,
                                               const unsigned short* __restrict__ W,
                                               float* __restrict__ C,
                                               int N, int ntn) {
  constexpr int K = KSTEPS * 64;
  constexpr int MR = BM / 32;
  constexpr int NR = BN / 32;
  __shared__ __align__(16) unsigned short As[BM * 64];
  __shared__ __align__(16) unsigned short Bs[BN * 64];
  int bm = blockIdx.x / ntn, bn = blockIdx.x - bm * ntn;
  int lane = threadIdx.x & 63, wid = threadIdx.x >> 6;
  int wr = wid >> 1, wc = wid & 1;
  const int arow = lane >> 3, acol = (lane & 7) * 8;
  f32x4 acc[MR][NR] = {};
  const unsigned short* Abase = A + (size_t)(bm * BM) * K;
  const unsigned short* Wbase = W + (size_t)(bn * BN) * K;
  for (int t = 0; t < KSTEPS; ++t) {
    int k0 = t * 64;
#pragma unroll
    for (int i = 0; i < BM / 32; ++i) {
      int chunk = wid * (BM / 32) + i;
      gld16(Abase + (size_t)(chunk * 8 + arow) * K + k0 + acol, &As[chunk * 512 + lane * 8]);
    }
#pragma unroll
    for (int i = 0; i < BN / 32; ++i) {
      int chunk = wid * (BN / 32) + i;
      gld16(Wbase + (size_t)(chunk * 8 + arow) * K + k0 + acol, &Bs[chunk * 512 + lane * 8]);
    }
    __syncthreads();
#pragma unroll
    for (int kk = 0; kk < 2; ++kk) {
      bf16x8 af[MR], bfr[NR];
#pragma unroll
      for (int mi = 0; mi < MR; ++mi)
        af[mi] = *(const bf16x8*)&As[(wr * (BM / 2) + mi * 16 + (lane & 15)) * 64 + kk * 32 + (lane >> 4) * 8];
#pragma unroll
      for (int nj = 0; nj < NR; ++nj)
        bfr[nj] = *(const bf16x8*)&Bs[(wc * (BN / 2) + nj * 16 + (lane & 15)) * 64 + kk * 32 + (lane >> 4) * 8];
#pragma unroll
      for (int mi = 0; mi < MR; ++mi)
#pragma unroll
        for (int nj = 0; nj < NR; ++nj)
          acc[mi][nj] = __builtin_amdgcn_mfma_f32_16x16x32_bf16(af[mi], bfr[nj], acc[mi][nj], 0, 0, 0);
    }
    __syncthreads();
  }
  int rr = (lane >> 4) * 4, rc = lane & 15;
#pragma unroll
  for (int mi = 0; mi < MR; ++mi)
#pragma unroll
    for (int nj = 0; nj < NR; ++nj) {
      int row = bm * BM + wr * (BM / 2) + mi * 16 + rr;
      int col = bn * BN + wc * (BN / 2) + nj * 16 + rc;
#pragma unroll
      for (int r = 0; r < 4; ++r) {
        float v = acc[mi][nj][r];
        if (ADD) v += C[(size_t)(row + r) * N + col];
        C[(size_t)(row + r) * N + col] = v;
      }
    }
}

// ---------- direct bf16 GEMM (small N): C[M,N] = A[M,K] @ W[N,K]^T ----------
template <bool ADD_RES>
__global__ __launch_bounds__(256) void k_gemm(const unsigned short* __restrict__ A,
                                              const unsigned short* __restrict__ W,
                                              float* __restrict__ C, int M, int N,
                                              int K, int ntn) {
  int bm = blockIdx.x / ntn, bn = blockIdx.x - bm * ntn;
  int lane = threadIdx.x & 63, wid = threadIdx.x >> 6;
  int wr = wid >> 1, wc = wid & 1;
  int r0 = bm * 64 + wr * 32 + (lane & 15);
  int c0 = bn * 64 + wc * 32 + (lane & 15);
  int koff = (lane >> 4) << 3;
  int cc0 = (c0 < N) ? c0 : (N - 1);
  int cc1 = (c0 + 16 < N) ? (c0 + 16) : (N - 1);
  const unsigned short* pa0 = A + (size_t)r0 * K + koff;
  const unsigned short* pa1 = A + (size_t)(r0 + 16) * K + koff;
  const unsigned short* pb0 = W + (size_t)cc0 * K + koff;
  const unsigned short* pb1 = W + (size_t)cc1 * K + koff;
  f32x4 acc[2][2] = {};
  for (int k0 = 0; k0 < K; k0 += 32) {
    bf16x8 a0 = *(const bf16x8*)(pa0 + k0);
    bf16x8 a1 = *(const bf16x8*)(pa1 + k0);
    bf16x8 b0 = *(const bf16x8*)(pb0 + k0);
    bf16x8 b1 = *(const bf16x8*)(pb1 + k0);
    acc[0][0] = __builtin_amdgcn_mfma_f32_16x16x32_bf16(a0, b0, acc[0][0], 0, 0, 0);
    acc[0][1] = __builtin_amdgcn_mfma_f32_16x16x32_bf16(a0, b1, acc[0][1], 0, 0, 0);
    acc[1][0] = __builtin_amdgcn_mfma_f32_16x16x32_bf16(a1, b0, acc[1][0], 0, 0, 0);
    acc[1][1] = __builtin_amdgcn_mfma_f32_16x16x32_bf16(a1, b1, acc[1][1], 0, 0, 0);
  }
  int rr = (lane >> 4) * 4, rc = lane & 15;
#pragma unroll
  for (int ti = 0; ti < 2; ++ti)
#pragma unroll
    for (int tj = 0; tj < 2; ++tj) {
      int col = bn * 64 + wc * 32 + tj * 16 + rc;
      if (col >= N) continue;
      int row = bm * 64 + wr * 32 + ti * 16 + rr;
#pragma unroll
      for (int r = 0; r < 4; ++r) {
        float v = acc[ti][tj][r];
        if (ADD_RES) v += C[(size_t)(row + r) * N + col];
        C[(size_t)(row + r) * N + col] = v;
      }
    }
}

// ---------- depthwise causal conv (DC=4) + silu; writes f32 + bf16 ----------
__global__ __launch_bounds__(256) void k_dwconv(const float* __restrict__ xz,
                                                const float* __restrict__ cw,
                                                const float* __restrict__ cb,
                                                float* __restrict__ xc,
                                                unsigned short* __restrict__ xcb) {
  int id = blockIdx.x * 256 + threadIdx.x;  // 6272*512
  int d = id & 511;
  int bl = id >> 9;
  int l = bl % 196;
  int b = bl / 196;
  const float* xi = xz + (size_t)(b * 196) * 1024 + d;
  float4 c4 = *(const float4*)(cw + d * 4);
  float acc = cb[d];
  if (l >= 3) acc = fmaf(xi[(size_t)(l - 3) * 1024], c4.x, acc);
  if (l >= 2) acc = fmaf(xi[(size_t)(l - 2) * 1024], c4.y, acc);
  if (l >= 1) acc = fmaf(xi[(size_t)(l - 1) * 1024], c4.z, acc);
  acc = fmaf(xi[(size_t)l * 1024], c4.w, acc);
  float s = acc / (1.f + __expf(-acc));
  xc[id] = s;
  xcb[id] = f2bu(s);
}

// ---------- dt = softplus(dbl[:, :16] @ w_dt^T + b_dt) ----------
__global__ __launch_bounds__(256) void k_dt(const float* __restrict__ dbl,
                                            const float* __restrict__ wdt,
                                            const float* __restrict__ bdt,
                                            float* __restrict__ dt) {
  int id = blockIdx.x * 256 + threadIdx.x;  // 6272*512
  int d = id & 511;
  int bl = id >> 9;
  const float4* a = (const float4*)(dbl + (size_t)bl * 144);
  const float4* w = (const float4*)(wdt + d * 16);
  float acc = bdt[d];
#pragma unroll
  for (int i = 0; i < 4; ++i) {
    float4 av = a[i], wv = w[i];
    acc += av.x * wv.x + av.y * wv.y + av.z * wv.z + av.w * wv.w;
  }
  dt[id] = fmaxf(acc, 0.f) + log1pf(__expf(-fabsf(acc)));
}

// ---------- selective scan: wave per (b,d), lane = state s ----------
__global__ __launch_bounds__(256) void k_scan(
    const float* __restrict__ dtb, const float* __restrict__ xc,
    const float* __restrict__ dbl, const float* __restrict__ xz,
    const float* __restrict__ a_log, const float* __restrict__ d_skip,
    unsigned short* __restrict__ y) {
  __shared__ float lds[4][584];
  int lane = threadIdx.x & 63, wid = threadIdx.x >> 6;
  int wgid = blockIdx.x * 4 + wid;  // 0..16383
  int b = wgid >> 9, d = wgid & 511;
  float A = -__expf(a_log[d * 64 + lane]);
  float dsk = d_skip[d];
  const float* dt_p = dtb + (size_t)(b * 196) * 512 + d;
  const float* xc_p = xc + (size_t)(b * 196) * 512 + d;
  const float* z_p = xz + (size_t)(b * 196) * 1024 + 512 + d;
  const float* bc_p = dbl + (size_t)(b * 196) * 144 + 16 + lane;
  unsigned short* y_p = y + (size_t)(b * 196) * 512 + d;
  float* L = lds[wid];
  float h = 0.f;
  int g = lane >> 3, j = lane & 7;
  for (int l0 = 0; l0 < 196; l0 += 8) {
    float p[8];
#pragma unroll
    for (int li = 0; li < 8; ++li) {
      int l = l0 + li;
      bool ok = (l < 196);
      float dtv = ok ? dt_p[(size_t)l * 512] : 0.f;
      float xv = ok ? xc_p[(size_t)l * 512] : 0.f;
      float Bv = ok ? bc_p[(size_t)l * 144] : 0.f;
      float Cv = ok ? bc_p[(size_t)l * 144 + 64] : 0.f;
      float dA = __expf(dtv * A);
      h = fmaf(dA, h, (dtv * xv) * Bv);
      p[li] = h * Cv;
    }
#pragma unroll
    for (int li = 0; li < 8; ++li) L[lane * 9 + li] = p[li];
    __builtin_amdgcn_wave_barrier();
    float s = 0.f;
#pragma unroll
    for (int k = 0; k < 8; ++k) s += L[(j * 8 + k) * 9 + g];
    __builtin_amdgcn_wave_barrier();
    s += __shfl_xor(s, 1);
    s += __shfl_xor(s, 2);
    s += __shfl_xor(s, 4);
    int l = l0 + g;
    if (j == 0 && l < 196) {
      float xv = xc_p[(size_t)l * 512];
      float zv = z_p[(size_t)l * 1024];
      float sig = 1.f / (1.f + __expf(-zv));
      y_p[(size_t)l * 512] = f2bu((s + dsk * xv) * (zv * sig));
    }
  }
}

// ---------- head ----------
__global__ __launch_bounds__(256) void k_mean(const float* __restrict__ h,
                                              float* __restrict__ pooled) {
  int b = blockIdx.x, e = threadIdx.x;
  float s = 0.f;
  for (int l = 0; l < 196; ++l) s += h[(size_t)(b * 196 + l) * 256 + e];
  pooled[b * 256 + e] = s * (1.f / 196.f);
}

__global__ __launch_bounds__(320) void k_fc(const float* __restrict__ pooled,
                                            const float* __restrict__ fw,
                                            const float* __restrict__ fb,
                                            float* __restrict__ out) {
  int t = threadIdx.x;
  if (t >= 320) return;
  int b = t / 10, n = t - b * 10;
  float s = fb[n];
  for (int e = 0; e < 256; ++e) s += pooled[b * 256 + e] * fw[n * 256 + e];
  out[t] = s;
}

// ---------- launcher ----------
static inline unsigned cdiv(unsigned a, unsigned b) { return (a + b - 1) / b; }

extern "C" void kernel_launch(void* const* d_in, const int* in_sizes, int n_in,
                              void* d_out, int out_size, void* d_ws, size_t ws_size,
                              hipStream_t stream) {
  const float* x = (const float*)d_in[0];
  const float* c1w = (const float*)d_in[1]; const float* c1b = (const float*)d_in[2];
  const float* b1g = (const float*)d_in[3]; const float* b1b = (const float*)d_in[4];
  const float* b1m = (const float*)d_in[5]; const float* b1v = (const float*)d_in[6];
  const float* c2w = (const float*)d_in[7]; const float* c2b = (const float*)d_in[8];
  const float* b2g = (const float*)d_in[9]; const float* b2b = (const float*)d_in[10];
  const float* b2m = (const float*)d_in[11]; const float* b2v = (const float*)d_in[12];
  const float* c3w = (const float*)d_in[13]; const float* c3b = (const float*)d_in[14];
  const float* b3g = (const float*)d_in[15]; const float* b3b = (const float*)d_in[16];
  const float* b3m = (const float*)d_in[17]; const float* b3v = (const float*)d_in[18];
  const float* ln_g = (const float*)d_in[19]; const float* ln_b = (const float*)d_in[20];
  const float* w_in = (const float*)d_in[21];
  const float* cw = (const float*)d_in[22]; const float* cbv = (const float*)d_in[23];
  const float* w_x = (const float*)d_in[24];
  const float* w_dt = (const float*)d_in[25]; const float* b_dt = (const float*)d_in[26];
  const float* a_log = (const float*)d_in[27]; const float* d_skip = (const float*)d_in[28];
  const float* w_out = (const float*)d_in[29];
  const float* fc_w = (const float*)d_in[30]; const float* fc_b = (const float*)d_in[31];

  char* ws = (char*)d_ws;
  size_t off = 0;
  auto take = [&](size_t bytes) { size_t o = off; off += bytes; return o; };
  // scratch region S: stem buffers (phase 1) union mamba buffers (phase 2)
  size_t S = take(67837952);
  // stem phase 1: conv1a output + pooled t1
  unsigned short* c1o = (unsigned short*)(ws + S + 0);          // 51.38 MB
  unsigned short* t1 = (unsigned short*)(ws + S + 51380224);    // 12.85 MB
  // stem phase 2 (c1o dead once t1 is written)
  unsigned short* t2 = (unsigned short*)(ws + S + 0);           // 25.69 MB
  unsigned short* t3 = (unsigned short*)(ws + S + 25690112);    // 6.42 MB
  unsigned short* t4 = (unsigned short*)(ws + S + 32112640);    // 12.85 MB
  // mamba phase (stem buffers dead)
  float* xz = (float*)(ws + S + 0);
  float* xc = (float*)(ws + S + 25690112);
  unsigned short* xcb = (unsigned short*)(ws + S + 38535168);
  float* dbl = (float*)(ws + S + 44957696);
  float* dtb = (float*)(ws + S + 48570368);
  unsigned short* ybf = (unsigned short*)(ws + S + 61415424);
  float* h = (float*)(ws + take(6422528));
  unsigned short* hbf = (unsigned short*)(ws + take(3211264));
  unsigned short* w_in_bf = (unsigned short*)(ws + take(3145728));
  unsigned short* w_x_bf = (unsigned short*)(ws + take(884736));
  unsigned short* w_out_bf = (unsigned short*)(ws + take(1572864));
  unsigned short* w2p = (unsigned short*)(ws + take(147456));
  unsigned short* w3p = (unsigned short*)(ws + take(589824));
  float* pooled = (float*)(ws + take(32768));
  (void)ws_size; (void)in_sizes; (void)n_in; (void)out_size;

  // weight conversion / repack
  k_f2b<<<cdiv(1572864, 256), 256, 0, stream>>>(w_in, w_in_bf, 1572864);
  k_f2b<<<cdiv(442368, 256), 256, 0, stream>>>(w_x, w_x_bf, 442368);
  k_f2b<<<cdiv(786432, 256), 256, 0, stream>>>(w_out, w_out_bf, 786432);
  k_repack<64><<<cdiv(73728, 256), 256, 0, stream>>>(c2w, w2p, 73728);
  k_repack<128><<<cdiv(294912, 256), 256, 0, stream>>>(c3w, w3p, 294912);

  // stem
  k_conv1a<<<100352, 256, 0, stream>>>(x, c1w, c1b, b1g, b1b, b1m, b1v, c1o);
  k_pool3<<<25088, 256, 0, stream>>>(c1o, t1);
  k_convgemm<56, 56, 64, 128><<<1568 * 2, 256, 0, stream>>>(t1, w2p, c2b, b2g, b2b, b2m, b2v, t2);
  k_pool<56, 56, 128, false><<<12544, 256, 0, stream>>>(t2, t3);
  k_convgemm<28, 28, 128, 256><<<392 * 4, 256, 0, stream>>>(t3, w3p, c3b, b3g, b3b, b3m, b3v, t4);
  k_pool<28, 28, 256, true><<<6272, 256, 0, stream>>>(t4, h);

  // mamba blocks
  for (int blk = 0; blk < 6; ++blk) {
    k_ln<<<1568, 256, 0, stream>>>(h, ln_g + blk * 256, ln_b + blk * 256, hbf);
    k_sgemm<128, 128, 4, false><<<49 * 8, 256, 0, stream>>>(
        hbf, w_in_bf + (size_t)blk * 1024 * 256, xz, 1024, 8);
    k_dwconv<<<12544, 256, 0, stream>>>(xz, cw + blk * 512 * 4, cbv + blk * 512, xc, xcb);
    k_gemm<false><<<98 * 3, 256, 0, stream>>>(xcb, w_x_bf + (size_t)blk * 144 * 512, dbl,
                                              6272, 144, 512, 3);
    k_dt<<<12544, 256, 0, stream>>>(dbl, w_dt + blk * 512 * 16, b_dt + blk * 512, dtb);
    k_scan<<<4096, 256, 0, stream>>>(dtb, xc, dbl, xz, a_log + blk * 512 * 64,
                                     d_skip + blk * 512, ybf);
    k_sgemm<64, 64, 8, true><<<98 * 4, 256, 0, stream>>>(
        ybf, w_out_bf + (size_t)blk * 256 * 512, h, 256, 4);
  }

  // head
  k_mean<<<32, 256, 0, stream>>>(h, pooled);
  k_fc<<<1, 320, 0, stream>>>(pooled, fc_w, fc_b, (float*)d_out);
}

// Round 4
// 1939.392 us; speedup vs baseline: 1.2985x; 1.2985x over previous
//
#include <hip/hip_runtime.h>

// ---------- types ----------
typedef __bf16 bf16x8 __attribute__((ext_vector_type(8)));
typedef float f32x4 __attribute__((ext_vector_type(4)));

#define EPS 1e-5f

__device__ __forceinline__ unsigned short f2bu(float f) {
  union { float f; unsigned u; } x; x.f = f;
  unsigned r = x.u + 0x7fffu + ((x.u >> 16) & 1u);  // RNE
  return (unsigned short)(r >> 16);
}
__device__ __forceinline__ float bu2f(unsigned short u) {
  union { unsigned u; float f; } x; x.u = ((unsigned)u) << 16;
  return x.f;
}

__device__ __forceinline__ void gld16(const void* g, void* l) {
  __builtin_amdgcn_global_load_lds((const __attribute__((address_space(1))) void*)g,
                                   (__attribute__((address_space(3))) void*)l, 16, 0, 0);
}

// ---------- generic f32 -> bf16 convert ----------
__global__ __launch_bounds__(256) void k_f2b(const float* __restrict__ in,
                                             unsigned short* __restrict__ out, int n) {
  int i = blockIdx.x * 256 + threadIdx.x;
  if (i < n) out[i] = f2bu(in[i]);
}

// ---------- conv weight repack (CO,CI,3,3) f32 -> (CO,9,CI) bf16 ----------
template <int CI>
__global__ __launch_bounds__(256) void k_repack(const float* __restrict__ w,
                                                unsigned short* __restrict__ out, int n) {
  int id = blockIdx.x * 256 + threadIdx.x;
  if (id >= n) return;
  int ci = id % CI;
  int tap = (id / CI) % 9;
  int co = id / (9 * CI);
  out[id] = f2bu(w[(co * CI + ci) * 9 + tap]);
}

// ---------- w_dt transpose: (NB,512,16) -> (NB,16,512) f32 ----------
__global__ __launch_bounds__(256) void k_wdt_t(const float* __restrict__ in,
                                               float* __restrict__ out) {
  int id = blockIdx.x * 256 + threadIdx.x;  // 6*16*512
  int d = id & 511;
  int r = (id >> 9) & 15;
  int blk = id >> 13;
  out[id] = in[(blk * 512 + d) * 16 + r];
}

// ---------- conv1 pass A: 3x3 s2 p1, NCHW f32 in -> NHWC bf16 (BN+ReLU fused) ----------
// weights + BN alpha/beta staged in LDS (odd stride 27 -> conflict-free reads)
__global__ __launch_bounds__(256) void k_conv1a(
    const float* __restrict__ x, const float* __restrict__ w,
    const float* __restrict__ cb, const float* __restrict__ g,
    const float* __restrict__ bb, const float* __restrict__ bm_,
    const float* __restrict__ bv, unsigned short* __restrict__ out) {
  __shared__ float sw[64 * 27];
  __shared__ float sa[64], sb[64];
  for (int i = threadIdx.x; i < 64 * 27; i += 256) sw[i] = w[i];
  if (threadIdx.x < 64) {
    int c = threadIdx.x;
    float alpha = g[c] * rsqrtf(bv[c] + EPS);
    sa[c] = alpha;
    sb[c] = (cb[c] - bm_[c]) * alpha + bb[c];
  }
  __syncthreads();
  int id = blockIdx.x * 256 + threadIdx.x;  // ((b*112+oy)*112+ox)*64 + c
  int c = id & 63;
  int t = id >> 6;
  int ox = t % 112; t /= 112;
  int oy = t % 112;
  int b = t / 112;
  const float* xb = x + (size_t)b * 3 * 224 * 224;
  const float* wc = sw + c * 27;
  float acc = 0.f;
#pragma unroll
  for (int ci = 0; ci < 3; ++ci)
#pragma unroll
    for (int ky = 0; ky < 3; ++ky) {
      int iy = oy * 2 - 1 + ky;
      bool vy = (unsigned)iy < 224u;
#pragma unroll
      for (int kx = 0; kx < 3; ++kx) {
        int ix = ox * 2 - 1 + kx;
        float v = (vy && (unsigned)ix < 224u) ? xb[(ci * 224 + iy) * 224 + ix] : 0.f;
        acc = fmaf(v, wc[ci * 9 + ky * 3 + kx], acc);
      }
    }
  out[id] = f2bu(fmaxf(acc * sa[c] + sb[c], 0.f));
}

// ---------- conv1 pass B: 3x3 s2 p1 maxpool on NHWC bf16 (values >= 0) ----------
__global__ __launch_bounds__(256) void k_pool3(const unsigned short* __restrict__ in,
                                               unsigned short* __restrict__ out) {
  int id = blockIdx.x * 256 + threadIdx.x;  // ((b*56+py)*56+px)*64 + c
  int c = id & 63;
  int t = id >> 6;
  int px = t % 56; t /= 56;
  int py = t % 56;
  int b = t / 56;
  float m = 0.f;  // inputs are post-ReLU (>= 0)
#pragma unroll
  for (int ky = 0; ky < 3; ++ky) {
    int iy = py * 2 - 1 + ky;
    if ((unsigned)iy >= 112u) continue;
#pragma unroll
    for (int kx = 0; kx < 3; ++kx) {
      int ix = px * 2 - 1 + kx;
      if ((unsigned)ix >= 112u) continue;
      m = fmaxf(m, bu2f(in[(((size_t)(b * 112 + iy) * 112) + ix) * 64 + c]));
    }
  }
  out[id] = f2bu(m);
}

// ---------- implicit-GEMM 3x3 s1 p1 conv, NHWC bf16 in/out, BN+ReLU epilogue ----------
template <int H, int Wd, int CI, int CO>
__global__ __launch_bounds__(256) void k_convgemm(
    const unsigned short* __restrict__ In, const unsigned short* __restrict__ Wt,
    const float* __restrict__ cb, const float* __restrict__ g,
    const float* __restrict__ bb, const float* __restrict__ bm_,
    const float* __restrict__ bv, unsigned short* __restrict__ Out) {
  constexpr int K = 9 * CI;
  constexpr int NTN = CO / 64;
  int bm = blockIdx.x / NTN, bn = blockIdx.x - bm * NTN;
  int lane = threadIdx.x & 63, wid = threadIdx.x >> 6;
  int wr = wid >> 1, wc = wid & 1;
  int r0 = bm * 64 + wr * 32 + (lane & 15);
  int r1 = r0 + 16;
  int c0 = bn * 64 + wc * 32 + (lane & 15);
  int koff = (lane >> 4) << 3;
  int ox0 = r0 % Wd; int t0 = r0 / Wd; int oy0 = t0 % H; int b0 = t0 / H;
  int ox1 = r1 % Wd; int t1 = r1 / Wd; int oy1 = t1 % H; int b1 = t1 / H;
  const unsigned short* pb0 = Wt + (size_t)c0 * K + koff;
  const unsigned short* pb1 = Wt + (size_t)(c0 + 16) * K + koff;
  f32x4 acc[2][2] = {};
  for (int k0 = 0; k0 < K; k0 += 32) {
    int k = k0 + koff;
    int tap = k / CI;
    int ci = k - tap * CI;
    int ky = tap / 3, kx = tap - ky * 3;
    int iy0 = oy0 + ky - 1, ix0 = ox0 + kx - 1;
    int iy1 = oy1 + ky - 1, ix1 = ox1 + kx - 1;
    bf16x8 a0 = {};
    bf16x8 a1 = {};
    if ((unsigned)iy0 < (unsigned)H && (unsigned)ix0 < (unsigned)Wd)
      a0 = *(const bf16x8*)(In + ((size_t)((b0 * H + iy0) * Wd + ix0)) * CI + ci);
    if ((unsigned)iy1 < (unsigned)H && (unsigned)ix1 < (unsigned)Wd)
      a1 = *(const bf16x8*)(In + ((size_t)((b1 * H + iy1) * Wd + ix1)) * CI + ci);
    bf16x8 w0 = *(const bf16x8*)(pb0 + k0);
    bf16x8 w1 = *(const bf16x8*)(pb1 + k0);
    acc[0][0] = __builtin_amdgcn_mfma_f32_16x16x32_bf16(a0, w0, acc[0][0], 0, 0, 0);
    acc[0][1] = __builtin_amdgcn_mfma_f32_16x16x32_bf16(a0, w1, acc[0][1], 0, 0, 0);
    acc[1][0] = __builtin_amdgcn_mfma_f32_16x16x32_bf16(a1, w0, acc[1][0], 0, 0, 0);
    acc[1][1] = __builtin_amdgcn_mfma_f32_16x16x32_bf16(a1, w1, acc[1][1], 0, 0, 0);
  }
  int rr = (lane >> 4) * 4, rc = lane & 15;
#pragma unroll
  for (int tj = 0; tj < 2; ++tj) {
    int col = bn * 64 + wc * 32 + tj * 16 + rc;
    float alpha = g[col] * rsqrtf(bv[col] + EPS);
    float beta = (cb[col] - bm_[col]) * alpha + bb[col];
#pragma unroll
    for (int ti = 0; ti < 2; ++ti) {
      int row = bm * 64 + wr * 32 + ti * 16 + rr;
#pragma unroll
      for (int r = 0; r < 4; ++r) {
        float v = fmaxf(acc[ti][tj][r] * alpha + beta, 0.f);
        Out[(size_t)(row + r) * CO + col] = f2bu(v);
      }
    }
  }
}

// ---------- NHWC 2x2/2 maxpool, bf16 in, bf16 or f32 out ----------
template <int H, int Wd, int C, bool OUTF>
__global__ __launch_bounds__(256) void k_pool(const unsigned short* __restrict__ in,
                                              void* __restrict__ outv) {
  constexpr int OH = H / 2, OW = Wd / 2;
  int id = blockIdx.x * 256 + threadIdx.x;  // 32*OH*OW*C exact
  int c = id % C;
  int t = id / C;
  int px = t % OW; t /= OW;
  int py = t % OH;
  int b = t / OH;
  const unsigned short* p = in + (((size_t)(b * H + py * 2) * Wd) + px * 2) * C + c;
  float m0 = bu2f(p[0]), m1 = bu2f(p[C]);
  float m2 = bu2f(p[(size_t)Wd * C]), m3 = bu2f(p[(size_t)Wd * C + C]);
  float m = fmaxf(fmaxf(m0, m1), fmaxf(m2, m3));
  if (OUTF) ((float*)outv)[id] = m;
  else ((unsigned short*)outv)[id] = f2bu(m);
}

// ---------- LayerNorm over 256, f32 in -> bf16 out ----------
__global__ __launch_bounds__(256) void k_ln(const float* __restrict__ h,
                                            const float* __restrict__ g,
                                            const float* __restrict__ b2,
                                            unsigned short* __restrict__ out) {
  int lane = threadIdx.x & 63, wid = threadIdx.x >> 6;
  int t = blockIdx.x * 4 + wid;
  float4 v = *(const float4*)(h + (size_t)t * 256 + lane * 4);
  float s = v.x + v.y + v.z + v.w;
  float q = v.x * v.x + v.y * v.y + v.z * v.z + v.w * v.w;
#pragma unroll
  for (int off = 32; off; off >>= 1) {
    s += __shfl_xor(s, off);
    q += __shfl_xor(q, off);
  }
  float mu = s * (1.f / 256.f);
  float var = q * (1.f / 256.f) - mu * mu;
  float rs = rsqrtf(var + EPS);
  float4 gg = *(const float4*)(g + lane * 4);
  float4 bb = *(const float4*)(b2 + lane * 4);
  ushort4 o;
  o.x = f2bu((v.x - mu) * rs * gg.x + bb.x);
  o.y = f2bu((v.y - mu) * rs * gg.y + bb.y);
  o.z = f2bu((v.z - mu) * rs * gg.z + bb.z);
  o.w = f2bu((v.w - mu) * rs * gg.w + bb.w);
  *(ushort4*)(out + (size_t)t * 256 + lane * 4) = o;
}

// ---------- LDS-staged bf16 GEMM (m97 structure): C[M,N] = A[M,K] @ W[N,K]^T ----------
template <int BM, int BN, int KSTEPS, bool ADD>
__global__ __launch_bounds__(256) void k_sgemm(const unsigned short* __restrict__ A,
                                               const unsigned short* __restrict__ W,
                                               float* __restrict__ C,
                                               int N, int ntn) {
  constexpr int K = KSTEPS * 64;
  constexpr int MR = BM / 32;
  constexpr int NR = BN / 32;
  __shared__ __align__(16) unsigned short As[BM * 64];
  __shared__ __align__(16) unsigned short Bs[BN * 64];
  int bm = blockIdx.x / ntn, bn = blockIdx.x - bm * ntn;
  int lane = threadIdx.x & 63, wid = threadIdx.x >> 6;
  int wr = wid >> 1, wc = wid & 1;
  const int arow = lane >> 3, acol = (lane & 7) * 8;
  f32x4 acc[MR][NR] = {};
  const unsigned short* Abase = A + (size_t)(bm * BM) * K;
  const unsigned short* Wbase = W + (size_t)(bn * BN) * K;
  for (int t = 0; t < KSTEPS; ++t) {
    int k0 = t * 64;
#pragma unroll
    for (int i = 0; i < BM / 32; ++i) {
      int chunk = wid * (BM / 32) + i;
      gld16(Abase + (size_t)(chunk * 8 + arow) * K + k0 + acol, &As[chunk * 512 + lane * 8]);
    }
#pragma unroll
    for (int i = 0; i < BN / 32; ++i) {
      int chunk = wid * (BN / 32) + i;
      gld16(Wbase + (size_t)(chunk * 8 + arow) * K + k0 + acol, &Bs[chunk * 512 + lane * 8]);
    }
    __syncthreads();
#pragma unroll
    for (int kk = 0; kk < 2; ++kk) {
      bf16x8 af[MR], bfr[NR];
#pragma unroll
      for (int mi = 0; mi < MR; ++mi)
        af[mi] = *(const bf16x8*)&As[(wr * (BM / 2) + mi * 16 + (lane & 15)) * 64 + kk * 32 + (lane >> 4) * 8];
#pragma unroll
      for (int nj = 0; nj < NR; ++nj)
        bfr[nj] = *(const bf16x8*)&Bs[(wc * (BN / 2) + nj * 16 + (lane & 15)) * 64 + kk * 32 + (lane >> 4) * 8];
#pragma unroll
      for (int mi = 0; mi < MR; ++mi)
#pragma unroll
        for (int nj = 0; nj < NR; ++nj)
          acc[mi][nj] = __builtin_amdgcn_mfma_f32_16x16x32_bf16(af[mi], bfr[nj], acc[mi][nj], 0, 0, 0);
    }
    __syncthreads();
  }
  int rr = (lane >> 4) * 4, rc = lane & 15;
#pragma unroll
  for (int mi = 0; mi < MR; ++mi)
#pragma unroll
    for (int nj = 0; nj < NR; ++nj) {
      int row = bm * BM + wr * (BM / 2) + mi * 16 + rr;
      int col = bn * BN + wc * (BN / 2) + nj * 16 + rc;
#pragma unroll
      for (int r = 0; r < 4; ++r) {
        float v = acc[mi][nj][r];
        if (ADD) v += C[(size_t)(row + r) * N + col];
        C[(size_t)(row + r) * N + col] = v;
      }
    }
}

// ---------- direct bf16 GEMM (small N): C[M,N] = A[M,K] @ W[N,K]^T ----------
template <bool ADD_RES>
__global__ __launch_bounds__(256) void k_gemm(const unsigned short* __restrict__ A,
                                              const unsigned short* __restrict__ W,
                                              float* __restrict__ C, int M, int N,
                                              int K, int ntn) {
  int bm = blockIdx.x / ntn, bn = blockIdx.x - bm * ntn;
  int lane = threadIdx.x & 63, wid = threadIdx.x >> 6;
  int wr = wid >> 1, wc = wid & 1;
  int r0 = bm * 64 + wr * 32 + (lane & 15);
  int c0 = bn * 64 + wc * 32 + (lane & 15);
  int koff = (lane >> 4) << 3;
  int cc0 = (c0 < N) ? c0 : (N - 1);
  int cc1 = (c0 + 16 < N) ? (c0 + 16) : (N - 1);
  const unsigned short* pa0 = A + (size_t)r0 * K + koff;
  const unsigned short* pa1 = A + (size_t)(r0 + 16) * K + koff;
  const unsigned short* pb0 = W + (size_t)cc0 * K + koff;
  const unsigned short* pb1 = W + (size_t)cc1 * K + koff;
  f32x4 acc[2][2] = {};
  for (int k0 = 0; k0 < K; k0 += 32) {
    bf16x8 a0 = *(const bf16x8*)(pa0 + k0);
    bf16x8 a1 = *(const bf16x8*)(pa1 + k0);
    bf16x8 b0 = *(const bf16x8*)(pb0 + k0);
    bf16x8 b1 = *(const bf16x8*)(pb1 + k0);
    acc[0][0] = __builtin_amdgcn_mfma_f32_16x16x32_bf16(a0, b0, acc[0][0], 0, 0, 0);
    acc[0][1] = __builtin_amdgcn_mfma_f32_16x16x32_bf16(a0, b1, acc[0][1], 0, 0, 0);
    acc[1][0] = __builtin_amdgcn_mfma_f32_16x16x32_bf16(a1, b0, acc[1][0], 0, 0, 0);
    acc[1][1] = __builtin_amdgcn_mfma_f32_16x16x32_bf16(a1, b1, acc[1][1], 0, 0, 0);
  }
  int rr = (lane >> 4) * 4, rc = lane & 15;
#pragma unroll
  for (int ti = 0; ti < 2; ++ti)
#pragma unroll
    for (int tj = 0; tj < 2; ++tj) {
      int col = bn * 64 + wc * 32 + tj * 16 + rc;
      if (col >= N) continue;
      int row = bm * 64 + wr * 32 + ti * 16 + rr;
#pragma unroll
      for (int r = 0; r < 4; ++r) {
        float v = acc[ti][tj][r];
        if (ADD_RES) v += C[(size_t)(row + r) * N + col];
        C[(size_t)(row + r) * N + col] = v;
      }
    }
}

// ---------- depthwise causal conv (DC=4) + silu; writes f32 + bf16 ----------
__global__ __launch_bounds__(256) void k_dwconv(const float* __restrict__ xz,
                                                const float* __restrict__ cw,
                                                const float* __restrict__ cb,
                                                float* __restrict__ xc,
                                                unsigned short* __restrict__ xcb) {
  int id = blockIdx.x * 256 + threadIdx.x;  // 6272*512
  int d = id & 511;
  int bl = id >> 9;
  int l = bl % 196;
  int b = bl / 196;
  const float* xi = xz + (size_t)(b * 196) * 1024 + d;
  float4 c4 = *(const float4*)(cw + d * 4);
  float acc = cb[d];
  if (l >= 3) acc = fmaf(xi[(size_t)(l - 3) * 1024], c4.x, acc);
  if (l >= 2) acc = fmaf(xi[(size_t)(l - 2) * 1024], c4.y, acc);
  if (l >= 1) acc = fmaf(xi[(size_t)(l - 1) * 1024], c4.z, acc);
  acc = fmaf(xi[(size_t)l * 1024], c4.w, acc);
  float s = acc / (1.f + __expf(-acc));
  xc[id] = s;
  xcb[id] = f2bu(s);
}

// ---------- dt = softplus(dbl[:, :16] @ w_dt^T + b_dt), transposed weights ----------
__global__ __launch_bounds__(256) void k_dt(const float* __restrict__ dbl,
                                            const float* __restrict__ wt,
                                            const float* __restrict__ bdt,
                                            float* __restrict__ dt) {
  int id = blockIdx.x * 256 + threadIdx.x;  // 6272*512
  int d = id & 511;
  int bl = id >> 9;
  const float4* a = (const float4*)(dbl + (size_t)bl * 144);
  float acc = bdt[d];
#pragma unroll
  for (int i = 0; i < 4; ++i) {
    float4 av = a[i];
    acc = fmaf(av.x, wt[(i * 4 + 0) * 512 + d], acc);
    acc = fmaf(av.y, wt[(i * 4 + 1) * 512 + d], acc);
    acc = fmaf(av.z, wt[(i * 4 + 2) * 512 + d], acc);
    acc = fmaf(av.w, wt[(i * 4 + 3) * 512 + d], acc);
  }
  dt[id] = fmaxf(acc, 0.f) + log1pf(__expf(-fabsf(acc)));
}

// ---------- selective scan: wave per (b,d), lane = state s ----------
__global__ __launch_bounds__(256) void k_scan(
    const float* __restrict__ dtb, const float* __restrict__ xc,
    const float* __restrict__ dbl, const float* __restrict__ xz,
    const float* __restrict__ a_log, const float* __restrict__ d_skip,
    unsigned short* __restrict__ y) {
  __shared__ float lds[4][584];
  int lane = threadIdx.x & 63, wid = threadIdx.x >> 6;
  int wgid = blockIdx.x * 4 + wid;  // 0..16383
  int b = wgid >> 9, d = wgid & 511;
  float A = -__expf(a_log[d * 64 + lane]);
  float dsk = d_skip[d];
  const float* dt_p = dtb + (size_t)(b * 196) * 512 + d;
  const float* xc_p = xc + (size_t)(b * 196) * 512 + d;
  const float* z_p = xz + (size_t)(b * 196) * 1024 + 512 + d;
  const float* bc_p = dbl + (size_t)(b * 196) * 144 + 16 + lane;
  unsigned short* y_p = y + (size_t)(b * 196) * 512 + d;
  float* L = lds[wid];
  float h = 0.f;
  int g = lane >> 3, j = lane & 7;
  for (int l0 = 0; l0 < 196; l0 += 8) {
    float p[8];
#pragma unroll
    for (int li = 0; li < 8; ++li) {
      int l = l0 + li;
      bool ok = (l < 196);
      float dtv = ok ? dt_p[(size_t)l * 512] : 0.f;
      float xv = ok ? xc_p[(size_t)l * 512] : 0.f;
      float Bv = ok ? bc_p[(size_t)l * 144] : 0.f;
      float Cv = ok ? bc_p[(size_t)l * 144 + 64] : 0.f;
      float dA = __expf(dtv * A);
      h = fmaf(dA, h, (dtv * xv) * Bv);
      p[li] = h * Cv;
    }
#pragma unroll
    for (int li = 0; li < 8; ++li) L[lane * 9 + li] = p[li];
    __builtin_amdgcn_wave_barrier();
    float s = 0.f;
#pragma unroll
    for (int k = 0; k < 8; ++k) s += L[(j * 8 + k) * 9 + g];
    __builtin_amdgcn_wave_barrier();
    s += __shfl_xor(s, 1);
    s += __shfl_xor(s, 2);
    s += __shfl_xor(s, 4);
    int l = l0 + g;
    if (j == 0 && l < 196) {
      float xv = xc_p[(size_t)l * 512];
      float zv = z_p[(size_t)l * 1024];
      float sig = 1.f / (1.f + __expf(-zv));
      y_p[(size_t)l * 512] = f2bu((s + dsk * xv) * (zv * sig));
    }
  }
}

// ---------- head ----------
__global__ __launch_bounds__(256) void k_mean(const float* __restrict__ h,
                                              float* __restrict__ pooled) {
  int b = blockIdx.x, e = threadIdx.x;
  float s = 0.f;
  for (int l = 0; l < 196; ++l) s += h[(size_t)(b * 196 + l) * 256 + e];
  pooled[b * 256 + e] = s * (1.f / 196.f);
}

__global__ __launch_bounds__(320) void k_fc(const float* __restrict__ pooled,
                                            const float* __restrict__ fw,
                                            const float* __restrict__ fb,
                                            float* __restrict__ out) {
  int t = threadIdx.x;
  if (t >= 320) return;
  int b = t / 10, n = t - b * 10;
  float s = fb[n];
  for (int e = 0; e < 256; ++e) s += pooled[b * 256 + e] * fw[n * 256 + e];
  out[t] = s;
}

// ---------- launcher ----------
static inline unsigned cdiv(unsigned a, unsigned b) { return (a + b - 1) / b; }

extern "C" void kernel_launch(void* const* d_in, const int* in_sizes, int n_in,
                              void* d_out, int out_size, void* d_ws, size_t ws_size,
                              hipStream_t stream) {
  const float* x = (const float*)d_in[0];
  const float* c1w = (const float*)d_in[1]; const float* c1b = (const float*)d_in[2];
  const float* b1g = (const float*)d_in[3]; const float* b1b = (const float*)d_in[4];
  const float* b1m = (const float*)d_in[5]; const float* b1v = (const float*)d_in[6];
  const float* c2w = (const float*)d_in[7]; const float* c2b = (const float*)d_in[8];
  const float* b2g = (const float*)d_in[9]; const float* b2b = (const float*)d_in[10];
  const float* b2m = (const float*)d_in[11]; const float* b2v = (const float*)d_in[12];
  const float* c3w = (const float*)d_in[13]; const float* c3b = (const float*)d_in[14];
  const float* b3g = (const float*)d_in[15]; const float* b3b = (const float*)d_in[16];
  const float* b3m = (const float*)d_in[17]; const float* b3v = (const float*)d_in[18];
  const float* ln_g = (const float*)d_in[19]; const float* ln_b = (const float*)d_in[20];
  const float* w_in = (const float*)d_in[21];
  const float* cw = (const float*)d_in[22]; const float* cbv = (const float*)d_in[23];
  const float* w_x = (const float*)d_in[24];
  const float* w_dt = (const float*)d_in[25]; const float* b_dt = (const float*)d_in[26];
  const float* a_log = (const float*)d_in[27]; const float* d_skip = (const float*)d_in[28];
  const float* w_out = (const float*)d_in[29];
  const float* fc_w = (const float*)d_in[30]; const float* fc_b = (const float*)d_in[31];

  char* ws = (char*)d_ws;
  size_t off = 0;
  auto take = [&](size_t bytes) { size_t o = off; off += bytes; return o; };
  // scratch region S: stem buffers (phase 1) union mamba buffers (phase 2)
  size_t S = take(67837952);
  // stem phase 1: conv1a output + pooled t1
  unsigned short* c1o = (unsigned short*)(ws + S + 0);          // 51.38 MB
  unsigned short* t1 = (unsigned short*)(ws + S + 51380224);    // 12.85 MB
  // stem phase 2 (c1o dead once t1 is written)
  unsigned short* t2 = (unsigned short*)(ws + S + 0);           // 25.69 MB
  unsigned short* t3 = (unsigned short*)(ws + S + 25690112);    // 6.42 MB
  unsigned short* t4 = (unsigned short*)(ws + S + 32112640);    // 12.85 MB
  // mamba phase (stem buffers dead)
  float* xz = (float*)(ws + S + 0);
  float* xc = (float*)(ws + S + 25690112);
  unsigned short* xcb = (unsigned short*)(ws + S + 38535168);
  float* dbl = (float*)(ws + S + 44957696);
  float* dtb = (float*)(ws + S + 48570368);
  unsigned short* ybf = (unsigned short*)(ws + S + 61415424);
  float* h = (float*)(ws + take(6422528));
  unsigned short* hbf = (unsigned short*)(ws + take(3211264));
  unsigned short* w_in_bf = (unsigned short*)(ws + take(3145728));
  unsigned short* w_x_bf = (unsigned short*)(ws + take(884736));
  unsigned short* w_out_bf = (unsigned short*)(ws + take(1572864));
  unsigned short* w2p = (unsigned short*)(ws + take(147456));
  unsigned short* w3p = (unsigned short*)(ws + take(589824));
  float* wdt_t = (float*)(ws + take(196608));
  float* pooled = (float*)(ws + take(32768));
  (void)ws_size; (void)in_sizes; (void)n_in; (void)out_size;

  // weight conversion / repack
  k_f2b<<<cdiv(1572864, 256), 256, 0, stream>>>(w_in, w_in_bf, 1572864);
  k_f2b<<<cdiv(442368, 256), 256, 0, stream>>>(w_x, w_x_bf, 442368);
  k_f2b<<<cdiv(786432, 256), 256, 0, stream>>>(w_out, w_out_bf, 786432);
  k_repack<64><<<cdiv(73728, 256), 256, 0, stream>>>(c2w, w2p, 73728);
  k_repack<128><<<cdiv(294912, 256), 256, 0, stream>>>(c3w, w3p, 294912);
  k_wdt_t<<<cdiv(49152, 256), 256, 0, stream>>>(w_dt, wdt_t);

  // stem
  k_conv1a<<<100352, 256, 0, stream>>>(x, c1w, c1b, b1g, b1b, b1m, b1v, c1o);
  k_pool3<<<25088, 256, 0, stream>>>(c1o, t1);
  k_convgemm<56, 56, 64, 128><<<1568 * 2, 256, 0, stream>>>(t1, w2p, c2b, b2g, b2b, b2m, b2v, t2);
  k_pool<56, 56, 128, false><<<12544, 256, 0, stream>>>(t2, t3);
  k_convgemm<28, 28, 128, 256><<<392 * 4, 256, 0, stream>>>(t3, w3p, c3b, b3g, b3b, b3m, b3v, t4);
  k_pool<28, 28, 256, true><<<6272, 256, 0, stream>>>(t4, h);

  // mamba blocks
  for (int blk = 0; blk < 6; ++blk) {
    k_ln<<<1568, 256, 0, stream>>>(h, ln_g + blk * 256, ln_b + blk * 256, hbf);
    k_sgemm<128, 128, 4, false><<<49 * 8, 256, 0, stream>>>(
        hbf, w_in_bf + (size_t)blk * 1024 * 256, xz, 1024, 8);
    k_dwconv<<<12544, 256, 0, stream>>>(xz, cw + blk * 512 * 4, cbv + blk * 512, xc, xcb);
    k_gemm<false><<<98 * 3, 256, 0, stream>>>(xcb, w_x_bf + (size_t)blk * 144 * 512, dbl,
                                              6272, 144, 512, 3);
    k_dt<<<12544, 256, 0, stream>>>(dbl, wdt_t + blk * 8192, b_dt + blk * 512, dtb);
    k_scan<<<4096, 256, 0, stream>>>(dtb, xc, dbl, xz, a_log + blk * 512 * 64,
                                     d_skip + blk * 512, ybf);
    k_sgemm<64, 64, 8, true><<<98 * 4, 256, 0, stream>>>(
        ybf, w_out_bf + (size_t)blk * 256 * 512, h, 256, 4);
  }

  // head
  k_mean<<<32, 256, 0, stream>>>(h, pooled);
  k_fc<<<1, 320, 0, stream>>>(pooled, fc_w, fc_b, (float*)d_out);
}

// Round 6
// 1937.484 us; speedup vs baseline: 1.2998x; 1.0010x over previous
//
#include <hip/hip_runtime.h>

// ---------- types ----------
typedef __bf16 bf16x8 __attribute__((ext_vector_type(8)));
typedef float f32x4 __attribute__((ext_vector_type(4)));

#define EPS 1e-5f

__device__ __forceinline__ unsigned short f2bu(float f) {
  union { float f; unsigned u; } x; x.f = f;
  unsigned r = x.u + 0x7fffu + ((x.u >> 16) & 1u);  // RNE
  return (unsigned short)(r >> 16);
}
__device__ __forceinline__ float bu2f(unsigned short u) {
  union { unsigned u; float f; } x; x.u = ((unsigned)u) << 16;
  return x.f;
}

__device__ __forceinline__ void gld16(const void* g, void* l) {
  __builtin_amdgcn_global_load_lds((const __attribute__((address_space(1))) void*)g,
                                   (__attribute__((address_space(3))) void*)l, 16, 0, 0);
}

// ---------- fused prep: f2b (w_in,w_x,w_out) + conv repacks + w_dt transpose ----------
__global__ __launch_bounds__(256) void k_prep(
    const float* __restrict__ w_in, unsigned short* __restrict__ w_in_bf,
    const float* __restrict__ w_x, unsigned short* __restrict__ w_x_bf,
    const float* __restrict__ w_out, unsigned short* __restrict__ w_out_bf,
    const float* __restrict__ c2w, unsigned short* __restrict__ w2p,
    const float* __restrict__ c3w, unsigned short* __restrict__ w3p,
    const float* __restrict__ w_dt, float* __restrict__ wdt_t) {
  int id = blockIdx.x * 256 + threadIdx.x;
  if (id < 1572864) { w_in_bf[id] = f2bu(w_in[id]); return; }
  id -= 1572864;
  if (id < 442368) { w_x_bf[id] = f2bu(w_x[id]); return; }
  id -= 442368;
  if (id < 786432) { w_out_bf[id] = f2bu(w_out[id]); return; }
  id -= 786432;
  if (id < 73728) {  // repack CI=64
    int ci = id % 64, tap = (id / 64) % 9, co = id / 576;
    w2p[id] = f2bu(c2w[(co * 64 + ci) * 9 + tap]);
    return;
  }
  id -= 73728;
  if (id < 294912) {  // repack CI=128
    int ci = id % 128, tap = (id / 128) % 9, co = id / 1152;
    w3p[id] = f2bu(c3w[(co * 128 + ci) * 9 + tap]);
    return;
  }
  id -= 294912;
  {  // w_dt transpose (6*16*512)
    int d = id & 511, r = (id >> 9) & 15, blk = id >> 13;
    wdt_t[id] = w_dt[(blk * 512 + d) * 16 + r];
  }
}

// ---------- conv1 pass A: 3x3 s2 p1, NCHW f32 in -> NHWC bf16 (BN+ReLU fused) ----------
// weights hoisted to VGPRs; wave-uniform interior fast path (no bounds checks)
__global__ __launch_bounds__(256) void k_conv1a(
    const float* __restrict__ x, const float* __restrict__ w,
    const float* __restrict__ cb, const float* __restrict__ g,
    const float* __restrict__ bb, const float* __restrict__ bm_,
    const float* __restrict__ bv, unsigned short* __restrict__ out) {
  __shared__ float sw[64 * 27];
  __shared__ float sa[64], sb[64];
  for (int i = threadIdx.x; i < 64 * 27; i += 256) sw[i] = w[i];
  if (threadIdx.x < 64) {
    int c = threadIdx.x;
    float alpha = g[c] * rsqrtf(bv[c] + EPS);
    sa[c] = alpha;
    sb[c] = (cb[c] - bm_[c]) * alpha + bb[c];
  }
  __syncthreads();
  int id = blockIdx.x * 256 + threadIdx.x;  // ((b*112+oy)*112+ox)*64 + c
  int c = id & 63;
  int t = id >> 6;
  int ox = t % 112; t /= 112;
  int oy = t % 112;
  int b = t / 112;
  float wr[27];
#pragma unroll
  for (int i = 0; i < 27; ++i) wr[i] = sw[c * 27 + i];
  float alpha = sa[c], beta = sb[c];
  const float* base = x + (size_t)b * 3 * 224 * 224 + (oy * 2 - 1) * 224 + (ox * 2 - 1);
  float acc = 0.f;
  if (oy >= 1 && ox >= 1) {  // wave-uniform branch: interior, all 27 taps in-bounds
#pragma unroll
    for (int ci = 0; ci < 3; ++ci)
#pragma unroll
      for (int ky = 0; ky < 3; ++ky)
#pragma unroll
        for (int kx = 0; kx < 3; ++kx)
          acc = fmaf(base[ci * 224 * 224 + ky * 224 + kx], wr[ci * 9 + ky * 3 + kx], acc);
  } else {  // border (oy==0 or ox==0)
#pragma unroll
    for (int ci = 0; ci < 3; ++ci)
#pragma unroll
      for (int ky = 0; ky < 3; ++ky) {
        int iy = oy * 2 - 1 + ky;
        bool vy = (unsigned)iy < 224u;
#pragma unroll
        for (int kx = 0; kx < 3; ++kx) {
          int ix = ox * 2 - 1 + kx;
          float v = (vy && (unsigned)ix < 224u)
                        ? x[(size_t)b * 3 * 224 * 224 + (ci * 224 + iy) * 224 + ix] : 0.f;
          acc = fmaf(v, wr[ci * 9 + ky * 3 + kx], acc);
        }
      }
  }
  out[id] = f2bu(fmaxf(acc * alpha + beta, 0.f));
}

// ---------- conv1 pass B: 3x3 s2 p1 maxpool on NHWC bf16 (values >= 0) ----------
__global__ __launch_bounds__(256) void k_pool3(const unsigned short* __restrict__ in,
                                               unsigned short* __restrict__ out) {
  int id = blockIdx.x * 256 + threadIdx.x;  // ((b*56+py)*56+px)*64 + c
  int c = id & 63;
  int t = id >> 6;
  int px = t % 56; t /= 56;
  int py = t % 56;
  int b = t / 56;
  float m = 0.f;  // inputs are post-ReLU (>= 0)
#pragma unroll
  for (int ky = 0; ky < 3; ++ky) {
    int iy = py * 2 - 1 + ky;
    if ((unsigned)iy >= 112u) continue;
#pragma unroll
    for (int kx = 0; kx < 3; ++kx) {
      int ix = px * 2 - 1 + kx;
      if ((unsigned)ix >= 112u) continue;
      m = fmaxf(m, bu2f(in[(((size_t)(b * 112 + iy) * 112) + ix) * 64 + c]));
    }
  }
  out[id] = f2bu(m);
}

// ---------- implicit-GEMM 3x3 s1 p1 conv, NHWC bf16 in/out, BN+ReLU epilogue ----------
template <int H, int Wd, int CI, int CO>
__global__ __launch_bounds__(256) void k_convgemm(
    const unsigned short* __restrict__ In, const unsigned short* __restrict__ Wt,
    const float* __restrict__ cb, const float* __restrict__ g,
    const float* __restrict__ bb, const float* __restrict__ bm_,
    const float* __restrict__ bv, unsigned short* __restrict__ Out) {
  constexpr int K = 9 * CI;
  constexpr int NTN = CO / 64;
  int bm = blockIdx.x / NTN, bn = blockIdx.x - bm * NTN;
  int lane = threadIdx.x & 63, wid = threadIdx.x >> 6;
  int wr = wid >> 1, wc = wid & 1;
  int r0 = bm * 64 + wr * 32 + (lane & 15);
  int r1 = r0 + 16;
  int c0 = bn * 64 + wc * 32 + (lane & 15);
  int koff = (lane >> 4) << 3;
  int ox0 = r0 % Wd; int t0 = r0 / Wd; int oy0 = t0 % H; int b0 = t0 / H;
  int ox1 = r1 % Wd; int t1 = r1 / Wd; int oy1 = t1 % H; int b1 = t1 / H;
  const unsigned short* pb0 = Wt + (size_t)c0 * K + koff;
  const unsigned short* pb1 = Wt + (size_t)(c0 + 16) * K + koff;
  f32x4 acc[2][2] = {};
  for (int k0 = 0; k0 < K; k0 += 32) {
    int k = k0 + koff;
    int tap = k / CI;
    int ci = k - tap * CI;
    int ky = tap / 3, kx = tap - ky * 3;
    int iy0 = oy0 + ky - 1, ix0 = ox0 + kx - 1;
    int iy1 = oy1 + ky - 1, ix1 = ox1 + kx - 1;
    bf16x8 a0 = {};
    bf16x8 a1 = {};
    if ((unsigned)iy0 < (unsigned)H && (unsigned)ix0 < (unsigned)Wd)
      a0 = *(const bf16x8*)(In + ((size_t)((b0 * H + iy0) * Wd + ix0)) * CI + ci);
    if ((unsigned)iy1 < (unsigned)H && (unsigned)ix1 < (unsigned)Wd)
      a1 = *(const bf16x8*)(In + ((size_t)((b1 * H + iy1) * Wd + ix1)) * CI + ci);
    bf16x8 w0 = *(const bf16x8*)(pb0 + k0);
    bf16x8 w1 = *(const bf16x8*)(pb1 + k0);
    acc[0][0] = __builtin_amdgcn_mfma_f32_16x16x32_bf16(a0, w0, acc[0][0], 0, 0, 0);
    acc[0][1] = __builtin_amdgcn_mfma_f32_16x16x32_bf16(a0, w1, acc[0][1], 0, 0, 0);
    acc[1][0] = __builtin_amdgcn_mfma_f32_16x16x32_bf16(a1, w0, acc[1][0], 0, 0, 0);
    acc[1][1] = __builtin_amdgcn_mfma_f32_16x16x32_bf16(a1, w1, acc[1][1], 0, 0, 0);
  }
  int rr = (lane >> 4) * 4, rc = lane & 15;
#pragma unroll
  for (int tj = 0; tj < 2; ++tj) {
    int col = bn * 64 + wc * 32 + tj * 16 + rc;
    float alpha = g[col] * rsqrtf(bv[col] + EPS);
    float beta = (cb[col] - bm_[col]) * alpha + bb[col];
#pragma unroll
    for (int ti = 0; ti < 2; ++ti) {
      int row = bm * 64 + wr * 32 + ti * 16 + rr;
#pragma unroll
      for (int r = 0; r < 4; ++r) {
        float v = fmaxf(acc[ti][tj][r] * alpha + beta, 0.f);
        Out[(size_t)(row + r) * CO + col] = f2bu(v);
      }
    }
  }
}

// ---------- NHWC 2x2/2 maxpool, bf16 in, bf16 or f32 out ----------
template <int H, int Wd, int C, bool OUTF>
__global__ __launch_bounds__(256) void k_pool(const unsigned short* __restrict__ in,
                                              void* __restrict__ outv) {
  constexpr int OH = H / 2, OW = Wd / 2;
  int id = blockIdx.x * 256 + threadIdx.x;  // 32*OH*OW*C exact
  int c = id % C;
  int t = id / C;
  int px = t % OW; t /= OW;
  int py = t % OH;
  int b = t / OH;
  const unsigned short* p = in + (((size_t)(b * H + py * 2) * Wd) + px * 2) * C + c;
  float m0 = bu2f(p[0]), m1 = bu2f(p[C]);
  float m2 = bu2f(p[(size_t)Wd * C]), m3 = bu2f(p[(size_t)Wd * C + C]);
  float m = fmaxf(fmaxf(m0, m1), fmaxf(m2, m3));
  if (OUTF) ((float*)outv)[id] = m;
  else ((unsigned short*)outv)[id] = f2bu(m);
}

// ---------- LayerNorm over 256, f32 in -> bf16 out ----------
__global__ __launch_bounds__(256) void k_ln(const float* __restrict__ h,
                                            const float* __restrict__ g,
                                            const float* __restrict__ b2,
                                            unsigned short* __restrict__ out) {
  int lane = threadIdx.x & 63, wid = threadIdx.x >> 6;
  int t = blockIdx.x * 4 + wid;
  float4 v = *(const float4*)(h + (size_t)t * 256 + lane * 4);
  float s = v.x + v.y + v.z + v.w;
  float q = v.x * v.x + v.y * v.y + v.z * v.z + v.w * v.w;
#pragma unroll
  for (int off = 32; off; off >>= 1) {
    s += __shfl_xor(s, off);
    q += __shfl_xor(q, off);
  }
  float mu = s * (1.f / 256.f);
  float var = q * (1.f / 256.f) - mu * mu;
  float rs = rsqrtf(var + EPS);
  float4 gg = *(const float4*)(g + lane * 4);
  float4 bb = *(const float4*)(b2 + lane * 4);
  ushort4 o;
  o.x = f2bu((v.x - mu) * rs * gg.x + bb.x);
  o.y = f2bu((v.y - mu) * rs * gg.y + bb.y);
  o.z = f2bu((v.z - mu) * rs * gg.z + bb.z);
  o.w = f2bu((v.w - mu) * rs * gg.w + bb.w);
  *(ushort4*)(out + (size_t)t * 256 + lane * 4) = o;
}

// ---------- LDS-staged bf16 GEMM (m97 structure): C[M,N] = A[M,K] @ W[N,K]^T ----------
template <int BM, int BN, int KSTEPS, bool ADD>
__global__ __launch_bounds__(256) void k_sgemm(const unsigned short* __restrict__ A,
                                               const unsigned short* __restrict__ W,
                                               float* __restrict__ C,
                                               int N, int ntn) {
  constexpr int K = KSTEPS * 64;
  constexpr int MR = BM / 32;
  constexpr int NR = BN / 32;
  __shared__ __align__(16) unsigned short As[BM * 64];
  __shared__ __align__(16) unsigned short Bs[BN * 64];
  int bm = blockIdx.x / ntn, bn = blockIdx.x - bm * ntn;
  int lane = threadIdx.x & 63, wid = threadIdx.x >> 6;
  int wr = wid >> 1, wc = wid & 1;
  const int arow = lane >> 3, acol = (lane & 7) * 8;
  f32x4 acc[MR][NR] = {};
  const unsigned short* Abase = A + (size_t)(bm * BM) * K;
  const unsigned short* Wbase = W + (size_t)(bn * BN) * K;
  for (int t = 0; t < KSTEPS; ++t) {
    int k0 = t * 64;
#pragma unroll
    for (int i = 0; i < BM / 32; ++i) {
      int chunk = wid * (BM / 32) + i;
      gld16(Abase + (size_t)(chunk * 8 + arow) * K + k0 + acol, &As[chunk * 512 + lane * 8]);
    }
#pragma unroll
    for (int i = 0; i < BN / 32; ++i) {
      int chunk = wid * (BN / 32) + i;
      gld16(Wbase + (size_t)(chunk * 8 + arow) * K + k0 + acol, &Bs[chunk * 512 + lane * 8]);
    }
    __syncthreads();
#pragma unroll
    for (int kk = 0; kk < 2; ++kk) {
      bf16x8 af[MR], bfr[NR];
#pragma unroll
      for (int mi = 0; mi < MR; ++mi)
        af[mi] = *(const bf16x8*)&As[(wr * (BM / 2) + mi * 16 + (lane & 15)) * 64 + kk * 32 + (lane >> 4) * 8];
#pragma unroll
      for (int nj = 0; nj < NR; ++nj)
        bfr[nj] = *(const bf16x8*)&Bs[(wc * (BN / 2) + nj * 16 + (lane & 15)) * 64 + kk * 32 + (lane >> 4) * 8];
#pragma unroll
      for (int mi = 0; mi < MR; ++mi)
#pragma unroll
        for (int nj = 0; nj < NR; ++nj)
          acc[mi][nj] = __builtin_amdgcn_mfma_f32_16x16x32_bf16(af[mi], bfr[nj], acc[mi][nj], 0, 0, 0);
    }
    __syncthreads();
  }
  int rr = (lane >> 4) * 4, rc = lane & 15;
#pragma unroll
  for (int mi = 0; mi < MR; ++mi)
#pragma unroll
    for (int nj = 0; nj < NR; ++nj) {
      int row = bm * BM + wr * (BM / 2) + mi * 16 + rr;
      int col = bn * BN + wc * (BN / 2) + nj * 16 + rc;
#pragma unroll
      for (int r = 0; r < 4; ++r) {
        float v = acc[mi][nj][r];
        if (ADD) v += C[(size_t)(row + r) * N + col];
        C[(size_t)(row + r) * N + col] = v;
      }
    }
}

// ---------- direct bf16 GEMM (small N): C[M,N] = A[M,K] @ W[N,K]^T ----------
template <bool ADD_RES>
__global__ __launch_bounds__(256) void k_gemm(const unsigned short* __restrict__ A,
                                              const unsigned short* __restrict__ W,
                                              float* __restrict__ C, int M, int N,
                                              int K, int ntn) {
  int bm = blockIdx.x / ntn, bn = blockIdx.x - bm * ntn;
  int lane = threadIdx.x & 63, wid = threadIdx.x >> 6;
  int wr = wid >> 1, wc = wid & 1;
  int r0 = bm * 64 + wr * 32 + (lane & 15);
  int c0 = bn * 64 + wc * 32 + (lane & 15);
  int koff = (lane >> 4) << 3;
  int cc0 = (c0 < N) ? c0 : (N - 1);
  int cc1 = (c0 + 16 < N) ? (c0 + 16) : (N - 1);
  const unsigned short* pa0 = A + (size_t)r0 * K + koff;
  const unsigned short* pa1 = A + (size_t)(r0 + 16) * K + koff;
  const unsigned short* pb0 = W + (size_t)cc0 * K + koff;
  const unsigned short* pb1 = W + (size_t)cc1 * K + koff;
  f32x4 acc[2][2] = {};
  for (int k0 = 0; k0 < K; k0 += 32) {
    bf16x8 a0 = *(const bf16x8*)(pa0 + k0);
    bf16x8 a1 = *(const bf16x8*)(pa1 + k0);
    bf16x8 b0 = *(const bf16x8*)(pb0 + k0);
    bf16x8 b1 = *(const bf16x8*)(pb1 + k0);
    acc[0][0] = __builtin_amdgcn_mfma_f32_16x16x32_bf16(a0, b0, acc[0][0], 0, 0, 0);
    acc[0][1] = __builtin_amdgcn_mfma_f32_16x16x32_bf16(a0, b1, acc[0][1], 0, 0, 0);
    acc[1][0] = __builtin_amdgcn_mfma_f32_16x16x32_bf16(a1, b0, acc[1][0], 0, 0, 0);
    acc[1][1] = __builtin_amdgcn_mfma_f32_16x16x32_bf16(a1, b1, acc[1][1], 0, 0, 0);
  }
  int rr = (lane >> 4) * 4, rc = lane & 15;
#pragma unroll
  for (int ti = 0; ti < 2; ++ti)
#pragma unroll
    for (int tj = 0; tj < 2; ++tj) {
      int col = bn * 64 + wc * 32 + tj * 16 + rc;
      if (col >= N) continue;
      int row = bm * 64 + wr * 32 + ti * 16 + rr;
#pragma unroll
      for (int r = 0; r < 4; ++r) {
        float v = acc[ti][tj][r];
        if (ADD_RES) v += C[(size_t)(row + r) * N + col];
        C[(size_t)(row + r) * N + col] = v;
      }
    }
}

// ---------- depthwise causal conv (DC=4) + silu; writes f32 + bf16 ----------
__global__ __launch_bounds__(256) void k_dwconv(const float* __restrict__ xz,
                                                const float* __restrict__ cw,
                                                const float* __restrict__ cb,
                                                float* __restrict__ xc,
                                                unsigned short* __restrict__ xcb) {
  int id = blockIdx.x * 256 + threadIdx.x;  // 6272*512
  int d = id & 511;
  int bl = id >> 9;
  int l = bl % 196;
  int b = bl / 196;
  const float* xi = xz + (size_t)(b * 196) * 1024 + d;
  float4 c4 = *(const float4*)(cw + d * 4);
  float acc = cb[d];
  if (l >= 3) acc = fmaf(xi[(size_t)(l - 3) * 1024], c4.x, acc);
  if (l >= 2) acc = fmaf(xi[(size_t)(l - 2) * 1024], c4.y, acc);
  if (l >= 1) acc = fmaf(xi[(size_t)(l - 1) * 1024], c4.z, acc);
  acc = fmaf(xi[(size_t)l * 1024], c4.w, acc);
  float s = acc / (1.f + __expf(-acc));
  xc[id] = s;
  xcb[id] = f2bu(s);
}

// ---------- dt = softplus(dbl[:, :16] @ w_dt^T + b_dt), transposed weights ----------
__global__ __launch_bounds__(256) void k_dt(const float* __restrict__ dbl,
                                            const float* __restrict__ wt,
                                            const float* __restrict__ bdt,
                                            float* __restrict__ dt) {
  int id = blockIdx.x * 256 + threadIdx.x;  // 6272*512
  int d = id & 511;
  int bl = id >> 9;
  const float4* a = (const float4*)(dbl + (size_t)bl * 144);
  float acc = bdt[d];
#pragma unroll
  for (int i = 0; i < 4; ++i) {
    float4 av = a[i];
    acc = fmaf(av.x, wt[(i * 4 + 0) * 512 + d], acc);
    acc = fmaf(av.y, wt[(i * 4 + 1) * 512 + d], acc);
    acc = fmaf(av.z, wt[(i * 4 + 2) * 512 + d], acc);
    acc = fmaf(av.w, wt[(i * 4 + 3) * 512 + d], acc);
  }
  dt[id] = fmaxf(acc, 0.f) + log1pf(__expf(-fabsf(acc)));
}

// ---------- selective scan: wave per (b,d), lane = state s ----------
__global__ __launch_bounds__(256) void k_scan(
    const float* __restrict__ dtb, const float* __restrict__ xc,
    const float* __restrict__ dbl, const float* __restrict__ xz,
    const float* __restrict__ a_log, const float* __restrict__ d_skip,
    unsigned short* __restrict__ y) {
  __shared__ float lds[4][584];
  int lane = threadIdx.x & 63, wid = threadIdx.x >> 6;
  int wgid = blockIdx.x * 4 + wid;  // 0..16383
  int b = wgid >> 9, d = wgid & 511;
  float A = -__expf(a_log[d * 64 + lane]);
  float dsk = d_skip[d];
  const float* dt_p = dtb + (size_t)(b * 196) * 512 + d;
  const float* xc_p = xc + (size_t)(b * 196) * 512 + d;
  const float* z_p = xz + (size_t)(b * 196) * 1024 + 512 + d;
  const float* bc_p = dbl + (size_t)(b * 196) * 144 + 16 + lane;
  unsigned short* y_p = y + (size_t)(b * 196) * 512 + d;
  float* L = lds[wid];
  float h = 0.f;
  int g = lane >> 3, j = lane & 7;
  for (int l0 = 0; l0 < 196; l0 += 8) {
    float p[8];
#pragma unroll
    for (int li = 0; li < 8; ++li) {
      int l = l0 + li;
      bool ok = (l < 196);
      float dtv = ok ? dt_p[(size_t)l * 512] : 0.f;
      float xv = ok ? xc_p[(size_t)l * 512] : 0.f;
      float Bv = ok ? bc_p[(size_t)l * 144] : 0.f;
      float Cv = ok ? bc_p[(size_t)l * 144 + 64] : 0.f;
      float dA = __expf(dtv * A);
      h = fmaf(dA, h, (dtv * xv) * Bv);
      p[li] = h * Cv;
    }
#pragma unroll
    for (int li = 0; li < 8; ++li) L[lane * 9 + li] = p[li];
    __builtin_amdgcn_wave_barrier();
    float s = 0.f;
#pragma unroll
    for (int k = 0; k < 8; ++k) s += L[(j * 8 + k) * 9 + g];
    __builtin_amdgcn_wave_barrier();
    s += __shfl_xor(s, 1);
    s += __shfl_xor(s, 2);
    s += __shfl_xor(s, 4);
    int l = l0 + g;
    if (j == 0 && l < 196) {
      float xv = xc_p[(size_t)l * 512];
      float zv = z_p[(size_t)l * 1024];
      float sig = 1.f / (1.f + __expf(-zv));
      y_p[(size_t)l * 512] = f2bu((s + dsk * xv) * (zv * sig));
    }
  }
}

// ---------- head: partial mean (4 chunks of 49 rows) then fused reduce+FC ----------
__global__ __launch_bounds__(256) void k_mean2(const float* __restrict__ h,
                                               float* __restrict__ part) {
  int b = blockIdx.x >> 2, q = blockIdx.x & 3;
  int e = threadIdx.x;
  const float* hb = h + ((size_t)b * 196 + q * 49) * 256 + e;
  float s = 0.f;
  for (int l = 0; l < 49; ++l) s += hb[(size_t)l * 256];
  part[((size_t)b * 4 + q) * 256 + e] = s;
}

__global__ __launch_bounds__(256) void k_head(const float* __restrict__ part,
                                              const float* __restrict__ fw,
                                              const float* __restrict__ fb,
                                              float* __restrict__ out) {
  __shared__ float sp[256];
  int b = blockIdx.x;
  int tid = threadIdx.x, lane = tid & 63, w = tid >> 6;
  const float* pb = part + (size_t)b * 4 * 256;
  sp[tid] = (pb[tid] + pb[256 + tid] + pb[512 + tid] + pb[768 + tid]) * (1.f / 196.f);
  __syncthreads();
  // wave w handles outputs n = w, w+4, w+8 (n < 10)
  for (int n = w; n < 10; n += 4) {
    float s = 0.f;
#pragma unroll
    for (int i = 0; i < 4; ++i) {
      int e = lane * 4 + i;
      e = e & 255;
      s += sp[e] * fw[n * 256 + e];
    }
    s += __shfl_xor(s, 1); s += __shfl_xor(s, 2); s += __shfl_xor(s, 4);
    s += __shfl_xor(s, 8); s += __shfl_xor(s, 16); s += __shfl_xor(s, 32);
    if (lane == 0) out[b * 10 + n] = s + fb[n];
  }
}

// ---------- launcher ----------
static inline unsigned cdiv(unsigned a, unsigned b) { return (a + b - 1) / b; }

extern "C" void kernel_launch(void* const* d_in, const int* in_sizes, int n_in,
                              void* d_out, int out_size, void* d_ws, size_t ws_size,
                              hipStream_t stream) {
  const float* x = (const float*)d_in[0];
  const float* c1w = (const float*)d_in[1]; const float* c1b = (const float*)d_in[2];
  const float* b1g = (const float*)d_in[3]; const float* b1b = (const float*)d_in[4];
  const float* b1m = (const float*)d_in[5]; const float* b1v = (const float*)d_in[6];
  const float* c2w = (const float*)d_in[7]; const float* c2b = (const float*)d_in[8];
  const float* b2g = (const float*)d_in[9]; const float* b2b = (const float*)d_in[10];
  const float* b2m = (const float*)d_in[11]; const float* b2v = (const float*)d_in[12];
  const float* c3w = (const float*)d_in[13]; const float* c3b = (const float*)d_in[14];
  const float* b3g = (const float*)d_in[15]; const float* b3b = (const float*)d_in[16];
  const float* b3m = (const float*)d_in[17]; const float* b3v = (const float*)d_in[18];
  const float* ln_g = (const float*)d_in[19]; const float* ln_b = (const float*)d_in[20];
  const float* w_in = (const float*)d_in[21];
  const float* cw = (const float*)d_in[22]; const float* cbv = (const float*)d_in[23];
  const float* w_x = (const float*)d_in[24];
  const float* w_dt = (const float*)d_in[25]; const float* b_dt = (const float*)d_in[26];
  const float* a_log = (const float*)d_in[27]; const float* d_skip = (const float*)d_in[28];
  const float* w_out = (const float*)d_in[29];
  const float* fc_w = (const float*)d_in[30]; const float* fc_b = (const float*)d_in[31];

  char* ws = (char*)d_ws;
  size_t off = 0;
  auto take = [&](size_t bytes) { size_t o = off; off += bytes; return o; };
  // scratch region S: stem buffers (phase 1) union mamba buffers (phase 2)
  size_t S = take(67837952);
  // stem phase 1: conv1a output + pooled t1
  unsigned short* c1o = (unsigned short*)(ws + S + 0);          // 51.38 MB
  unsigned short* t1 = (unsigned short*)(ws + S + 51380224);    // 12.85 MB
  // stem phase 2 (c1o dead once t1 is written)
  unsigned short* t2 = (unsigned short*)(ws + S + 0);           // 25.69 MB
  unsigned short* t3 = (unsigned short*)(ws + S + 25690112);    // 6.42 MB
  unsigned short* t4 = (unsigned short*)(ws + S + 32112640);    // 12.85 MB
  // mamba phase (stem buffers dead)
  float* xz = (float*)(ws + S + 0);
  float* xc = (float*)(ws + S + 25690112);
  unsigned short* xcb = (unsigned short*)(ws + S + 38535168);
  float* dbl = (float*)(ws + S + 44957696);
  float* dtb = (float*)(ws + S + 48570368);
  unsigned short* ybf = (unsigned short*)(ws + S + 61415424);
  float* h = (float*)(ws + take(6422528));
  unsigned short* hbf = (unsigned short*)(ws + take(3211264));
  unsigned short* w_in_bf = (unsigned short*)(ws + take(3145728));
  unsigned short* w_x_bf = (unsigned short*)(ws + take(884736));
  unsigned short* w_out_bf = (unsigned short*)(ws + take(1572864));
  unsigned short* w2p = (unsigned short*)(ws + take(147456));
  unsigned short* w3p = (unsigned short*)(ws + take(589824));
  float* wdt_t = (float*)(ws + take(196608));
  float* part = (float*)(ws + take(131072));
  (void)ws_size; (void)in_sizes; (void)n_in; (void)out_size;

  // fused weight conversion / repack / transpose (3219456 elems = 12576 * 256)
  k_prep<<<12576, 256, 0, stream>>>(w_in, w_in_bf, w_x, w_x_bf, w_out, w_out_bf,
                                    c2w, w2p, c3w, w3p, w_dt, wdt_t);

  // stem
  k_conv1a<<<100352, 256, 0, stream>>>(x, c1w, c1b, b1g, b1b, b1m, b1v, c1o);
  k_pool3<<<25088, 256, 0, stream>>>(c1o, t1);
  k_convgemm<56, 56, 64, 128><<<1568 * 2, 256, 0, stream>>>(t1, w2p, c2b, b2g, b2b, b2m, b2v, t2);
  k_pool<56, 56, 128, false><<<12544, 256, 0, stream>>>(t2, t3);
  k_convgemm<28, 28, 128, 256><<<392 * 4, 256, 0, stream>>>(t3, w3p, c3b, b3g, b3b, b3m, b3v, t4);
  k_pool<28, 28, 256, true><<<6272, 256, 0, stream>>>(t4, h);

  // mamba blocks
  for (int blk = 0; blk < 6; ++blk) {
    k_ln<<<1568, 256, 0, stream>>>(h, ln_g + blk * 256, ln_b + blk * 256, hbf);
    k_sgemm<128, 128, 4, false><<<49 * 8, 256, 0, stream>>>(
        hbf, w_in_bf + (size_t)blk * 1024 * 256, xz, 1024, 8);
    k_dwconv<<<12544, 256, 0, stream>>>(xz, cw + blk * 512 * 4, cbv + blk * 512, xc, xcb);
    k_gemm<false><<<98 * 3, 256, 0, stream>>>(xcb, w_x_bf + (size_t)blk * 144 * 512, dbl,
                                              6272, 144, 512, 3);
    k_dt<<<12544, 256, 0, stream>>>(dbl, wdt_t + blk * 8192, b_dt + blk * 512, dtb);
    k_scan<<<4096, 256, 0, stream>>>(dtb, xc, dbl, xz, a_log + blk * 512 * 64,
                                     d_skip + blk * 512, ybf);
    k_sgemm<64, 64, 8, true><<<98 * 4, 256, 0, stream>>>(
        ybf, w_out_bf + (size_t)blk * 256 * 512, h, 256, 4);
  }

  // head
  k_mean2<<<128, 256, 0, stream>>>(h, part);
  k_head<<<32, 256, 0, stream>>>(part, fc_w, fc_b, (float*)d_out);
}

// Round 7
// 1769.760 us; speedup vs baseline: 1.4230x; 1.0948x over previous
//
#include <hip/hip_runtime.h>

// ---------- types ----------
typedef __bf16 bf16x8 __attribute__((ext_vector_type(8)));
typedef float f32x4 __attribute__((ext_vector_type(4)));

#define EPS 1e-5f

__device__ __forceinline__ unsigned short f2bu(float f) {
  union { float f; unsigned u; } x; x.f = f;
  unsigned r = x.u + 0x7fffu + ((x.u >> 16) & 1u);  // RNE
  return (unsigned short)(r >> 16);
}
__device__ __forceinline__ float bu2f(unsigned short u) {
  union { unsigned u; float f; } x; x.u = ((unsigned)u) << 16;
  return x.f;
}

__device__ __forceinline__ void gld16(const void* g, void* l) {
  __builtin_amdgcn_global_load_lds((const __attribute__((address_space(1))) void*)g,
                                   (__attribute__((address_space(3))) void*)l, 16, 0, 0);
}

// ---------- fused prep: f2b (w_in,w_x,w_out) + conv repacks + w_dt transpose ----------
__global__ __launch_bounds__(256) void k_prep(
    const float* __restrict__ w_in, unsigned short* __restrict__ w_in_bf,
    const float* __restrict__ w_x, unsigned short* __restrict__ w_x_bf,
    const float* __restrict__ w_out, unsigned short* __restrict__ w_out_bf,
    const float* __restrict__ c2w, unsigned short* __restrict__ w2p,
    const float* __restrict__ c3w, unsigned short* __restrict__ w3p,
    const float* __restrict__ w_dt, float* __restrict__ wdt_t) {
  int id = blockIdx.x * 256 + threadIdx.x;
  if (id < 1572864) { w_in_bf[id] = f2bu(w_in[id]); return; }
  id -= 1572864;
  if (id < 442368) { w_x_bf[id] = f2bu(w_x[id]); return; }
  id -= 442368;
  if (id < 786432) { w_out_bf[id] = f2bu(w_out[id]); return; }
  id -= 786432;
  if (id < 73728) {  // repack CI=64
    int ci = id % 64, tap = (id / 64) % 9, co = id / 576;
    w2p[id] = f2bu(c2w[(co * 64 + ci) * 9 + tap]);
    return;
  }
  id -= 73728;
  if (id < 294912) {  // repack CI=128
    int ci = id % 128, tap = (id / 128) % 9, co = id / 1152;
    w3p[id] = f2bu(c3w[(co * 128 + ci) * 9 + tap]);
    return;
  }
  id -= 294912;
  {  // w_dt transpose (6*16*512)
    int d = id & 511, r = (id >> 9) & 15, blk = id >> 13;
    wdt_t[id] = w_dt[(blk * 512 + d) * 16 + r];
  }
}

// ---------- conv1 pass A v4: block = (b,oy) row; LDS-staged x window; ----------
// thread = (channel, ox-group of 28); broadcast ds_read_b128 x; zero-pad edges.
__global__ __launch_bounds__(256) void k_conv1a(
    const float* __restrict__ x, const float* __restrict__ w,
    const float* __restrict__ cb, const float* __restrict__ g,
    const float* __restrict__ bb, const float* __restrict__ bm_,
    const float* __restrict__ bv, unsigned short* __restrict__ out) {
  __shared__ __align__(16) float sx[9][228];  // [ci*3+ky][1+ix], zero-padded
  __shared__ float sw[64 * 27];
  __shared__ float sa[64], sb[64];
  int tid = threadIdx.x;
  int oy = blockIdx.x % 112, b = blockIdx.x / 112;
  // stage input rows (zero-filled outside [0,224))
  for (int i = tid; i < 9 * 228; i += 256) {
    int row = i / 228;
    int ixl = i - row * 228;
    int ci = row / 3, ky = row - ci * 3;
    int iy = 2 * oy - 1 + ky;
    int ix = ixl - 1;
    float v = 0.f;
    if ((unsigned)iy < 224u && (unsigned)ix < 224u)
      v = x[((size_t)(b * 3 + ci) * 224 + iy) * 224 + ix];
    sx[row][ixl] = v;
  }
  // stage weights + folded BN
  for (int i = tid; i < 64 * 27; i += 256) sw[i] = w[i];
  if (tid < 64) {
    int c = tid;
    float alpha = g[c] * rsqrtf(bv[c] + EPS);
    sa[c] = alpha;
    sb[c] = (cb[c] - bm_[c]) * alpha + bb[c];
  }
  __syncthreads();
  int c = tid & 63, grp = tid >> 6;  // 4 groups x 28 pixels
  int ox0 = grp * 28;
  float acc[28];
#pragma unroll
  for (int i = 0; i < 28; ++i) acc[i] = 0.f;
#pragma unroll
  for (int ci = 0; ci < 3; ++ci) {
    float wr[9];
#pragma unroll
    for (int j = 0; j < 9; ++j) wr[j] = sw[c * 27 + ci * 9 + j];
#pragma unroll
    for (int ky = 0; ky < 3; ++ky) {
      const float* row = sx[ci * 3 + ky];
#pragma unroll
      for (int q = 0; q < 7; ++q) {
        int base = 2 * (ox0 + q * 4);  // 16B-aligned
        f32x4 a0 = *(const f32x4*)&row[base];
        f32x4 a1 = *(const f32x4*)&row[base + 4];
        f32x4 a2 = *(const f32x4*)&row[base + 8];
        float xv[12] = {a0[0], a0[1], a0[2], a0[3], a1[0], a1[1],
                        a1[2], a1[3], a2[0], a2[1], a2[2], a2[3]};
#pragma unroll
        for (int p = 0; p < 4; ++p) {
          acc[q * 4 + p] = fmaf(xv[2 * p + 0], wr[ky * 3 + 0], acc[q * 4 + p]);
          acc[q * 4 + p] = fmaf(xv[2 * p + 1], wr[ky * 3 + 1], acc[q * 4 + p]);
          acc[q * 4 + p] = fmaf(xv[2 * p + 2], wr[ky * 3 + 2], acc[q * 4 + p]);
        }
      }
    }
  }
  float alpha = sa[c], beta = sb[c];
  unsigned short* op = out + (((size_t)(b * 112 + oy)) * 112 + ox0) * 64 + c;
#pragma unroll
  for (int p = 0; p < 28; ++p)
    op[(size_t)p * 64] = f2bu(fmaxf(acc[p] * alpha + beta, 0.f));
}

// ---------- conv1 pass B: 3x3 s2 p1 maxpool on NHWC bf16 (values >= 0) ----------
__global__ __launch_bounds__(256) void k_pool3(const unsigned short* __restrict__ in,
                                               unsigned short* __restrict__ out) {
  int id = blockIdx.x * 256 + threadIdx.x;  // ((b*56+py)*56+px)*64 + c
  int c = id & 63;
  int t = id >> 6;
  int px = t % 56; t /= 56;
  int py = t % 56;
  int b = t / 56;
  float m = 0.f;  // inputs are post-ReLU (>= 0)
#pragma unroll
  for (int ky = 0; ky < 3; ++ky) {
    int iy = py * 2 - 1 + ky;
    if ((unsigned)iy >= 112u) continue;
#pragma unroll
    for (int kx = 0; kx < 3; ++kx) {
      int ix = px * 2 - 1 + kx;
      if ((unsigned)ix >= 112u) continue;
      m = fmaxf(m, bu2f(in[(((size_t)(b * 112 + iy) * 112) + ix) * 64 + c]));
    }
  }
  out[id] = f2bu(m);
}

// ---------- implicit-GEMM 3x3 s1 p1 conv, NHWC bf16 in/out, BN+ReLU epilogue ----------
template <int H, int Wd, int CI, int CO>
__global__ __launch_bounds__(256) void k_convgemm(
    const unsigned short* __restrict__ In, const unsigned short* __restrict__ Wt,
    const float* __restrict__ cb, const float* __restrict__ g,
    const float* __restrict__ bb, const float* __restrict__ bm_,
    const float* __restrict__ bv, unsigned short* __restrict__ Out) {
  constexpr int K = 9 * CI;
  constexpr int NTN = CO / 64;
  int bm = blockIdx.x / NTN, bn = blockIdx.x - bm * NTN;
  int lane = threadIdx.x & 63, wid = threadIdx.x >> 6;
  int wr = wid >> 1, wc = wid & 1;
  int r0 = bm * 64 + wr * 32 + (lane & 15);
  int r1 = r0 + 16;
  int c0 = bn * 64 + wc * 32 + (lane & 15);
  int koff = (lane >> 4) << 3;
  int ox0 = r0 % Wd; int t0 = r0 / Wd; int oy0 = t0 % H; int b0 = t0 / H;
  int ox1 = r1 % Wd; int t1 = r1 / Wd; int oy1 = t1 % H; int b1 = t1 / H;
  const unsigned short* pb0 = Wt + (size_t)c0 * K + koff;
  const unsigned short* pb1 = Wt + (size_t)(c0 + 16) * K + koff;
  f32x4 acc[2][2] = {};
  for (int k0 = 0; k0 < K; k0 += 32) {
    int k = k0 + koff;
    int tap = k / CI;
    int ci = k - tap * CI;
    int ky = tap / 3, kx = tap - ky * 3;
    int iy0 = oy0 + ky - 1, ix0 = ox0 + kx - 1;
    int iy1 = oy1 + ky - 1, ix1 = ox1 + kx - 1;
    bf16x8 a0 = {};
    bf16x8 a1 = {};
    if ((unsigned)iy0 < (unsigned)H && (unsigned)ix0 < (unsigned)Wd)
      a0 = *(const bf16x8*)(In + ((size_t)((b0 * H + iy0) * Wd + ix0)) * CI + ci);
    if ((unsigned)iy1 < (unsigned)H && (unsigned)ix1 < (unsigned)Wd)
      a1 = *(const bf16x8*)(In + ((size_t)((b1 * H + iy1) * Wd + ix1)) * CI + ci);
    bf16x8 w0 = *(const bf16x8*)(pb0 + k0);
    bf16x8 w1 = *(const bf16x8*)(pb1 + k0);
    acc[0][0] = __builtin_amdgcn_mfma_f32_16x16x32_bf16(a0, w0, acc[0][0], 0, 0, 0);
    acc[0][1] = __builtin_amdgcn_mfma_f32_16x16x32_bf16(a0, w1, acc[0][1], 0, 0, 0);
    acc[1][0] = __builtin_amdgcn_mfma_f32_16x16x32_bf16(a1, w0, acc[1][0], 0, 0, 0);
    acc[1][1] = __builtin_amdgcn_mfma_f32_16x16x32_bf16(a1, w1, acc[1][1], 0, 0, 0);
  }
  int rr = (lane >> 4) * 4, rc = lane & 15;
#pragma unroll
  for (int tj = 0; tj < 2; ++tj) {
    int col = bn * 64 + wc * 32 + tj * 16 + rc;
    float alpha = g[col] * rsqrtf(bv[col] + EPS);
    float beta = (cb[col] - bm_[col]) * alpha + bb[col];
#pragma unroll
    for (int ti = 0; ti < 2; ++ti) {
      int row = bm * 64 + wr * 32 + ti * 16 + rr;
#pragma unroll
      for (int r = 0; r < 4; ++r) {
        float v = fmaxf(acc[ti][tj][r] * alpha + beta, 0.f);
        Out[(size_t)(row + r) * CO + col] = f2bu(v);
      }
    }
  }
}

// ---------- NHWC 2x2/2 maxpool, bf16 in, bf16 or f32 out ----------
template <int H, int Wd, int C, bool OUTF>
__global__ __launch_bounds__(256) void k_pool(const unsigned short* __restrict__ in,
                                              void* __restrict__ outv) {
  constexpr int OH = H / 2, OW = Wd / 2;
  int id = blockIdx.x * 256 + threadIdx.x;  // 32*OH*OW*C exact
  int c = id % C;
  int t = id / C;
  int px = t % OW; t /= OW;
  int py = t % OH;
  int b = t / OH;
  const unsigned short* p = in + (((size_t)(b * H + py * 2) * Wd) + px * 2) * C + c;
  float m0 = bu2f(p[0]), m1 = bu2f(p[C]);
  float m2 = bu2f(p[(size_t)Wd * C]), m3 = bu2f(p[(size_t)Wd * C + C]);
  float m = fmaxf(fmaxf(m0, m1), fmaxf(m2, m3));
  if (OUTF) ((float*)outv)[id] = m;
  else ((unsigned short*)outv)[id] = f2bu(m);
}

// ---------- LayerNorm over 256, f32 in -> bf16 out ----------
__global__ __launch_bounds__(256) void k_ln(const float* __restrict__ h,
                                            const float* __restrict__ g,
                                            const float* __restrict__ b2,
                                            unsigned short* __restrict__ out) {
  int lane = threadIdx.x & 63, wid = threadIdx.x >> 6;
  int t = blockIdx.x * 4 + wid;
  float4 v = *(const float4*)(h + (size_t)t * 256 + lane * 4);
  float s = v.x + v.y + v.z + v.w;
  float q = v.x * v.x + v.y * v.y + v.z * v.z + v.w * v.w;
#pragma unroll
  for (int off = 32; off; off >>= 1) {
    s += __shfl_xor(s, off);
    q += __shfl_xor(q, off);
  }
  float mu = s * (1.f / 256.f);
  float var = q * (1.f / 256.f) - mu * mu;
  float rs = rsqrtf(var + EPS);
  float4 gg = *(const float4*)(g + lane * 4);
  float4 bb = *(const float4*)(b2 + lane * 4);
  ushort4 o;
  o.x = f2bu((v.x - mu) * rs * gg.x + bb.x);
  o.y = f2bu((v.y - mu) * rs * gg.y + bb.y);
  o.z = f2bu((v.z - mu) * rs * gg.z + bb.z);
  o.w = f2bu((v.w - mu) * rs * gg.w + bb.w);
  *(ushort4*)(out + (size_t)t * 256 + lane * 4) = o;
}

// ---------- LDS-staged bf16 GEMM (m97 structure): C[M,N] = A[M,K] @ W[N,K]^T ----------
template <int BM, int BN, int KSTEPS, bool ADD>
__global__ __launch_bounds__(256) void k_sgemm(const unsigned short* __restrict__ A,
                                               const unsigned short* __restrict__ W,
                                               float* __restrict__ C,
                                               int N, int ntn) {
  constexpr int K = KSTEPS * 64;
  constexpr int MR = BM / 32;
  constexpr int NR = BN / 32;
  __shared__ __align__(16) unsigned short As[BM * 64];
  __shared__ __align__(16) unsigned short Bs[BN * 64];
  int bm = blockIdx.x / ntn, bn = blockIdx.x - bm * ntn;
  int lane = threadIdx.x & 63, wid = threadIdx.x >> 6;
  int wr = wid >> 1, wc = wid & 1;
  const int arow = lane >> 3, acol = (lane & 7) * 8;
  f32x4 acc[MR][NR] = {};
  const unsigned short* Abase = A + (size_t)(bm * BM) * K;
  const unsigned short* Wbase = W + (size_t)(bn * BN) * K;
  for (int t = 0; t < KSTEPS; ++t) {
    int k0 = t * 64;
#pragma unroll
    for (int i = 0; i < BM / 32; ++i) {
      int chunk = wid * (BM / 32) + i;
      gld16(Abase + (size_t)(chunk * 8 + arow) * K + k0 + acol, &As[chunk * 512 + lane * 8]);
    }
#pragma unroll
    for (int i = 0; i < BN / 32; ++i) {
      int chunk = wid * (BN / 32) + i;
      gld16(Wbase + (size_t)(chunk * 8 + arow) * K + k0 + acol, &Bs[chunk * 512 + lane * 8]);
    }
    __syncthreads();
#pragma unroll
    for (int kk = 0; kk < 2; ++kk) {
      bf16x8 af[MR], bfr[NR];
#pragma unroll
      for (int mi = 0; mi < MR; ++mi)
        af[mi] = *(const bf16x8*)&As[(wr * (BM / 2) + mi * 16 + (lane & 15)) * 64 + kk * 32 + (lane >> 4) * 8];
#pragma unroll
      for (int nj = 0; nj < NR; ++nj)
        bfr[nj] = *(const bf16x8*)&Bs[(wc * (BN / 2) + nj * 16 + (lane & 15)) * 64 + kk * 32 + (lane >> 4) * 8];
#pragma unroll
      for (int mi = 0; mi < MR; ++mi)
#pragma unroll
        for (int nj = 0; nj < NR; ++nj)
          acc[mi][nj] = __builtin_amdgcn_mfma_f32_16x16x32_bf16(af[mi], bfr[nj], acc[mi][nj], 0, 0, 0);
    }
    __syncthreads();
  }
  int rr = (lane >> 4) * 4, rc = lane & 15;
#pragma unroll
  for (int mi = 0; mi < MR; ++mi)
#pragma unroll
    for (int nj = 0; nj < NR; ++nj) {
      int row = bm * BM + wr * (BM / 2) + mi * 16 + rr;
      int col = bn * BN + wc * (BN / 2) + nj * 16 + rc;
#pragma unroll
      for (int r = 0; r < 4; ++r) {
        float v = acc[mi][nj][r];
        if (ADD) v += C[(size_t)(row + r) * N + col];
        C[(size_t)(row + r) * N + col] = v;
      }
    }
}

// ---------- direct bf16 GEMM (small N): C[M,N] = A[M,K] @ W[N,K]^T ----------
template <bool ADD_RES>
__global__ __launch_bounds__(256) void k_gemm(const unsigned short* __restrict__ A,
                                              const unsigned short* __restrict__ W,
                                              float* __restrict__ C, int M, int N,
                                              int K, int ntn) {
  int bm = blockIdx.x / ntn, bn = blockIdx.x - bm * ntn;
  int lane = threadIdx.x & 63, wid = threadIdx.x >> 6;
  int wr = wid >> 1, wc = wid & 1;
  int r0 = bm * 64 + wr * 32 + (lane & 15);
  int c0 = bn * 64 + wc * 32 + (lane & 15);
  int koff = (lane >> 4) << 3;
  int cc0 = (c0 < N) ? c0 : (N - 1);
  int cc1 = (c0 + 16 < N) ? (c0 + 16) : (N - 1);
  const unsigned short* pa0 = A + (size_t)r0 * K + koff;
  const unsigned short* pa1 = A + (size_t)(r0 + 16) * K + koff;
  const unsigned short* pb0 = W + (size_t)cc0 * K + koff;
  const unsigned short* pb1 = W + (size_t)cc1 * K + koff;
  f32x4 acc[2][2] = {};
  for (int k0 = 0; k0 < K; k0 += 32) {
    bf16x8 a0 = *(const bf16x8*)(pa0 + k0);
    bf16x8 a1 = *(const bf16x8*)(pa1 + k0);
    bf16x8 b0 = *(const bf16x8*)(pb0 + k0);
    bf16x8 b1 = *(const bf16x8*)(pb1 + k0);
    acc[0][0] = __builtin_amdgcn_mfma_f32_16x16x32_bf16(a0, b0, acc[0][0], 0, 0, 0);
    acc[0][1] = __builtin_amdgcn_mfma_f32_16x16x32_bf16(a0, b1, acc[0][1], 0, 0, 0);
    acc[1][0] = __builtin_amdgcn_mfma_f32_16x16x32_bf16(a1, b0, acc[1][0], 0, 0, 0);
    acc[1][1] = __builtin_amdgcn_mfma_f32_16x16x32_bf16(a1, b1, acc[1][1], 0, 0, 0);
  }
  int rr = (lane >> 4) * 4, rc = lane & 15;
#pragma unroll
  for (int ti = 0; ti < 2; ++ti)
#pragma unroll
    for (int tj = 0; tj < 2; ++tj) {
      int col = bn * 64 + wc * 32 + tj * 16 + rc;
      if (col >= N) continue;
      int row = bm * 64 + wr * 32 + ti * 16 + rr;
#pragma unroll
      for (int r = 0; r < 4; ++r) {
        float v = acc[ti][tj][r];
        if (ADD_RES) v += C[(size_t)(row + r) * N + col];
        C[(size_t)(row + r) * N + col] = v;
      }
    }
}

// ---------- depthwise causal conv (DC=4) + silu; writes f32 + bf16 ----------
__global__ __launch_bounds__(256) void k_dwconv(const float* __restrict__ xz,
                                                const float* __restrict__ cw,
                                                const float* __restrict__ cb,
                                                float* __restrict__ xc,
                                                unsigned short* __restrict__ xcb) {
  int id = blockIdx.x * 256 + threadIdx.x;  // 6272*512
  int d = id & 511;
  int bl = id >> 9;
  int l = bl % 196;
  int b = bl / 196;
  const float* xi = xz + (size_t)(b * 196) * 1024 + d;
  float4 c4 = *(const float4*)(cw + d * 4);
  float acc = cb[d];
  if (l >= 3) acc = fmaf(xi[(size_t)(l - 3) * 1024], c4.x, acc);
  if (l >= 2) acc = fmaf(xi[(size_t)(l - 2) * 1024], c4.y, acc);
  if (l >= 1) acc = fmaf(xi[(size_t)(l - 1) * 1024], c4.z, acc);
  acc = fmaf(xi[(size_t)l * 1024], c4.w, acc);
  float s = acc / (1.f + __expf(-acc));
  xc[id] = s;
  xcb[id] = f2bu(s);
}

// ---------- dt = softplus(dbl[:, :16] @ w_dt^T + b_dt), transposed weights ----------
__global__ __launch_bounds__(256) void k_dt(const float* __restrict__ dbl,
                                            const float* __restrict__ wt,
                                            const float* __restrict__ bdt,
                                            float* __restrict__ dt) {
  int id = blockIdx.x * 256 + threadIdx.x;  // 6272*512
  int d = id & 511;
  int bl = id >> 9;
  const float4* a = (const float4*)(dbl + (size_t)bl * 144);
  float acc = bdt[d];
#pragma unroll
  for (int i = 0; i < 4; ++i) {
    float4 av = a[i];
    acc = fmaf(av.x, wt[(i * 4 + 0) * 512 + d], acc);
    acc = fmaf(av.y, wt[(i * 4 + 1) * 512 + d], acc);
    acc = fmaf(av.z, wt[(i * 4 + 2) * 512 + d], acc);
    acc = fmaf(av.w, wt[(i * 4 + 3) * 512 + d], acc);
  }
  dt[id] = fmaxf(acc, 0.f) + log1pf(__expf(-fabsf(acc)));
}

// ---------- selective scan: wave per (b,d), lane = state s ----------
__global__ __launch_bounds__(256) void k_scan(
    const float* __restrict__ dtb, const float* __restrict__ xc,
    const float* __restrict__ dbl, const float* __restrict__ xz,
    const float* __restrict__ a_log, const float* __restrict__ d_skip,
    unsigned short* __restrict__ y) {
  __shared__ float lds[4][584];
  int lane = threadIdx.x & 63, wid = threadIdx.x >> 6;
  int wgid = blockIdx.x * 4 + wid;  // 0..16383
  int b = wgid >> 9, d = wgid & 511;
  float A = -__expf(a_log[d * 64 + lane]);
  float dsk = d_skip[d];
  const float* dt_p = dtb + (size_t)(b * 196) * 512 + d;
  const float* xc_p = xc + (size_t)(b * 196) * 512 + d;
  const float* z_p = xz + (size_t)(b * 196) * 1024 + 512 + d;
  const float* bc_p = dbl + (size_t)(b * 196) * 144 + 16 + lane;
  unsigned short* y_p = y + (size_t)(b * 196) * 512 + d;
  float* L = lds[wid];
  float h = 0.f;
  int g = lane >> 3, j = lane & 7;
  for (int l0 = 0; l0 < 196; l0 += 8) {
    float p[8];
#pragma unroll
    for (int li = 0; li < 8; ++li) {
      int l = l0 + li;
      bool ok = (l < 196);
      float dtv = ok ? dt_p[(size_t)l * 512] : 0.f;
      float xv = ok ? xc_p[(size_t)l * 512] : 0.f;
      float Bv = ok ? bc_p[(size_t)l * 144] : 0.f;
      float Cv = ok ? bc_p[(size_t)l * 144 + 64] : 0.f;
      float dA = __expf(dtv * A);
      h = fmaf(dA, h, (dtv * xv) * Bv);
      p[li] = h * Cv;
    }
#pragma unroll
    for (int li = 0; li < 8; ++li) L[lane * 9 + li] = p[li];
    __builtin_amdgcn_wave_barrier();
    float s = 0.f;
#pragma unroll
    for (int k = 0; k < 8; ++k) s += L[(j * 8 + k) * 9 + g];
    __builtin_amdgcn_wave_barrier();
    s += __shfl_xor(s, 1);
    s += __shfl_xor(s, 2);
    s += __shfl_xor(s, 4);
    int l = l0 + g;
    if (j == 0 && l < 196) {
      float xv = xc_p[(size_t)l * 512];
      float zv = z_p[(size_t)l * 1024];
      float sig = 1.f / (1.f + __expf(-zv));
      y_p[(size_t)l * 512] = f2bu((s + dsk * xv) * (zv * sig));
    }
  }
}

// ---------- head: partial mean (4 chunks of 49 rows) then fused reduce+FC ----------
__global__ __launch_bounds__(256) void k_mean2(const float* __restrict__ h,
                                               float* __restrict__ part) {
  int b = blockIdx.x >> 2, q = blockIdx.x & 3;
  int e = threadIdx.x;
  const float* hb = h + ((size_t)b * 196 + q * 49) * 256 + e;
  float s = 0.f;
  for (int l = 0; l < 49; ++l) s += hb[(size_t)l * 256];
  part[((size_t)b * 4 + q) * 256 + e] = s;
}

__global__ __launch_bounds__(256) void k_head(const float* __restrict__ part,
                                              const float* __restrict__ fw,
                                              const float* __restrict__ fb,
                                              float* __restrict__ out) {
  __shared__ float sp[256];
  int b = blockIdx.x;
  int tid = threadIdx.x, lane = tid & 63, w = tid >> 6;
  const float* pb = part + (size_t)b * 4 * 256;
  sp[tid] = (pb[tid] + pb[256 + tid] + pb[512 + tid] + pb[768 + tid]) * (1.f / 196.f);
  __syncthreads();
  // wave w handles outputs n = w, w+4, w+8 (n < 10)
  for (int n = w; n < 10; n += 4) {
    float s = 0.f;
#pragma unroll
    for (int i = 0; i < 4; ++i) {
      int e = lane * 4 + i;
      e = e & 255;
      s += sp[e] * fw[n * 256 + e];
    }
    s += __shfl_xor(s, 1); s += __shfl_xor(s, 2); s += __shfl_xor(s, 4);
    s += __shfl_xor(s, 8); s += __shfl_xor(s, 16); s += __shfl_xor(s, 32);
    if (lane == 0) out[b * 10 + n] = s + fb[n];
  }
}

// ---------- launcher ----------
static inline unsigned cdiv(unsigned a, unsigned b) { return (a + b - 1) / b; }

extern "C" void kernel_launch(void* const* d_in, const int* in_sizes, int n_in,
                              void* d_out, int out_size, void* d_ws, size_t ws_size,
                              hipStream_t stream) {
  const float* x = (const float*)d_in[0];
  const float* c1w = (const float*)d_in[1]; const float* c1b = (const float*)d_in[2];
  const float* b1g = (const float*)d_in[3]; const float* b1b = (const float*)d_in[4];
  const float* b1m = (const float*)d_in[5]; const float* b1v = (const float*)d_in[6];
  const float* c2w = (const float*)d_in[7]; const float* c2b = (const float*)d_in[8];
  const float* b2g = (const float*)d_in[9]; const float* b2b = (const float*)d_in[10];
  const float* b2m = (const float*)d_in[11]; const float* b2v = (const float*)d_in[12];
  const float* c3w = (const float*)d_in[13]; const float* c3b = (const float*)d_in[14];
  const float* b3g = (const float*)d_in[15]; const float* b3b = (const float*)d_in[16];
  const float* b3m = (const float*)d_in[17]; const float* b3v = (const float*)d_in[18];
  const float* ln_g = (const float*)d_in[19]; const float* ln_b = (const float*)d_in[20];
  const float* w_in = (const float*)d_in[21];
  const float* cw = (const float*)d_in[22]; const float* cbv = (const float*)d_in[23];
  const float* w_x = (const float*)d_in[24];
  const float* w_dt = (const float*)d_in[25]; const float* b_dt = (const float*)d_in[26];
  const float* a_log = (const float*)d_in[27]; const float* d_skip = (const float*)d_in[28];
  const float* w_out = (const float*)d_in[29];
  const float* fc_w = (const float*)d_in[30]; const float* fc_b = (const float*)d_in[31];

  char* ws = (char*)d_ws;
  size_t off = 0;
  auto take = [&](size_t bytes) { size_t o = off; off += bytes; return o; };
  // scratch region S: stem buffers (phase 1) union mamba buffers (phase 2)
  size_t S = take(67837952);
  // stem phase 1: conv1a output + pooled t1
  unsigned short* c1o = (unsigned short*)(ws + S + 0);          // 51.38 MB
  unsigned short* t1 = (unsigned short*)(ws + S + 51380224);    // 12.85 MB
  // stem phase 2 (c1o dead once t1 is written)
  unsigned short* t2 = (unsigned short*)(ws + S + 0);           // 25.69 MB
  unsigned short* t3 = (unsigned short*)(ws + S + 25690112);    // 6.42 MB
  unsigned short* t4 = (unsigned short*)(ws + S + 32112640);    // 12.85 MB
  // mamba phase (stem buffers dead)
  float* xz = (float*)(ws + S + 0);
  float* xc = (float*)(ws + S + 25690112);
  unsigned short* xcb = (unsigned short*)(ws + S + 38535168);
  float* dbl = (float*)(ws + S + 44957696);
  float* dtb = (float*)(ws + S + 48570368);
  unsigned short* ybf = (unsigned short*)(ws + S + 61415424);
  float* h = (float*)(ws + take(6422528));
  unsigned short* hbf = (unsigned short*)(ws + take(3211264));
  unsigned short* w_in_bf = (unsigned short*)(ws + take(3145728));
  unsigned short* w_x_bf = (unsigned short*)(ws + take(884736));
  unsigned short* w_out_bf = (unsigned short*)(ws + take(1572864));
  unsigned short* w2p = (unsigned short*)(ws + take(147456));
  unsigned short* w3p = (unsigned short*)(ws + take(589824));
  float* wdt_t = (float*)(ws + take(196608));
  float* part = (float*)(ws + take(131072));
  (void)ws_size; (void)in_sizes; (void)n_in; (void)out_size;

  // fused weight conversion / repack / transpose (3219456 elems = 12576 * 256)
  k_prep<<<12576, 256, 0, stream>>>(w_in, w_in_bf, w_x, w_x_bf, w_out, w_out_bf,
                                    c2w, w2p, c3w, w3p, w_dt, wdt_t);

  // stem
  k_conv1a<<<3584, 256, 0, stream>>>(x, c1w, c1b, b1g, b1b, b1m, b1v, c1o);
  k_pool3<<<25088, 256, 0, stream>>>(c1o, t1);
  k_convgemm<56, 56, 64, 128><<<1568 * 2, 256, 0, stream>>>(t1, w2p, c2b, b2g, b2b, b2m, b2v, t2);
  k_pool<56, 56, 128, false><<<12544, 256, 0, stream>>>(t2, t3);
  k_convgemm<28, 28, 128, 256><<<392 * 4, 256, 0, stream>>>(t3, w3p, c3b, b3g, b3b, b3m, b3v, t4);
  k_pool<28, 28, 256, true><<<6272, 256, 0, stream>>>(t4, h);

  // mamba blocks
  for (int blk = 0; blk < 6; ++blk) {
    k_ln<<<1568, 256, 0, stream>>>(h, ln_g + blk * 256, ln_b + blk * 256, hbf);
    k_sgemm<128, 128, 4, false><<<49 * 8, 256, 0, stream>>>(
        hbf, w_in_bf + (size_t)blk * 1024 * 256, xz, 1024, 8);
    k_dwconv<<<12544, 256, 0, stream>>>(xz, cw + blk * 512 * 4, cbv + blk * 512, xc, xcb);
    k_gemm<false><<<98 * 3, 256, 0, stream>>>(xcb, w_x_bf + (size_t)blk * 144 * 512, dbl,
                                              6272, 144, 512, 3);
    k_dt<<<12544, 256, 0, stream>>>(dbl, wdt_t + blk * 8192, b_dt + blk * 512, dtb);
    k_scan<<<4096, 256, 0, stream>>>(dtb, xc, dbl, xz, a_log + blk * 512 * 64,
                                     d_skip + blk * 512, ybf);
    k_sgemm<64, 64, 8, true><<<98 * 4, 256, 0, stream>>>(
        ybf, w_out_bf + (size_t)blk * 256 * 512, h, 256, 4);
  }

  // head
  k_mean2<<<128, 256, 0, stream>>>(h, part);
  k_head<<<32, 256, 0, stream>>>(part, fc_w, fc_b, (float*)d_out);
}

// Round 9
// 1652.439 us; speedup vs baseline: 1.5240x; 1.0710x over previous
//
#include <hip/hip_runtime.h>

// ---------- types ----------
typedef __bf16 bf16x8 __attribute__((ext_vector_type(8)));
typedef float f32x4 __attribute__((ext_vector_type(4)));

#define EPS 1e-5f

__device__ __forceinline__ unsigned short f2bu(float f) {
  union { float f; unsigned u; } x; x.f = f;
  unsigned r = x.u + 0x7fffu + ((x.u >> 16) & 1u);  // RNE
  return (unsigned short)(r >> 16);
}
__device__ __forceinline__ float bu2f(unsigned short u) {
  union { unsigned u; float f; } x; x.u = ((unsigned)u) << 16;
  return x.f;
}

__device__ __forceinline__ void gld16(const void* g, void* l) {
  __builtin_amdgcn_global_load_lds((const __attribute__((address_space(1))) void*)g,
                                   (__attribute__((address_space(3))) void*)l, 16, 0, 0);
}

// ---------- fused prep: f2b (w_in,w_x,w_out) + conv repacks + w_dt transpose ----------
__global__ __launch_bounds__(256) void k_prep(
    const float* __restrict__ w_in, unsigned short* __restrict__ w_in_bf,
    const float* __restrict__ w_x, unsigned short* __restrict__ w_x_bf,
    const float* __restrict__ w_out, unsigned short* __restrict__ w_out_bf,
    const float* __restrict__ c2w, unsigned short* __restrict__ w2p,
    const float* __restrict__ c3w, unsigned short* __restrict__ w3p,
    const float* __restrict__ w_dt, float* __restrict__ wdt_t) {
  int id = blockIdx.x * 256 + threadIdx.x;
  if (id < 1572864) { w_in_bf[id] = f2bu(w_in[id]); return; }
  id -= 1572864;
  if (id < 442368) { w_x_bf[id] = f2bu(w_x[id]); return; }
  id -= 442368;
  if (id < 786432) { w_out_bf[id] = f2bu(w_out[id]); return; }
  id -= 786432;
  if (id < 73728) {  // repack CI=64
    int ci = id % 64, tap = (id / 64) % 9, co = id / 576;
    w2p[id] = f2bu(c2w[(co * 64 + ci) * 9 + tap]);
    return;
  }
  id -= 73728;
  if (id < 294912) {  // repack CI=128
    int ci = id % 128, tap = (id / 128) % 9, co = id / 1152;
    w3p[id] = f2bu(c3w[(co * 128 + ci) * 9 + tap]);
    return;
  }
  id -= 294912;
  {  // w_dt transpose (6*16*512)
    int d = id & 511, r = (id >> 9) & 15, blk = id >> 13;
    wdt_t[id] = w_dt[(blk * 512 + d) * 16 + r];
  }
}

// ---------- conv1 pass A v4: block = (b,oy) row; LDS-staged x window; ----------
// thread = (channel, ox-group of 28); broadcast ds_read_b128 x; zero-pad edges.
__global__ __launch_bounds__(256) void k_conv1a(
    const float* __restrict__ x, const float* __restrict__ w,
    const float* __restrict__ cb, const float* __restrict__ g,
    const float* __restrict__ bb, const float* __restrict__ bm_,
    const float* __restrict__ bv, unsigned short* __restrict__ out) {
  __shared__ __align__(16) float sx[9][228];  // [ci*3+ky][1+ix], zero-padded
  __shared__ float sw[64 * 27];
  __shared__ float sa[64], sb[64];
  int tid = threadIdx.x;
  int oy = blockIdx.x % 112, b = blockIdx.x / 112;
  // stage input rows (zero-filled outside [0,224))
  for (int i = tid; i < 9 * 228; i += 256) {
    int row = i / 228;
    int ixl = i - row * 228;
    int ci = row / 3, ky = row - ci * 3;
    int iy = 2 * oy - 1 + ky;
    int ix = ixl - 1;
    float v = 0.f;
    if ((unsigned)iy < 224u && (unsigned)ix < 224u)
      v = x[((size_t)(b * 3 + ci) * 224 + iy) * 224 + ix];
    sx[row][ixl] = v;
  }
  // stage weights + folded BN
  for (int i = tid; i < 64 * 27; i += 256) sw[i] = w[i];
  if (tid < 64) {
    int c = tid;
    float alpha = g[c] * rsqrtf(bv[c] + EPS);
    sa[c] = alpha;
    sb[c] = (cb[c] - bm_[c]) * alpha + bb[c];
  }
  __syncthreads();
  int c = tid & 63, grp = tid >> 6;  // 4 groups x 28 pixels
  int ox0 = grp * 28;
  float acc[28];
#pragma unroll
  for (int i = 0; i < 28; ++i) acc[i] = 0.f;
#pragma unroll
  for (int ci = 0; ci < 3; ++ci) {
    float wr[9];
#pragma unroll
    for (int j = 0; j < 9; ++j) wr[j] = sw[c * 27 + ci * 9 + j];
#pragma unroll
    for (int ky = 0; ky < 3; ++ky) {
      const float* row = sx[ci * 3 + ky];
#pragma unroll
      for (int q = 0; q < 7; ++q) {
        int base = 2 * (ox0 + q * 4);  // 16B-aligned
        f32x4 a0 = *(const f32x4*)&row[base];
        f32x4 a1 = *(const f32x4*)&row[base + 4];
        f32x4 a2 = *(const f32x4*)&row[base + 8];
        float xv[12] = {a0[0], a0[1], a0[2], a0[3], a1[0], a1[1],
                        a1[2], a1[3], a2[0], a2[1], a2[2], a2[3]};
#pragma unroll
        for (int p = 0; p < 4; ++p) {
          acc[q * 4 + p] = fmaf(xv[2 * p + 0], wr[ky * 3 + 0], acc[q * 4 + p]);
          acc[q * 4 + p] = fmaf(xv[2 * p + 1], wr[ky * 3 + 1], acc[q * 4 + p]);
          acc[q * 4 + p] = fmaf(xv[2 * p + 2], wr[ky * 3 + 2], acc[q * 4 + p]);
        }
      }
    }
  }
  float alpha = sa[c], beta = sb[c];
  unsigned short* op = out + (((size_t)(b * 112 + oy)) * 112 + ox0) * 64 + c;
#pragma unroll
  for (int p = 0; p < 28; ++p)
    op[(size_t)p * 64] = f2bu(fmaxf(acc[p] * alpha + beta, 0.f));
}

// ---------- conv1 pass B: 3x3 s2 p1 maxpool on NHWC bf16 (values >= 0) ----------
__global__ __launch_bounds__(256) void k_pool3(const unsigned short* __restrict__ in,
                                               unsigned short* __restrict__ out) {
  int id = blockIdx.x * 256 + threadIdx.x;  // ((b*56+py)*56+px)*64 + c
  int c = id & 63;
  int t = id >> 6;
  int px = t % 56; t /= 56;
  int py = t % 56;
  int b = t / 56;
  float m = 0.f;  // inputs are post-ReLU (>= 0)
#pragma unroll
  for (int ky = 0; ky < 3; ++ky) {
    int iy = py * 2 - 1 + ky;
    if ((unsigned)iy >= 112u) continue;
#pragma unroll
    for (int kx = 0; kx < 3; ++kx) {
      int ix = px * 2 - 1 + kx;
      if ((unsigned)ix >= 112u) continue;
      m = fmaxf(m, bu2f(in[(((size_t)(b * 112 + iy) * 112) + ix) * 64 + c]));
    }
  }
  out[id] = f2bu(m);
}

// ---------- implicit-GEMM 3x3 s1 p1 conv, NHWC bf16 in/out, BN+ReLU epilogue ----------
template <int H, int Wd, int CI, int CO>
__global__ __launch_bounds__(256) void k_convgemm(
    const unsigned short* __restrict__ In, const unsigned short* __restrict__ Wt,
    const float* __restrict__ cb, const float* __restrict__ g,
    const float* __restrict__ bb, const float* __restrict__ bm_,
    const float* __restrict__ bv, unsigned short* __restrict__ Out) {
  constexpr int K = 9 * CI;
  constexpr int NTN = CO / 64;
  int bm = blockIdx.x / NTN, bn = blockIdx.x - bm * NTN;
  int lane = threadIdx.x & 63, wid = threadIdx.x >> 6;
  int wr = wid >> 1, wc = wid & 1;
  int r0 = bm * 64 + wr * 32 + (lane & 15);
  int r1 = r0 + 16;
  int c0 = bn * 64 + wc * 32 + (lane & 15);
  int koff = (lane >> 4) << 3;
  int ox0 = r0 % Wd; int t0 = r0 / Wd; int oy0 = t0 % H; int b0 = t0 / H;
  int ox1 = r1 % Wd; int t1 = r1 / Wd; int oy1 = t1 % H; int b1 = t1 / H;
  const unsigned short* pb0 = Wt + (size_t)c0 * K + koff;
  const unsigned short* pb1 = Wt + (size_t)(c0 + 16) * K + koff;
  f32x4 acc[2][2] = {};
  for (int k0 = 0; k0 < K; k0 += 32) {
    int k = k0 + koff;
    int tap = k / CI;
    int ci = k - tap * CI;
    int ky = tap / 3, kx = tap - ky * 3;
    int iy0 = oy0 + ky - 1, ix0 = ox0 + kx - 1;
    int iy1 = oy1 + ky - 1, ix1 = ox1 + kx - 1;
    bf16x8 a0 = {};
    bf16x8 a1 = {};
    if ((unsigned)iy0 < (unsigned)H && (unsigned)ix0 < (unsigned)Wd)
      a0 = *(const bf16x8*)(In + ((size_t)((b0 * H + iy0) * Wd + ix0)) * CI + ci);
    if ((unsigned)iy1 < (unsigned)H && (unsigned)ix1 < (unsigned)Wd)
      a1 = *(const bf16x8*)(In + ((size_t)((b1 * H + iy1) * Wd + ix1)) * CI + ci);
    bf16x8 w0 = *(const bf16x8*)(pb0 + k0);
    bf16x8 w1 = *(const bf16x8*)(pb1 + k0);
    acc[0][0] = __builtin_amdgcn_mfma_f32_16x16x32_bf16(a0, w0, acc[0][0], 0, 0, 0);
    acc[0][1] = __builtin_amdgcn_mfma_f32_16x16x32_bf16(a0, w1, acc[0][1], 0, 0, 0);
    acc[1][0] = __builtin_amdgcn_mfma_f32_16x16x32_bf16(a1, w0, acc[1][0], 0, 0, 0);
    acc[1][1] = __builtin_amdgcn_mfma_f32_16x16x32_bf16(a1, w1, acc[1][1], 0, 0, 0);
  }
  int rr = (lane >> 4) * 4, rc = lane & 15;
#pragma unroll
  for (int tj = 0; tj < 2; ++tj) {
    int col = bn * 64 + wc * 32 + tj * 16 + rc;
    float alpha = g[col] * rsqrtf(bv[col] + EPS);
    float beta = (cb[col] - bm_[col]) * alpha + bb[col];
#pragma unroll
    for (int ti = 0; ti < 2; ++ti) {
      int row = bm * 64 + wr * 32 + ti * 16 + rr;
#pragma unroll
      for (int r = 0; r < 4; ++r) {
        float v = fmaxf(acc[ti][tj][r] * alpha + beta, 0.f);
        Out[(size_t)(row + r) * CO + col] = f2bu(v);
      }
    }
  }
}

// ---------- NHWC 2x2/2 maxpool, bf16 in, bf16 or f32 out ----------
template <int H, int Wd, int C, bool OUTF>
__global__ __launch_bounds__(256) void k_pool(const unsigned short* __restrict__ in,
                                              void* __restrict__ outv) {
  constexpr int OH = H / 2, OW = Wd / 2;
  int id = blockIdx.x * 256 + threadIdx.x;  // 32*OH*OW*C exact
  int c = id % C;
  int t = id / C;
  int px = t % OW; t /= OW;
  int py = t % OH;
  int b = t / OH;
  const unsigned short* p = in + (((size_t)(b * H + py * 2) * Wd) + px * 2) * C + c;
  float m0 = bu2f(p[0]), m1 = bu2f(p[C]);
  float m2 = bu2f(p[(size_t)Wd * C]), m3 = bu2f(p[(size_t)Wd * C + C]);
  float m = fmaxf(fmaxf(m0, m1), fmaxf(m2, m3));
  if (OUTF) ((float*)outv)[id] = m;
  else ((unsigned short*)outv)[id] = f2bu(m);
}

// ---------- LayerNorm over 256, f32 in -> bf16 out ----------
__global__ __launch_bounds__(256) void k_ln(const float* __restrict__ h,
                                            const float* __restrict__ g,
                                            const float* __restrict__ b2,
                                            unsigned short* __restrict__ out) {
  int lane = threadIdx.x & 63, wid = threadIdx.x >> 6;
  int t = blockIdx.x * 4 + wid;
  float4 v = *(const float4*)(h + (size_t)t * 256 + lane * 4);
  float s = v.x + v.y + v.z + v.w;
  float q = v.x * v.x + v.y * v.y + v.z * v.z + v.w * v.w;
#pragma unroll
  for (int off = 32; off; off >>= 1) {
    s += __shfl_xor(s, off);
    q += __shfl_xor(q, off);
  }
  float mu = s * (1.f / 256.f);
  float var = q * (1.f / 256.f) - mu * mu;
  float rs = rsqrtf(var + EPS);
  float4 gg = *(const float4*)(g + lane * 4);
  float4 bb = *(const float4*)(b2 + lane * 4);
  ushort4 o;
  o.x = f2bu((v.x - mu) * rs * gg.x + bb.x);
  o.y = f2bu((v.y - mu) * rs * gg.y + bb.y);
  o.z = f2bu((v.z - mu) * rs * gg.z + bb.z);
  o.w = f2bu((v.w - mu) * rs * gg.w + bb.w);
  *(ushort4*)(out + (size_t)t * 256 + lane * 4) = o;
}

// ---------- LDS-staged bf16 GEMM (m97 structure): C[M,N] = A[M,K] @ W[N,K]^T ----------
template <int BM, int BN, int KSTEPS, bool ADD>
__global__ __launch_bounds__(256) void k_sgemm(const unsigned short* __restrict__ A,
                                               const unsigned short* __restrict__ W,
                                               float* __restrict__ C,
                                               int N, int ntn) {
  constexpr int K = KSTEPS * 64;
  constexpr int MR = BM / 32;
  constexpr int NR = BN / 32;
  __shared__ __align__(16) unsigned short As[BM * 64];
  __shared__ __align__(16) unsigned short Bs[BN * 64];
  int bm = blockIdx.x / ntn, bn = blockIdx.x - bm * ntn;
  int lane = threadIdx.x & 63, wid = threadIdx.x >> 6;
  int wr = wid >> 1, wc = wid & 1;
  const int arow = lane >> 3, acol = (lane & 7) * 8;
  f32x4 acc[MR][NR] = {};
  const unsigned short* Abase = A + (size_t)(bm * BM) * K;
  const unsigned short* Wbase = W + (size_t)(bn * BN) * K;
  for (int t = 0; t < KSTEPS; ++t) {
    int k0 = t * 64;
#pragma unroll
    for (int i = 0; i < BM / 32; ++i) {
      int chunk = wid * (BM / 32) + i;
      gld16(Abase + (size_t)(chunk * 8 + arow) * K + k0 + acol, &As[chunk * 512 + lane * 8]);
    }
#pragma unroll
    for (int i = 0; i < BN / 32; ++i) {
      int chunk = wid * (BN / 32) + i;
      gld16(Wbase + (size_t)(chunk * 8 + arow) * K + k0 + acol, &Bs[chunk * 512 + lane * 8]);
    }
    __syncthreads();
#pragma unroll
    for (int kk = 0; kk < 2; ++kk) {
      bf16x8 af[MR], bfr[NR];
#pragma unroll
      for (int mi = 0; mi < MR; ++mi)
        af[mi] = *(const bf16x8*)&As[(wr * (BM / 2) + mi * 16 + (lane & 15)) * 64 + kk * 32 + (lane >> 4) * 8];
#pragma unroll
      for (int nj = 0; nj < NR; ++nj)
        bfr[nj] = *(const bf16x8*)&Bs[(wc * (BN / 2) + nj * 16 + (lane & 15)) * 64 + kk * 32 + (lane >> 4) * 8];
#pragma unroll
      for (int mi = 0; mi < MR; ++mi)
#pragma unroll
        for (int nj = 0; nj < NR; ++nj)
          acc[mi][nj] = __builtin_amdgcn_mfma_f32_16x16x32_bf16(af[mi], bfr[nj], acc[mi][nj], 0, 0, 0);
    }
    __syncthreads();
  }
  int rr = (lane >> 4) * 4, rc = lane & 15;
#pragma unroll
  for (int mi = 0; mi < MR; ++mi)
#pragma unroll
    for (int nj = 0; nj < NR; ++nj) {
      int row = bm * BM + wr * (BM / 2) + mi * 16 + rr;
      int col = bn * BN + wc * (BN / 2) + nj * 16 + rc;
#pragma unroll
      for (int r = 0; r < 4; ++r) {
        float v = acc[mi][nj][r];
        if (ADD) v += C[(size_t)(row + r) * N + col];
        C[(size_t)(row + r) * N + col] = v;
      }
    }
}

// ---------- direct bf16 GEMM (small N): C[M,N] = A[M,K] @ W[N,K]^T ----------
template <bool ADD_RES>
__global__ __launch_bounds__(256) void k_gemm(const unsigned short* __restrict__ A,
                                              const unsigned short* __restrict__ W,
                                              float* __restrict__ C, int M, int N,
                                              int K, int ntn) {
  int bm = blockIdx.x / ntn, bn = blockIdx.x - bm * ntn;
  int lane = threadIdx.x & 63, wid = threadIdx.x >> 6;
  int wr = wid >> 1, wc = wid & 1;
  int r0 = bm * 64 + wr * 32 + (lane & 15);
  int c0 = bn * 64 + wc * 32 + (lane & 15);
  int koff = (lane >> 4) << 3;
  int cc0 = (c0 < N) ? c0 : (N - 1);
  int cc1 = (c0 + 16 < N) ? (c0 + 16) : (N - 1);
  const unsigned short* pa0 = A + (size_t)r0 * K + koff;
  const unsigned short* pa1 = A + (size_t)(r0 + 16) * K + koff;
  const unsigned short* pb0 = W + (size_t)cc0 * K + koff;
  const unsigned short* pb1 = W + (size_t)cc1 * K + koff;
  f32x4 acc[2][2] = {};
  for (int k0 = 0; k0 < K; k0 += 32) {
    bf16x8 a0 = *(const bf16x8*)(pa0 + k0);
    bf16x8 a1 = *(const bf16x8*)(pa1 + k0);
    bf16x8 b0 = *(const bf16x8*)(pb0 + k0);
    bf16x8 b1 = *(const bf16x8*)(pb1 + k0);
    acc[0][0] = __builtin_amdgcn_mfma_f32_16x16x32_bf16(a0, b0, acc[0][0], 0, 0, 0);
    acc[0][1] = __builtin_amdgcn_mfma_f32_16x16x32_bf16(a0, b1, acc[0][1], 0, 0, 0);
    acc[1][0] = __builtin_amdgcn_mfma_f32_16x16x32_bf16(a1, b0, acc[1][0], 0, 0, 0);
    acc[1][1] = __builtin_amdgcn_mfma_f32_16x16x32_bf16(a1, b1, acc[1][1], 0, 0, 0);
  }
  int rr = (lane >> 4) * 4, rc = lane & 15;
#pragma unroll
  for (int ti = 0; ti < 2; ++ti)
#pragma unroll
    for (int tj = 0; tj < 2; ++tj) {
      int col = bn * 64 + wc * 32 + tj * 16 + rc;
      if (col >= N) continue;
      int row = bm * 64 + wr * 32 + ti * 16 + rr;
#pragma unroll
      for (int r = 0; r < 4; ++r) {
        float v = acc[ti][tj][r];
        if (ADD_RES) v += C[(size_t)(row + r) * N + col];
        C[(size_t)(row + r) * N + col] = v;
      }
    }
}

// ---------- depthwise causal conv (DC=4) + silu; writes f32 + bf16 ----------
__global__ __launch_bounds__(256) void k_dwconv(const float* __restrict__ xz,
                                                const float* __restrict__ cw,
                                                const float* __restrict__ cb,
                                                float* __restrict__ xc,
                                                unsigned short* __restrict__ xcb) {
  int id = blockIdx.x * 256 + threadIdx.x;  // 6272*512
  int d = id & 511;
  int bl = id >> 9;
  int l = bl % 196;
  int b = bl / 196;
  const float* xi = xz + (size_t)(b * 196) * 1024 + d;
  float4 c4 = *(const float4*)(cw + d * 4);
  float acc = cb[d];
  if (l >= 3) acc = fmaf(xi[(size_t)(l - 3) * 1024], c4.x, acc);
  if (l >= 2) acc = fmaf(xi[(size_t)(l - 2) * 1024], c4.y, acc);
  if (l >= 1) acc = fmaf(xi[(size_t)(l - 1) * 1024], c4.z, acc);
  acc = fmaf(xi[(size_t)l * 1024], c4.w, acc);
  float s = acc / (1.f + __expf(-acc));
  xc[id] = s;
  xcb[id] = f2bu(s);
}

// ---------- dt = softplus(dbl[:, :16] @ w_dt^T + b_dt), transposed weights ----------
__global__ __launch_bounds__(256) void k_dt(const float* __restrict__ dbl,
                                            const float* __restrict__ wt,
                                            const float* __restrict__ bdt,
                                            float* __restrict__ dt) {
  int id = blockIdx.x * 256 + threadIdx.x;  // 6272*512
  int d = id & 511;
  int bl = id >> 9;
  const float4* a = (const float4*)(dbl + (size_t)bl * 144);
  float acc = bdt[d];
#pragma unroll
  for (int i = 0; i < 4; ++i) {
    float4 av = a[i];
    acc = fmaf(av.x, wt[(i * 4 + 0) * 512 + d], acc);
    acc = fmaf(av.y, wt[(i * 4 + 1) * 512 + d], acc);
    acc = fmaf(av.z, wt[(i * 4 + 2) * 512 + d], acc);
    acc = fmaf(av.w, wt[(i * 4 + 3) * 512 + d], acc);
  }
  dt[id] = fmaxf(acc, 0.f) + log1pf(__expf(-fabsf(acc)));
}

// ---------- selective scan v2: XCD-swizzled, unguarded main tiles ----------
__global__ __launch_bounds__(256) void k_scan(
    const float* __restrict__ dtb, const float* __restrict__ xc,
    const float* __restrict__ dbl, const float* __restrict__ xz,
    const float* __restrict__ a_log, const float* __restrict__ d_skip,
    unsigned short* __restrict__ y) {
  __shared__ float lds[4][584];
  int lane = threadIdx.x & 63, wid = threadIdx.x >> 6;
  // XCD-bijective swizzle: XCD x (= bid%8) owns 4 complete b's -> dt/xc/z
  // cachelines (shared by 16 neighboring-d waves) stay in one XCD's L2.
  int bid = blockIdx.x;                       // 4096 blocks
  int nbid = (bid & 7) * 512 + (bid >> 3);    // bijective [0,4096)
  int wgid = nbid * 4 + wid;                  // 0..16383
  int b = wgid >> 9, d = wgid & 511;
  float A = -__expf(a_log[d * 64 + lane]);
  float dsk = d_skip[d];
  const float* dt_p = dtb + (size_t)(b * 196) * 512 + d;
  const float* xc_p = xc + (size_t)(b * 196) * 512 + d;
  const float* z_p = xz + (size_t)(b * 196) * 1024 + 512 + d;
  const float* bc_p = dbl + (size_t)(b * 196) * 144 + 16 + lane;
  unsigned short* y_p = y + (size_t)(b * 196) * 512 + d;
  float* L = lds[wid];
  float h = 0.f;
  int g = lane >> 3, j = lane & 7;
  const float* dt_c = dt_p;
  const float* xc_c = xc_p;
  const float* bc_c = bc_p;
  // 24 unguarded tiles of 8 steps (l = 0..191)
  for (int t = 0; t < 24; ++t) {
    int l0 = t * 8;
    float p[8];
#pragma unroll
    for (int li = 0; li < 8; ++li) {
      float dtv = dt_c[li * 512];
      float xv = xc_c[li * 512];
      float Bv = bc_c[li * 144];
      float Cv = bc_c[li * 144 + 64];
      float dA = __expf(dtv * A);
      h = fmaf(dA, h, (dtv * xv) * Bv);
      p[li] = h * Cv;
    }
#pragma unroll
    for (int li = 0; li < 8; ++li) L[lane * 9 + li] = p[li];
    __builtin_amdgcn_wave_barrier();
    float s = 0.f;
#pragma unroll
    for (int k = 0; k < 8; ++k) s += L[(j * 8 + k) * 9 + g];
    __builtin_amdgcn_wave_barrier();
    s += __shfl_xor(s, 1);
    s += __shfl_xor(s, 2);
    s += __shfl_xor(s, 4);
    if (j == 0) {
      int l = l0 + g;
      float xv = xc_p[(size_t)l * 512];
      float zv = z_p[(size_t)l * 1024];
      float sig = 1.f / (1.f + __expf(-zv));
      y_p[(size_t)l * 512] = f2bu((s + dsk * xv) * (zv * sig));
    }
    dt_c += 8 * 512;
    xc_c += 8 * 512;
    bc_c += 8 * 144;
  }
  // tail tile: l = 192..195 (4 valid steps)
  {
    float p[8];
#pragma unroll
    for (int li = 0; li < 8; ++li) {
      bool ok = (li < 4);
      float dtv = ok ? dt_c[li * 512] : 0.f;
      float xv = ok ? xc_c[li * 512] : 0.f;
      float Bv = ok ? bc_c[li * 144] : 0.f;
      float Cv = ok ? bc_c[li * 144 + 64] : 0.f;
      float dA = __expf(dtv * A);
      h = fmaf(dA, h, (dtv * xv) * Bv);
      p[li] = h * Cv;
    }
#pragma unroll
    for (int li = 0; li < 8; ++li) L[lane * 9 + li] = p[li];
    __builtin_amdgcn_wave_barrier();
    float s = 0.f;
#pragma unroll
    for (int k = 0; k < 8; ++k) s += L[(j * 8 + k) * 9 + g];
    __builtin_amdgcn_wave_barrier();
    s += __shfl_xor(s, 1);
    s += __shfl_xor(s, 2);
    s += __shfl_xor(s, 4);
    int l = 192 + g;
    if (j == 0 && l < 196) {
      float xv = xc_p[(size_t)l * 512];
      float zv = z_p[(size_t)l * 1024];
      float sig = 1.f / (1.f + __expf(-zv));
      y_p[(size_t)l * 512] = f2bu((s + dsk * xv) * (zv * sig));
    }
  }
}

// ---------- head: partial mean (4 chunks of 49 rows) then fused reduce+FC ----------
__global__ __launch_bounds__(256) void k_mean2(const float* __restrict__ h,
                                               float* __restrict__ part) {
  int b = blockIdx.x >> 2, q = blockIdx.x & 3;
  int e = threadIdx.x;
  const float* hb = h + ((size_t)b * 196 + q * 49) * 256 + e;
  float s = 0.f;
  for (int l = 0; l < 49; ++l) s += hb[(size_t)l * 256];
  part[((size_t)b * 4 + q) * 256 + e] = s;
}

__global__ __launch_bounds__(256) void k_head(const float* __restrict__ part,
                                              const float* __restrict__ fw,
                                              const float* __restrict__ fb,
                                              float* __restrict__ out) {
  __shared__ float sp[256];
  int b = blockIdx.x;
  int tid = threadIdx.x, lane = tid & 63, w = tid >> 6;
  const float* pb = part + (size_t)b * 4 * 256;
  sp[tid] = (pb[tid] + pb[256 + tid] + pb[512 + tid] + pb[768 + tid]) * (1.f / 196.f);
  __syncthreads();
  // wave w handles outputs n = w, w+4, w+8 (n < 10)
  for (int n = w; n < 10; n += 4) {
    float s = 0.f;
#pragma unroll
    for (int i = 0; i < 4; ++i) {
      int e = lane * 4 + i;
      e = e & 255;
      s += sp[e] * fw[n * 256 + e];
    }
    s += __shfl_xor(s, 1); s += __shfl_xor(s, 2); s += __shfl_xor(s, 4);
    s += __shfl_xor(s, 8); s += __shfl_xor(s, 16); s += __shfl_xor(s, 32);
    if (lane == 0) out[b * 10 + n] = s + fb[n];
  }
}

// ---------- launcher ----------
static inline unsigned cdiv(unsigned a, unsigned b) { return (a + b - 1) / b; }

extern "C" void kernel_launch(void* const* d_in, const int* in_sizes, int n_in,
                              void* d_out, int out_size, void* d_ws, size_t ws_size,
                              hipStream_t stream) {
  const float* x = (const float*)d_in[0];
  const float* c1w = (const float*)d_in[1]; const float* c1b = (const float*)d_in[2];
  const float* b1g = (const float*)d_in[3]; const float* b1b = (const float*)d_in[4];
  const float* b1m = (const float*)d_in[5]; const float* b1v = (const float*)d_in[6];
  const float* c2w = (const float*)d_in[7]; const float* c2b = (const float*)d_in[8];
  const float* b2g = (const float*)d_in[9]; const float* b2b = (const float*)d_in[10];
  const float* b2m = (const float*)d_in[11]; const float* b2v = (const float*)d_in[12];
  const float* c3w = (const float*)d_in[13]; const float* c3b = (const float*)d_in[14];
  const float* b3g = (const float*)d_in[15]; const float* b3b = (const float*)d_in[16];
  const float* b3m = (const float*)d_in[17]; const float* b3v = (const float*)d_in[18];
  const float* ln_g = (const float*)d_in[19]; const float* ln_b = (const float*)d_in[20];
  const float* w_in = (const float*)d_in[21];
  const float* cw = (const float*)d_in[22]; const float* cbv = (const float*)d_in[23];
  const float* w_x = (const float*)d_in[24];
  const float* w_dt = (const float*)d_in[25]; const float* b_dt = (const float*)d_in[26];
  const float* a_log = (const float*)d_in[27]; const float* d_skip = (const float*)d_in[28];
  const float* w_out = (const float*)d_in[29];
  const float* fc_w = (const float*)d_in[30]; const float* fc_b = (const float*)d_in[31];

  char* ws = (char*)d_ws;
  size_t off = 0;
  auto take = [&](size_t bytes) { size_t o = off; off += bytes; return o; };
  // scratch region S: stem buffers (phase 1) union mamba buffers (phase 2)
  size_t S = take(67837952);
  // stem phase 1: conv1a output + pooled t1
  unsigned short* c1o = (unsigned short*)(ws + S + 0);          // 51.38 MB
  unsigned short* t1 = (unsigned short*)(ws + S + 51380224);    // 12.85 MB
  // stem phase 2 (c1o dead once t1 is written)
  unsigned short* t2 = (unsigned short*)(ws + S + 0);           // 25.69 MB
  unsigned short* t3 = (unsigned short*)(ws + S + 25690112);    // 6.42 MB
  unsigned short* t4 = (unsigned short*)(ws + S + 32112640);    // 12.85 MB
  // mamba phase (stem buffers dead)
  float* xz = (float*)(ws + S + 0);
  float* xc = (float*)(ws + S + 25690112);
  unsigned short* xcb = (unsigned short*)(ws + S + 38535168);
  float* dbl = (float*)(ws + S + 44957696);
  float* dtb = (float*)(ws + S + 48570368);
  unsigned short* ybf = (unsigned short*)(ws + S + 61415424);
  float* h = (float*)(ws + take(6422528));
  unsigned short* hbf = (unsigned short*)(ws + take(3211264));
  unsigned short* w_in_bf = (unsigned short*)(ws + take(3145728));
  unsigned short* w_x_bf = (unsigned short*)(ws + take(884736));
  unsigned short* w_out_bf = (unsigned short*)(ws + take(1572864));
  unsigned short* w2p = (unsigned short*)(ws + take(147456));
  unsigned short* w3p = (unsigned short*)(ws + take(589824));
  float* wdt_t = (float*)(ws + take(196608));
  float* part = (float*)(ws + take(131072));
  (void)ws_size; (void)in_sizes; (void)n_in; (void)out_size;

  // fused weight conversion / repack / transpose (3219456 elems = 12576 * 256)
  k_prep<<<12576, 256, 0, stream>>>(w_in, w_in_bf, w_x, w_x_bf, w_out, w_out_bf,
                                    c2w, w2p, c3w, w3p, w_dt, wdt_t);

  // stem
  k_conv1a<<<3584, 256, 0, stream>>>(x, c1w, c1b, b1g, b1b, b1m, b1v, c1o);
  k_pool3<<<25088, 256, 0, stream>>>(c1o, t1);
  k_convgemm<56, 56, 64, 128><<<1568 * 2, 256, 0, stream>>>(t1, w2p, c2b, b2g, b2b, b2m, b2v, t2);
  k_pool<56, 56, 128, false><<<12544, 256, 0, stream>>>(t2, t3);
  k_convgemm<28, 28, 128, 256><<<392 * 4, 256, 0, stream>>>(t3, w3p, c3b, b3g, b3b, b3m, b3v, t4);
  k_pool<28, 28, 256, true><<<6272, 256, 0, stream>>>(t4, h);

  // mamba blocks
  for (int blk = 0; blk < 6; ++blk) {
    k_ln<<<1568, 256, 0, stream>>>(h, ln_g + blk * 256, ln_b + blk * 256, hbf);
    k_sgemm<128, 128, 4, false><<<49 * 8, 256, 0, stream>>>(
        hbf, w_in_bf + (size_t)blk * 1024 * 256, xz, 1024, 8);
    k_dwconv<<<12544, 256, 0, stream>>>(xz, cw + blk * 512 * 4, cbv + blk * 512, xc, xcb);
    k_gemm<false><<<98 * 3, 256, 0, stream>>>(xcb, w_x_bf + (size_t)blk * 144 * 512, dbl,
                                              6272, 144, 512, 3);
    k_dt<<<12544, 256, 0, stream>>>(dbl, wdt_t + blk * 8192, b_dt + blk * 512, dtb);
    k_scan<<<4096, 256, 0, stream>>>(dtb, xc, dbl, xz, a_log + blk * 512 * 64,
                                     d_skip + blk * 512, ybf);
    k_sgemm<64, 64, 8, true><<<98 * 4, 256, 0, stream>>>(
        ybf, w_out_bf + (size_t)blk * 256 * 512, h, 256, 4);
  }

  // head
  k_mean2<<<128, 256, 0, stream>>>(h, part);
  k_head<<<32, 256, 0, stream>>>(part, fc_w, fc_b, (float*)d_out);
}

// Round 10
// 1624.557 us; speedup vs baseline: 1.5502x; 1.0172x over previous
//
#include <hip/hip_runtime.h>

// ---------- types ----------
typedef __bf16 bf16x8 __attribute__((ext_vector_type(8)));
typedef float f32x4 __attribute__((ext_vector_type(4)));

#define EPS 1e-5f

__device__ __forceinline__ unsigned short f2bu(float f) {
  union { float f; unsigned u; } x; x.f = f;
  unsigned r = x.u + 0x7fffu + ((x.u >> 16) & 1u);  // RNE
  return (unsigned short)(r >> 16);
}
__device__ __forceinline__ float bu2f(unsigned short u) {
  union { unsigned u; float f; } x; x.u = ((unsigned)u) << 16;
  return x.f;
}

__device__ __forceinline__ void gld16(const void* g, void* l) {
  __builtin_amdgcn_global_load_lds((const __attribute__((address_space(1))) void*)g,
                                   (__attribute__((address_space(3))) void*)l, 16, 0, 0);
}

// ---------- fused prep: f2b (w_in,w_x,w_out) + conv repacks + w_dt transpose ----------
__global__ __launch_bounds__(256) void k_prep(
    const float* __restrict__ w_in, unsigned short* __restrict__ w_in_bf,
    const float* __restrict__ w_x, unsigned short* __restrict__ w_x_bf,
    const float* __restrict__ w_out, unsigned short* __restrict__ w_out_bf,
    const float* __restrict__ c2w, unsigned short* __restrict__ w2p,
    const float* __restrict__ c3w, unsigned short* __restrict__ w3p,
    const float* __restrict__ w_dt, float* __restrict__ wdt_t) {
  int id = blockIdx.x * 256 + threadIdx.x;
  if (id < 1572864) { w_in_bf[id] = f2bu(w_in[id]); return; }
  id -= 1572864;
  if (id < 442368) { w_x_bf[id] = f2bu(w_x[id]); return; }
  id -= 442368;
  if (id < 786432) { w_out_bf[id] = f2bu(w_out[id]); return; }
  id -= 786432;
  if (id < 73728) {  // repack CI=64
    int ci = id % 64, tap = (id / 64) % 9, co = id / 576;
    w2p[id] = f2bu(c2w[(co * 64 + ci) * 9 + tap]);
    return;
  }
  id -= 73728;
  if (id < 294912) {  // repack CI=128
    int ci = id % 128, tap = (id / 128) % 9, co = id / 1152;
    w3p[id] = f2bu(c3w[(co * 128 + ci) * 9 + tap]);
    return;
  }
  id -= 294912;
  {  // w_dt transpose (6*16*512)
    int d = id & 511, r = (id >> 9) & 15, blk = id >> 13;
    wdt_t[id] = w_dt[(blk * 512 + d) * 16 + r];
  }
}

// ---------- conv1 pass A v4: block = (b,oy) row; LDS-staged x window; ----------
// thread = (channel, ox-group of 28); broadcast ds_read_b128 x; zero-pad edges.
__global__ __launch_bounds__(256) void k_conv1a(
    const float* __restrict__ x, const float* __restrict__ w,
    const float* __restrict__ cb, const float* __restrict__ g,
    const float* __restrict__ bb, const float* __restrict__ bm_,
    const float* __restrict__ bv, unsigned short* __restrict__ out) {
  __shared__ __align__(16) float sx[9][228];  // [ci*3+ky][1+ix], zero-padded
  __shared__ float sw[64 * 27];
  __shared__ float sa[64], sb[64];
  int tid = threadIdx.x;
  int oy = blockIdx.x % 112, b = blockIdx.x / 112;
  // stage input rows (zero-filled outside [0,224))
  for (int i = tid; i < 9 * 228; i += 256) {
    int row = i / 228;
    int ixl = i - row * 228;
    int ci = row / 3, ky = row - ci * 3;
    int iy = 2 * oy - 1 + ky;
    int ix = ixl - 1;
    float v = 0.f;
    if ((unsigned)iy < 224u && (unsigned)ix < 224u)
      v = x[((size_t)(b * 3 + ci) * 224 + iy) * 224 + ix];
    sx[row][ixl] = v;
  }
  // stage weights + folded BN
  for (int i = tid; i < 64 * 27; i += 256) sw[i] = w[i];
  if (tid < 64) {
    int c = tid;
    float alpha = g[c] * rsqrtf(bv[c] + EPS);
    sa[c] = alpha;
    sb[c] = (cb[c] - bm_[c]) * alpha + bb[c];
  }
  __syncthreads();
  int c = tid & 63, grp = tid >> 6;  // 4 groups x 28 pixels
  int ox0 = grp * 28;
  float acc[28];
#pragma unroll
  for (int i = 0; i < 28; ++i) acc[i] = 0.f;
#pragma unroll
  for (int ci = 0; ci < 3; ++ci) {
    float wr[9];
#pragma unroll
    for (int j = 0; j < 9; ++j) wr[j] = sw[c * 27 + ci * 9 + j];
#pragma unroll
    for (int ky = 0; ky < 3; ++ky) {
      const float* row = sx[ci * 3 + ky];
#pragma unroll
      for (int q = 0; q < 7; ++q) {
        int base = 2 * (ox0 + q * 4);  // 16B-aligned
        f32x4 a0 = *(const f32x4*)&row[base];
        f32x4 a1 = *(const f32x4*)&row[base + 4];
        f32x4 a2 = *(const f32x4*)&row[base + 8];
        float xv[12] = {a0[0], a0[1], a0[2], a0[3], a1[0], a1[1],
                        a1[2], a1[3], a2[0], a2[1], a2[2], a2[3]};
#pragma unroll
        for (int p = 0; p < 4; ++p) {
          acc[q * 4 + p] = fmaf(xv[2 * p + 0], wr[ky * 3 + 0], acc[q * 4 + p]);
          acc[q * 4 + p] = fmaf(xv[2 * p + 1], wr[ky * 3 + 1], acc[q * 4 + p]);
          acc[q * 4 + p] = fmaf(xv[2 * p + 2], wr[ky * 3 + 2], acc[q * 4 + p]);
        }
      }
    }
  }
  float alpha = sa[c], beta = sb[c];
  unsigned short* op = out + (((size_t)(b * 112 + oy)) * 112 + ox0) * 64 + c;
#pragma unroll
  for (int p = 0; p < 28; ++p)
    op[(size_t)p * 64] = f2bu(fmaxf(acc[p] * alpha + beta, 0.f));
}

// ---------- conv1 pass B: 3x3 s2 p1 maxpool on NHWC bf16 (values >= 0) ----------
__global__ __launch_bounds__(256) void k_pool3(const unsigned short* __restrict__ in,
                                               unsigned short* __restrict__ out) {
  int id = blockIdx.x * 256 + threadIdx.x;  // ((b*56+py)*56+px)*64 + c
  int c = id & 63;
  int t = id >> 6;
  int px = t % 56; t /= 56;
  int py = t % 56;
  int b = t / 56;
  float m = 0.f;  // inputs are post-ReLU (>= 0)
#pragma unroll
  for (int ky = 0; ky < 3; ++ky) {
    int iy = py * 2 - 1 + ky;
    if ((unsigned)iy >= 112u) continue;
#pragma unroll
    for (int kx = 0; kx < 3; ++kx) {
      int ix = px * 2 - 1 + kx;
      if ((unsigned)ix >= 112u) continue;
      m = fmaxf(m, bu2f(in[(((size_t)(b * 112 + iy) * 112) + ix) * 64 + c]));
    }
  }
  out[id] = f2bu(m);
}

// ---------- implicit-GEMM 3x3 s1 p1 conv, NHWC bf16 in/out, BN+ReLU epilogue ----------
template <int H, int Wd, int CI, int CO>
__global__ __launch_bounds__(256) void k_convgemm(
    const unsigned short* __restrict__ In, const unsigned short* __restrict__ Wt,
    const float* __restrict__ cb, const float* __restrict__ g,
    const float* __restrict__ bb, const float* __restrict__ bm_,
    const float* __restrict__ bv, unsigned short* __restrict__ Out) {
  constexpr int K = 9 * CI;
  constexpr int NTN = CO / 64;
  int bm = blockIdx.x / NTN, bn = blockIdx.x - bm * NTN;
  int lane = threadIdx.x & 63, wid = threadIdx.x >> 6;
  int wr = wid >> 1, wc = wid & 1;
  int r0 = bm * 64 + wr * 32 + (lane & 15);
  int r1 = r0 + 16;
  int c0 = bn * 64 + wc * 32 + (lane & 15);
  int koff = (lane >> 4) << 3;
  int ox0 = r0 % Wd; int t0 = r0 / Wd; int oy0 = t0 % H; int b0 = t0 / H;
  int ox1 = r1 % Wd; int t1 = r1 / Wd; int oy1 = t1 % H; int b1 = t1 / H;
  const unsigned short* pb0 = Wt + (size_t)c0 * K + koff;
  const unsigned short* pb1 = Wt + (size_t)(c0 + 16) * K + koff;
  f32x4 acc[2][2] = {};
  for (int k0 = 0; k0 < K; k0 += 32) {
    int k = k0 + koff;
    int tap = k / CI;
    int ci = k - tap * CI;
    int ky = tap / 3, kx = tap - ky * 3;
    int iy0 = oy0 + ky - 1, ix0 = ox0 + kx - 1;
    int iy1 = oy1 + ky - 1, ix1 = ox1 + kx - 1;
    bf16x8 a0 = {};
    bf16x8 a1 = {};
    if ((unsigned)iy0 < (unsigned)H && (unsigned)ix0 < (unsigned)Wd)
      a0 = *(const bf16x8*)(In + ((size_t)((b0 * H + iy0) * Wd + ix0)) * CI + ci);
    if ((unsigned)iy1 < (unsigned)H && (unsigned)ix1 < (unsigned)Wd)
      a1 = *(const bf16x8*)(In + ((size_t)((b1 * H + iy1) * Wd + ix1)) * CI + ci);
    bf16x8 w0 = *(const bf16x8*)(pb0 + k0);
    bf16x8 w1 = *(const bf16x8*)(pb1 + k0);
    acc[0][0] = __builtin_amdgcn_mfma_f32_16x16x32_bf16(a0, w0, acc[0][0], 0, 0, 0);
    acc[0][1] = __builtin_amdgcn_mfma_f32_16x16x32_bf16(a0, w1, acc[0][1], 0, 0, 0);
    acc[1][0] = __builtin_amdgcn_mfma_f32_16x16x32_bf16(a1, w0, acc[1][0], 0, 0, 0);
    acc[1][1] = __builtin_amdgcn_mfma_f32_16x16x32_bf16(a1, w1, acc[1][1], 0, 0, 0);
  }
  int rr = (lane >> 4) * 4, rc = lane & 15;
#pragma unroll
  for (int tj = 0; tj < 2; ++tj) {
    int col = bn * 64 + wc * 32 + tj * 16 + rc;
    float alpha = g[col] * rsqrtf(bv[col] + EPS);
    float beta = (cb[col] - bm_[col]) * alpha + bb[col];
#pragma unroll
    for (int ti = 0; ti < 2; ++ti) {
      int row = bm * 64 + wr * 32 + ti * 16 + rr;
#pragma unroll
      for (int r = 0; r < 4; ++r) {
        float v = fmaxf(acc[ti][tj][r] * alpha + beta, 0.f);
        Out[(size_t)(row + r) * CO + col] = f2bu(v);
      }
    }
  }
}

// ---------- NHWC 2x2/2 maxpool, bf16 in, bf16 or f32 out ----------
template <int H, int Wd, int C, bool OUTF>
__global__ __launch_bounds__(256) void k_pool(const unsigned short* __restrict__ in,
                                              void* __restrict__ outv) {
  constexpr int OH = H / 2, OW = Wd / 2;
  int id = blockIdx.x * 256 + threadIdx.x;  // 32*OH*OW*C exact
  int c = id % C;
  int t = id / C;
  int px = t % OW; t /= OW;
  int py = t % OH;
  int b = t / OH;
  const unsigned short* p = in + (((size_t)(b * H + py * 2) * Wd) + px * 2) * C + c;
  float m0 = bu2f(p[0]), m1 = bu2f(p[C]);
  float m2 = bu2f(p[(size_t)Wd * C]), m3 = bu2f(p[(size_t)Wd * C + C]);
  float m = fmaxf(fmaxf(m0, m1), fmaxf(m2, m3));
  if (OUTF) ((float*)outv)[id] = m;
  else ((unsigned short*)outv)[id] = f2bu(m);
}

// ---------- LayerNorm over 256, f32 in -> bf16 out ----------
__global__ __launch_bounds__(256) void k_ln(const float* __restrict__ h,
                                            const float* __restrict__ g,
                                            const float* __restrict__ b2,
                                            unsigned short* __restrict__ out) {
  int lane = threadIdx.x & 63, wid = threadIdx.x >> 6;
  int t = blockIdx.x * 4 + wid;
  float4 v = *(const float4*)(h + (size_t)t * 256 + lane * 4);
  float s = v.x + v.y + v.z + v.w;
  float q = v.x * v.x + v.y * v.y + v.z * v.z + v.w * v.w;
#pragma unroll
  for (int off = 32; off; off >>= 1) {
    s += __shfl_xor(s, off);
    q += __shfl_xor(q, off);
  }
  float mu = s * (1.f / 256.f);
  float var = q * (1.f / 256.f) - mu * mu;
  float rs = rsqrtf(var + EPS);
  float4 gg = *(const float4*)(g + lane * 4);
  float4 bb = *(const float4*)(b2 + lane * 4);
  ushort4 o;
  o.x = f2bu((v.x - mu) * rs * gg.x + bb.x);
  o.y = f2bu((v.y - mu) * rs * gg.y + bb.y);
  o.z = f2bu((v.z - mu) * rs * gg.z + bb.z);
  o.w = f2bu((v.w - mu) * rs * gg.w + bb.w);
  *(ushort4*)(out + (size_t)t * 256 + lane * 4) = o;
}

// ---------- LDS-staged bf16 GEMM (m97 structure): C[M,N] = A[M,K] @ W[N,K]^T ----------
template <int BM, int BN, int KSTEPS, bool ADD>
__global__ __launch_bounds__(256) void k_sgemm(const unsigned short* __restrict__ A,
                                               const unsigned short* __restrict__ W,
                                               float* __restrict__ C,
                                               int N, int ntn) {
  constexpr int K = KSTEPS * 64;
  constexpr int MR = BM / 32;
  constexpr int NR = BN / 32;
  __shared__ __align__(16) unsigned short As[BM * 64];
  __shared__ __align__(16) unsigned short Bs[BN * 64];
  int bm = blockIdx.x / ntn, bn = blockIdx.x - bm * ntn;
  int lane = threadIdx.x & 63, wid = threadIdx.x >> 6;
  int wr = wid >> 1, wc = wid & 1;
  const int arow = lane >> 3, acol = (lane & 7) * 8;
  f32x4 acc[MR][NR] = {};
  const unsigned short* Abase = A + (size_t)(bm * BM) * K;
  const unsigned short* Wbase = W + (size_t)(bn * BN) * K;
  for (int t = 0; t < KSTEPS; ++t) {
    int k0 = t * 64;
#pragma unroll
    for (int i = 0; i < BM / 32; ++i) {
      int chunk = wid * (BM / 32) + i;
      gld16(Abase + (size_t)(chunk * 8 + arow) * K + k0 + acol, &As[chunk * 512 + lane * 8]);
    }
#pragma unroll
    for (int i = 0; i < BN / 32; ++i) {
      int chunk = wid * (BN / 32) + i;
      gld16(Wbase + (size_t)(chunk * 8 + arow) * K + k0 + acol, &Bs[chunk * 512 + lane * 8]);
    }
    __syncthreads();
#pragma unroll
    for (int kk = 0; kk < 2; ++kk) {
      bf16x8 af[MR], bfr[NR];
#pragma unroll
      for (int mi = 0; mi < MR; ++mi)
        af[mi] = *(const bf16x8*)&As[(wr * (BM / 2) + mi * 16 + (lane & 15)) * 64 + kk * 32 + (lane >> 4) * 8];
#pragma unroll
      for (int nj = 0; nj < NR; ++nj)
        bfr[nj] = *(const bf16x8*)&Bs[(wc * (BN / 2) + nj * 16 + (lane & 15)) * 64 + kk * 32 + (lane >> 4) * 8];
#pragma unroll
      for (int mi = 0; mi < MR; ++mi)
#pragma unroll
        for (int nj = 0; nj < NR; ++nj)
          acc[mi][nj] = __builtin_amdgcn_mfma_f32_16x16x32_bf16(af[mi], bfr[nj], acc[mi][nj], 0, 0, 0);
    }
    __syncthreads();
  }
  int rr = (lane >> 4) * 4, rc = lane & 15;
#pragma unroll
  for (int mi = 0; mi < MR; ++mi)
#pragma unroll
    for (int nj = 0; nj < NR; ++nj) {
      int row = bm * BM + wr * (BM / 2) + mi * 16 + rr;
      int col = bn * BN + wc * (BN / 2) + nj * 16 + rc;
#pragma unroll
      for (int r = 0; r < 4; ++r) {
        float v = acc[mi][nj][r];
        if (ADD) v += C[(size_t)(row + r) * N + col];
        C[(size_t)(row + r) * N + col] = v;
      }
    }
}

// ---------- direct bf16 GEMM (small N): C[M,N] = A[M,K] @ W[N,K]^T ----------
template <bool ADD_RES>
__global__ __launch_bounds__(256) void k_gemm(const unsigned short* __restrict__ A,
                                              const unsigned short* __restrict__ W,
                                              float* __restrict__ C, int M, int N,
                                              int K, int ntn) {
  int bm = blockIdx.x / ntn, bn = blockIdx.x - bm * ntn;
  int lane = threadIdx.x & 63, wid = threadIdx.x >> 6;
  int wr = wid >> 1, wc = wid & 1;
  int r0 = bm * 64 + wr * 32 + (lane & 15);
  int c0 = bn * 64 + wc * 32 + (lane & 15);
  int koff = (lane >> 4) << 3;
  int cc0 = (c0 < N) ? c0 : (N - 1);
  int cc1 = (c0 + 16 < N) ? (c0 + 16) : (N - 1);
  const unsigned short* pa0 = A + (size_t)r0 * K + koff;
  const unsigned short* pa1 = A + (size_t)(r0 + 16) * K + koff;
  const unsigned short* pb0 = W + (size_t)cc0 * K + koff;
  const unsigned short* pb1 = W + (size_t)cc1 * K + koff;
  f32x4 acc[2][2] = {};
  for (int k0 = 0; k0 < K; k0 += 32) {
    bf16x8 a0 = *(const bf16x8*)(pa0 + k0);
    bf16x8 a1 = *(const bf16x8*)(pa1 + k0);
    bf16x8 b0 = *(const bf16x8*)(pb0 + k0);
    bf16x8 b1 = *(const bf16x8*)(pb1 + k0);
    acc[0][0] = __builtin_amdgcn_mfma_f32_16x16x32_bf16(a0, b0, acc[0][0], 0, 0, 0);
    acc[0][1] = __builtin_amdgcn_mfma_f32_16x16x32_bf16(a0, b1, acc[0][1], 0, 0, 0);
    acc[1][0] = __builtin_amdgcn_mfma_f32_16x16x32_bf16(a1, b0, acc[1][0], 0, 0, 0);
    acc[1][1] = __builtin_amdgcn_mfma_f32_16x16x32_bf16(a1, b1, acc[1][1], 0, 0, 0);
  }
  int rr = (lane >> 4) * 4, rc = lane & 15;
#pragma unroll
  for (int ti = 0; ti < 2; ++ti)
#pragma unroll
    for (int tj = 0; tj < 2; ++tj) {
      int col = bn * 64 + wc * 32 + tj * 16 + rc;
      if (col >= N) continue;
      int row = bm * 64 + wr * 32 + ti * 16 + rr;
#pragma unroll
      for (int r = 0; r < 4; ++r) {
        float v = acc[ti][tj][r];
        if (ADD_RES) v += C[(size_t)(row + r) * N + col];
        C[(size_t)(row + r) * N + col] = v;
      }
    }
}

// ---------- depthwise causal conv (DC=4) + silu; writes f32 + bf16 ----------
__global__ __launch_bounds__(256) void k_dwconv(const float* __restrict__ xz,
                                                const float* __restrict__ cw,
                                                const float* __restrict__ cb,
                                                float* __restrict__ xc,
                                                unsigned short* __restrict__ xcb) {
  int id = blockIdx.x * 256 + threadIdx.x;  // 6272*512
  int d = id & 511;
  int bl = id >> 9;
  int l = bl % 196;
  int b = bl / 196;
  const float* xi = xz + (size_t)(b * 196) * 1024 + d;
  float4 c4 = *(const float4*)(cw + d * 4);
  float acc = cb[d];
  if (l >= 3) acc = fmaf(xi[(size_t)(l - 3) * 1024], c4.x, acc);
  if (l >= 2) acc = fmaf(xi[(size_t)(l - 2) * 1024], c4.y, acc);
  if (l >= 1) acc = fmaf(xi[(size_t)(l - 1) * 1024], c4.z, acc);
  acc = fmaf(xi[(size_t)l * 1024], c4.w, acc);
  float s = acc / (1.f + __expf(-acc));
  xc[id] = s;
  xcb[id] = f2bu(s);
}

// ---------- dt = softplus(dbl[:, :16] @ w_dt^T + b_dt), transposed weights ----------
__global__ __launch_bounds__(256) void k_dt(const float* __restrict__ dbl,
                                            const float* __restrict__ wt,
                                            const float* __restrict__ bdt,
                                            float* __restrict__ dt) {
  int id = blockIdx.x * 256 + threadIdx.x;  // 6272*512
  int d = id & 511;
  int bl = id >> 9;
  const float4* a = (const float4*)(dbl + (size_t)bl * 144);
  float acc = bdt[d];
#pragma unroll
  for (int i = 0; i < 4; ++i) {
    float4 av = a[i];
    acc = fmaf(av.x, wt[(i * 4 + 0) * 512 + d], acc);
    acc = fmaf(av.y, wt[(i * 4 + 1) * 512 + d], acc);
    acc = fmaf(av.z, wt[(i * 4 + 2) * 512 + d], acc);
    acc = fmaf(av.w, wt[(i * 4 + 3) * 512 + d], acc);
  }
  dt[id] = fmaxf(acc, 0.f) + log1pf(__expf(-fabsf(acc)));
}

// ---------- selective scan v3: 16 waves/block (full occupancy), XCD-swizzled ----------
__global__ __launch_bounds__(1024) void k_scan(
    const float* __restrict__ dtb, const float* __restrict__ xc,
    const float* __restrict__ dbl, const float* __restrict__ xz,
    const float* __restrict__ a_log, const float* __restrict__ d_skip,
    unsigned short* __restrict__ y) {
  __shared__ float lds[16][584];
  int lane = threadIdx.x & 63, wid = threadIdx.x >> 6;  // wid 0..15
  // XCD-bijective swizzle over 1024 blocks: XCD x owns bids == x (mod 8) ->
  // nbid in [x*128, x*128+128) -> 2048 consecutive wgid = 4 complete b's.
  int bid = blockIdx.x;                        // 1024 blocks
  int nbid = (bid & 7) * 128 + (bid >> 3);     // bijective [0,1024)
  int wgid = nbid * 16 + wid;                  // 0..16383
  int b = wgid >> 9, d = wgid & 511;
  float A = -__expf(a_log[d * 64 + lane]);
  float dsk = d_skip[d];
  const float* dt_p = dtb + (size_t)(b * 196) * 512 + d;
  const float* xc_p = xc + (size_t)(b * 196) * 512 + d;
  const float* z_p = xz + (size_t)(b * 196) * 1024 + 512 + d;
  const float* bc_p = dbl + (size_t)(b * 196) * 144 + 16 + lane;
  unsigned short* y_p = y + (size_t)(b * 196) * 512 + d;
  float* L = lds[wid];
  float h = 0.f;
  int g = lane >> 3, j = lane & 7;
  const float* dt_c = dt_p;
  const float* xc_c = xc_p;
  const float* bc_c = bc_p;
  // 24 unguarded tiles of 8 steps (l = 0..191)
  for (int t = 0; t < 24; ++t) {
    int l0 = t * 8;
    float p[8];
#pragma unroll
    for (int li = 0; li < 8; ++li) {
      float dtv = dt_c[li * 512];
      float xv = xc_c[li * 512];
      float Bv = bc_c[li * 144];
      float Cv = bc_c[li * 144 + 64];
      float dA = __expf(dtv * A);
      h = fmaf(dA, h, (dtv * xv) * Bv);
      p[li] = h * Cv;
    }
#pragma unroll
    for (int li = 0; li < 8; ++li) L[lane * 9 + li] = p[li];
    __builtin_amdgcn_wave_barrier();
    float s = 0.f;
#pragma unroll
    for (int k = 0; k < 8; ++k) s += L[(j * 8 + k) * 9 + g];
    __builtin_amdgcn_wave_barrier();
    s += __shfl_xor(s, 1);
    s += __shfl_xor(s, 2);
    s += __shfl_xor(s, 4);
    if (j == 0) {
      int l = l0 + g;
      float xv = xc_p[(size_t)l * 512];
      float zv = z_p[(size_t)l * 1024];
      float sig = 1.f / (1.f + __expf(-zv));
      y_p[(size_t)l * 512] = f2bu((s + dsk * xv) * (zv * sig));
    }
    dt_c += 8 * 512;
    xc_c += 8 * 512;
    bc_c += 8 * 144;
  }
  // tail tile: l = 192..195 (4 valid steps)
  {
    float p[8];
#pragma unroll
    for (int li = 0; li < 8; ++li) {
      bool ok = (li < 4);
      float dtv = ok ? dt_c[li * 512] : 0.f;
      float xv = ok ? xc_c[li * 512] : 0.f;
      float Bv = ok ? bc_c[li * 144] : 0.f;
      float Cv = ok ? bc_c[li * 144 + 64] : 0.f;
      float dA = __expf(dtv * A);
      h = fmaf(dA, h, (dtv * xv) * Bv);
      p[li] = h * Cv;
    }
#pragma unroll
    for (int li = 0; li < 8; ++li) L[lane * 9 + li] = p[li];
    __builtin_amdgcn_wave_barrier();
    float s = 0.f;
#pragma unroll
    for (int k = 0; k < 8; ++k) s += L[(j * 8 + k) * 9 + g];
    __builtin_amdgcn_wave_barrier();
    s += __shfl_xor(s, 1);
    s += __shfl_xor(s, 2);
    s += __shfl_xor(s, 4);
    int l = 192 + g;
    if (j == 0 && l < 196) {
      float xv = xc_p[(size_t)l * 512];
      float zv = z_p[(size_t)l * 1024];
      float sig = 1.f / (1.f + __expf(-zv));
      y_p[(size_t)l * 512] = f2bu((s + dsk * xv) * (zv * sig));
    }
  }
}

// ---------- head: partial mean (4 chunks of 49 rows) then fused reduce+FC ----------
__global__ __launch_bounds__(256) void k_mean2(const float* __restrict__ h,
                                               float* __restrict__ part) {
  int b = blockIdx.x >> 2, q = blockIdx.x & 3;
  int e = threadIdx.x;
  const float* hb = h + ((size_t)b * 196 + q * 49) * 256 + e;
  float s = 0.f;
  for (int l = 0; l < 49; ++l) s += hb[(size_t)l * 256];
  part[((size_t)b * 4 + q) * 256 + e] = s;
}

__global__ __launch_bounds__(256) void k_head(const float* __restrict__ part,
                                              const float* __restrict__ fw,
                                              const float* __restrict__ fb,
                                              float* __restrict__ out) {
  __shared__ float sp[256];
  int b = blockIdx.x;
  int tid = threadIdx.x, lane = tid & 63, w = tid >> 6;
  const float* pb = part + (size_t)b * 4 * 256;
  sp[tid] = (pb[tid] + pb[256 + tid] + pb[512 + tid] + pb[768 + tid]) * (1.f / 196.f);
  __syncthreads();
  // wave w handles outputs n = w, w+4, w+8 (n < 10)
  for (int n = w; n < 10; n += 4) {
    float s = 0.f;
#pragma unroll
    for (int i = 0; i < 4; ++i) {
      int e = lane * 4 + i;
      e = e & 255;
      s += sp[e] * fw[n * 256 + e];
    }
    s += __shfl_xor(s, 1); s += __shfl_xor(s, 2); s += __shfl_xor(s, 4);
    s += __shfl_xor(s, 8); s += __shfl_xor(s, 16); s += __shfl_xor(s, 32);
    if (lane == 0) out[b * 10 + n] = s + fb[n];
  }
}

// ---------- launcher ----------
static inline unsigned cdiv(unsigned a, unsigned b) { return (a + b - 1) / b; }

extern "C" void kernel_launch(void* const* d_in, const int* in_sizes, int n_in,
                              void* d_out, int out_size, void* d_ws, size_t ws_size,
                              hipStream_t stream) {
  const float* x = (const float*)d_in[0];
  const float* c1w = (const float*)d_in[1]; const float* c1b = (const float*)d_in[2];
  const float* b1g = (const float*)d_in[3]; const float* b1b = (const float*)d_in[4];
  const float* b1m = (const float*)d_in[5]; const float* b1v = (const float*)d_in[6];
  const float* c2w = (const float*)d_in[7]; const float* c2b = (const float*)d_in[8];
  const float* b2g = (const float*)d_in[9]; const float* b2b = (const float*)d_in[10];
  const float* b2m = (const float*)d_in[11]; const float* b2v = (const float*)d_in[12];
  const float* c3w = (const float*)d_in[13]; const float* c3b = (const float*)d_in[14];
  const float* b3g = (const float*)d_in[15]; const float* b3b = (const float*)d_in[16];
  const float* b3m = (const float*)d_in[17]; const float* b3v = (const float*)d_in[18];
  const float* ln_g = (const float*)d_in[19]; const float* ln_b = (const float*)d_in[20];
  const float* w_in = (const float*)d_in[21];
  const float* cw = (const float*)d_in[22]; const float* cbv = (const float*)d_in[23];
  const float* w_x = (const float*)d_in[24];
  const float* w_dt = (const float*)d_in[25]; const float* b_dt = (const float*)d_in[26];
  const float* a_log = (const float*)d_in[27]; const float* d_skip = (const float*)d_in[28];
  const float* w_out = (const float*)d_in[29];
  const float* fc_w = (const float*)d_in[30]; const float* fc_b = (const float*)d_in[31];

  char* ws = (char*)d_ws;
  size_t off = 0;
  auto take = [&](size_t bytes) { size_t o = off; off += bytes; return o; };
  // scratch region S: stem buffers (phase 1) union mamba buffers (phase 2)
  size_t S = take(67837952);
  // stem phase 1: conv1a output + pooled t1
  unsigned short* c1o = (unsigned short*)(ws + S + 0);          // 51.38 MB
  unsigned short* t1 = (unsigned short*)(ws + S + 51380224);    // 12.85 MB
  // stem phase 2 (c1o dead once t1 is written)
  unsigned short* t2 = (unsigned short*)(ws + S + 0);           // 25.69 MB
  unsigned short* t3 = (unsigned short*)(ws + S + 25690112);    // 6.42 MB
  unsigned short* t4 = (unsigned short*)(ws + S + 32112640);    // 12.85 MB
  // mamba phase (stem buffers dead)
  float* xz = (float*)(ws + S + 0);
  float* xc = (float*)(ws + S + 25690112);
  unsigned short* xcb = (unsigned short*)(ws + S + 38535168);
  float* dbl = (float*)(ws + S + 44957696);
  float* dtb = (float*)(ws + S + 48570368);
  unsigned short* ybf = (unsigned short*)(ws + S + 61415424);
  float* h = (float*)(ws + take(6422528));
  unsigned short* hbf = (unsigned short*)(ws + take(3211264));
  unsigned short* w_in_bf = (unsigned short*)(ws + take(3145728));
  unsigned short* w_x_bf = (unsigned short*)(ws + take(884736));
  unsigned short* w_out_bf = (unsigned short*)(ws + take(1572864));
  unsigned short* w2p = (unsigned short*)(ws + take(147456));
  unsigned short* w3p = (unsigned short*)(ws + take(589824));
  float* wdt_t = (float*)(ws + take(196608));
  float* part = (float*)(ws + take(131072));
  (void)ws_size; (void)in_sizes; (void)n_in; (void)out_size;

  // fused weight conversion / repack / transpose (3219456 elems = 12576 * 256)
  k_prep<<<12576, 256, 0, stream>>>(w_in, w_in_bf, w_x, w_x_bf, w_out, w_out_bf,
                                    c2w, w2p, c3w, w3p, w_dt, wdt_t);

  // stem
  k_conv1a<<<3584, 256, 0, stream>>>(x, c1w, c1b, b1g, b1b, b1m, b1v, c1o);
  k_pool3<<<25088, 256, 0, stream>>>(c1o, t1);
  k_convgemm<56, 56, 64, 128><<<1568 * 2, 256, 0, stream>>>(t1, w2p, c2b, b2g, b2b, b2m, b2v, t2);
  k_pool<56, 56, 128, false><<<12544, 256, 0, stream>>>(t2, t3);
  k_convgemm<28, 28, 128, 256><<<392 * 4, 256, 0, stream>>>(t3, w3p, c3b, b3g, b3b, b3m, b3v, t4);
  k_pool<28, 28, 256, true><<<6272, 256, 0, stream>>>(t4, h);

  // mamba blocks
  for (int blk = 0; blk < 6; ++blk) {
    k_ln<<<1568, 256, 0, stream>>>(h, ln_g + blk * 256, ln_b + blk * 256, hbf);
    k_sgemm<128, 128, 4, false><<<49 * 8, 256, 0, stream>>>(
        hbf, w_in_bf + (size_t)blk * 1024 * 256, xz, 1024, 8);
    k_dwconv<<<12544, 256, 0, stream>>>(xz, cw + blk * 512 * 4, cbv + blk * 512, xc, xcb);
    k_gemm<false><<<98 * 3, 256, 0, stream>>>(xcb, w_x_bf + (size_t)blk * 144 * 512, dbl,
                                              6272, 144, 512, 3);
    k_dt<<<12544, 256, 0, stream>>>(dbl, wdt_t + blk * 8192, b_dt + blk * 512, dtb);
    k_scan<<<1024, 1024, 0, stream>>>(dtb, xc, dbl, xz, a_log + blk * 512 * 64,
                                      d_skip + blk * 512, ybf);
    k_sgemm<64, 64, 8, true><<<98 * 4, 256, 0, stream>>>(
        ybf, w_out_bf + (size_t)blk * 256 * 512, h, 256, 4);
  }

  // head
  k_mean2<<<128, 256, 0, stream>>>(h, part);
  k_head<<<32, 256, 0, stream>>>(part, fc_w, fc_b, (float*)d_out);
}

// Round 11
// 1574.765 us; speedup vs baseline: 1.5992x; 1.0316x over previous
//
#include <hip/hip_runtime.h>

// ---------- types ----------
typedef __bf16 bf16x8 __attribute__((ext_vector_type(8)));
typedef float f32x4 __attribute__((ext_vector_type(4)));

#define EPS 1e-5f

__device__ __forceinline__ unsigned short f2bu(float f) {
  union { float f; unsigned u; } x; x.f = f;
  unsigned r = x.u + 0x7fffu + ((x.u >> 16) & 1u);  // RNE
  return (unsigned short)(r >> 16);
}
__device__ __forceinline__ float bu2f(unsigned short u) {
  union { unsigned u; float f; } x; x.u = ((unsigned)u) << 16;
  return x.f;
}

__device__ __forceinline__ void gld16(const void* g, void* l) {
  __builtin_amdgcn_global_load_lds((const __attribute__((address_space(1))) void*)g,
                                   (__attribute__((address_space(3))) void*)l, 16, 0, 0);
}

// ---------- fused prep: f2b (w_in,w_x,w_out) + conv repacks + w_dt transpose ----------
__global__ __launch_bounds__(256) void k_prep(
    const float* __restrict__ w_in, unsigned short* __restrict__ w_in_bf,
    const float* __restrict__ w_x, unsigned short* __restrict__ w_x_bf,
    const float* __restrict__ w_out, unsigned short* __restrict__ w_out_bf,
    const float* __restrict__ c2w, unsigned short* __restrict__ w2p,
    const float* __restrict__ c3w, unsigned short* __restrict__ w3p,
    const float* __restrict__ w_dt, float* __restrict__ wdt_t) {
  int id = blockIdx.x * 256 + threadIdx.x;
  if (id < 1572864) { w_in_bf[id] = f2bu(w_in[id]); return; }
  id -= 1572864;
  if (id < 442368) { w_x_bf[id] = f2bu(w_x[id]); return; }
  id -= 442368;
  if (id < 786432) { w_out_bf[id] = f2bu(w_out[id]); return; }
  id -= 786432;
  if (id < 73728) {  // repack CI=64
    int ci = id % 64, tap = (id / 64) % 9, co = id / 576;
    w2p[id] = f2bu(c2w[(co * 64 + ci) * 9 + tap]);
    return;
  }
  id -= 73728;
  if (id < 294912) {  // repack CI=128
    int ci = id % 128, tap = (id / 128) % 9, co = id / 1152;
    w3p[id] = f2bu(c3w[(co * 128 + ci) * 9 + tap]);
    return;
  }
  id -= 294912;
  {  // w_dt transpose (6*16*512)
    int d = id & 511, r = (id >> 9) & 15, blk = id >> 13;
    wdt_t[id] = w_dt[(blk * 512 + d) * 16 + r];
  }
}

// ---------- conv1 pass A v4: block = (b,oy) row; LDS-staged x window ----------
__global__ __launch_bounds__(256) void k_conv1a(
    const float* __restrict__ x, const float* __restrict__ w,
    const float* __restrict__ cb, const float* __restrict__ g,
    const float* __restrict__ bb, const float* __restrict__ bm_,
    const float* __restrict__ bv, unsigned short* __restrict__ out) {
  __shared__ __align__(16) float sx[9][228];  // [ci*3+ky][1+ix], zero-padded
  __shared__ float sw[64 * 27];
  __shared__ float sa[64], sb[64];
  int tid = threadIdx.x;
  int oy = blockIdx.x % 112, b = blockIdx.x / 112;
  for (int i = tid; i < 9 * 228; i += 256) {
    int row = i / 228;
    int ixl = i - row * 228;
    int ci = row / 3, ky = row - ci * 3;
    int iy = 2 * oy - 1 + ky;
    int ix = ixl - 1;
    float v = 0.f;
    if ((unsigned)iy < 224u && (unsigned)ix < 224u)
      v = x[((size_t)(b * 3 + ci) * 224 + iy) * 224 + ix];
    sx[row][ixl] = v;
  }
  for (int i = tid; i < 64 * 27; i += 256) sw[i] = w[i];
  if (tid < 64) {
    int c = tid;
    float alpha = g[c] * rsqrtf(bv[c] + EPS);
    sa[c] = alpha;
    sb[c] = (cb[c] - bm_[c]) * alpha + bb[c];
  }
  __syncthreads();
  int c = tid & 63, grp = tid >> 6;  // 4 groups x 28 pixels
  int ox0 = grp * 28;
  float acc[28];
#pragma unroll
  for (int i = 0; i < 28; ++i) acc[i] = 0.f;
#pragma unroll
  for (int ci = 0; ci < 3; ++ci) {
    float wr[9];
#pragma unroll
    for (int j = 0; j < 9; ++j) wr[j] = sw[c * 27 + ci * 9 + j];
#pragma unroll
    for (int ky = 0; ky < 3; ++ky) {
      const float* row = sx[ci * 3 + ky];
#pragma unroll
      for (int q = 0; q < 7; ++q) {
        int base = 2 * (ox0 + q * 4);  // 16B-aligned
        f32x4 a0 = *(const f32x4*)&row[base];
        f32x4 a1 = *(const f32x4*)&row[base + 4];
        f32x4 a2 = *(const f32x4*)&row[base + 8];
        float xv[12] = {a0[0], a0[1], a0[2], a0[3], a1[0], a1[1],
                        a1[2], a1[3], a2[0], a2[1], a2[2], a2[3]};
#pragma unroll
        for (int p = 0; p < 4; ++p) {
          acc[q * 4 + p] = fmaf(xv[2 * p + 0], wr[ky * 3 + 0], acc[q * 4 + p]);
          acc[q * 4 + p] = fmaf(xv[2 * p + 1], wr[ky * 3 + 1], acc[q * 4 + p]);
          acc[q * 4 + p] = fmaf(xv[2 * p + 2], wr[ky * 3 + 2], acc[q * 4 + p]);
        }
      }
    }
  }
  float alpha = sa[c], beta = sb[c];
  unsigned short* op = out + (((size_t)(b * 112 + oy)) * 112 + ox0) * 64 + c;
#pragma unroll
  for (int p = 0; p < 28; ++p)
    op[(size_t)p * 64] = f2bu(fmaxf(acc[p] * alpha + beta, 0.f));
}

// ---------- conv1 pass B: 3x3 s2 p1 maxpool on NHWC bf16 (values >= 0) ----------
__global__ __launch_bounds__(256) void k_pool3(const unsigned short* __restrict__ in,
                                               unsigned short* __restrict__ out) {
  int id = blockIdx.x * 256 + threadIdx.x;  // ((b*56+py)*56+px)*64 + c
  int c = id & 63;
  int t = id >> 6;
  int px = t % 56; t /= 56;
  int py = t % 56;
  int b = t / 56;
  float m = 0.f;  // inputs are post-ReLU (>= 0)
#pragma unroll
  for (int ky = 0; ky < 3; ++ky) {
    int iy = py * 2 - 1 + ky;
    if ((unsigned)iy >= 112u) continue;
#pragma unroll
    for (int kx = 0; kx < 3; ++kx) {
      int ix = px * 2 - 1 + kx;
      if ((unsigned)ix >= 112u) continue;
      m = fmaxf(m, bu2f(in[(((size_t)(b * 112 + iy) * 112) + ix) * 64 + c]));
    }
  }
  out[id] = f2bu(m);
}

// ---------- implicit-GEMM 3x3 s1 p1 conv, NHWC bf16 in/out, BN+ReLU epilogue ----------
template <int H, int Wd, int CI, int CO>
__global__ __launch_bounds__(256) void k_convgemm(
    const unsigned short* __restrict__ In, const unsigned short* __restrict__ Wt,
    const float* __restrict__ cb, const float* __restrict__ g,
    const float* __restrict__ bb, const float* __restrict__ bm_,
    const float* __restrict__ bv, unsigned short* __restrict__ Out) {
  constexpr int K = 9 * CI;
  constexpr int NTN = CO / 64;
  int bm = blockIdx.x / NTN, bn = blockIdx.x - bm * NTN;
  int lane = threadIdx.x & 63, wid = threadIdx.x >> 6;
  int wr = wid >> 1, wc = wid & 1;
  int r0 = bm * 64 + wr * 32 + (lane & 15);
  int r1 = r0 + 16;
  int c0 = bn * 64 + wc * 32 + (lane & 15);
  int koff = (lane >> 4) << 3;
  int ox0 = r0 % Wd; int t0 = r0 / Wd; int oy0 = t0 % H; int b0 = t0 / H;
  int ox1 = r1 % Wd; int t1 = r1 / Wd; int oy1 = t1 % H; int b1 = t1 / H;
  const unsigned short* pb0 = Wt + (size_t)c0 * K + koff;
  const unsigned short* pb1 = Wt + (size_t)(c0 + 16) * K + koff;
  f32x4 acc[2][2] = {};
  for (int k0 = 0; k0 < K; k0 += 32) {
    int k = k0 + koff;
    int tap = k / CI;
    int ci = k - tap * CI;
    int ky = tap / 3, kx = tap - ky * 3;
    int iy0 = oy0 + ky - 1, ix0 = ox0 + kx - 1;
    int iy1 = oy1 + ky - 1, ix1 = ox1 + kx - 1;
    bf16x8 a0 = {};
    bf16x8 a1 = {};
    if ((unsigned)iy0 < (unsigned)H && (unsigned)ix0 < (unsigned)Wd)
      a0 = *(const bf16x8*)(In + ((size_t)((b0 * H + iy0) * Wd + ix0)) * CI + ci);
    if ((unsigned)iy1 < (unsigned)H && (unsigned)ix1 < (unsigned)Wd)
      a1 = *(const bf16x8*)(In + ((size_t)((b1 * H + iy1) * Wd + ix1)) * CI + ci);
    bf16x8 w0 = *(const bf16x8*)(pb0 + k0);
    bf16x8 w1 = *(const bf16x8*)(pb1 + k0);
    acc[0][0] = __builtin_amdgcn_mfma_f32_16x16x32_bf16(a0, w0, acc[0][0], 0, 0, 0);
    acc[0][1] = __builtin_amdgcn_mfma_f32_16x16x32_bf16(a0, w1, acc[0][1], 0, 0, 0);
    acc[1][0] = __builtin_amdgcn_mfma_f32_16x16x32_bf16(a1, w0, acc[1][0], 0, 0, 0);
    acc[1][1] = __builtin_amdgcn_mfma_f32_16x16x32_bf16(a1, w1, acc[1][1], 0, 0, 0);
  }
  int rr = (lane >> 4) * 4, rc = lane & 15;
#pragma unroll
  for (int tj = 0; tj < 2; ++tj) {
    int col = bn * 64 + wc * 32 + tj * 16 + rc;
    float alpha = g[col] * rsqrtf(bv[col] + EPS);
    float beta = (cb[col] - bm_[col]) * alpha + bb[col];
#pragma unroll
    for (int ti = 0; ti < 2; ++ti) {
      int row = bm * 64 + wr * 32 + ti * 16 + rr;
#pragma unroll
      for (int r = 0; r < 4; ++r) {
        float v = fmaxf(acc[ti][tj][r] * alpha + beta, 0.f);
        Out[(size_t)(row + r) * CO + col] = f2bu(v);
      }
    }
  }
}

// ---------- NHWC 2x2/2 maxpool, bf16 in, bf16 or f32 out ----------
template <int H, int Wd, int C, bool OUTF>
__global__ __launch_bounds__(256) void k_pool(const unsigned short* __restrict__ in,
                                              void* __restrict__ outv) {
  constexpr int OH = H / 2, OW = Wd / 2;
  int id = blockIdx.x * 256 + threadIdx.x;  // 32*OH*OW*C exact
  int c = id % C;
  int t = id / C;
  int px = t % OW; t /= OW;
  int py = t % OH;
  int b = t / OH;
  const unsigned short* p = in + (((size_t)(b * H + py * 2) * Wd) + px * 2) * C + c;
  float m0 = bu2f(p[0]), m1 = bu2f(p[C]);
  float m2 = bu2f(p[(size_t)Wd * C]), m3 = bu2f(p[(size_t)Wd * C + C]);
  float m = fmaxf(fmaxf(m0, m1), fmaxf(m2, m3));
  if (OUTF) ((float*)outv)[id] = m;
  else ((unsigned short*)outv)[id] = f2bu(m);
}

// ---------- LayerNorm over 256, f32 in -> bf16 out ----------
__global__ __launch_bounds__(256) void k_ln(const float* __restrict__ h,
                                            const float* __restrict__ g,
                                            const float* __restrict__ b2,
                                            unsigned short* __restrict__ out) {
  int lane = threadIdx.x & 63, wid = threadIdx.x >> 6;
  int t = blockIdx.x * 4 + wid;
  float4 v = *(const float4*)(h + (size_t)t * 256 + lane * 4);
  float s = v.x + v.y + v.z + v.w;
  float q = v.x * v.x + v.y * v.y + v.z * v.z + v.w * v.w;
#pragma unroll
  for (int off = 32; off; off >>= 1) {
    s += __shfl_xor(s, off);
    q += __shfl_xor(q, off);
  }
  float mu = s * (1.f / 256.f);
  float var = q * (1.f / 256.f) - mu * mu;
  float rs = rsqrtf(var + EPS);
  float4 gg = *(const float4*)(g + lane * 4);
  float4 bb = *(const float4*)(b2 + lane * 4);
  ushort4 o;
  o.x = f2bu((v.x - mu) * rs * gg.x + bb.x);
  o.y = f2bu((v.y - mu) * rs * gg.y + bb.y);
  o.z = f2bu((v.z - mu) * rs * gg.z + bb.z);
  o.w = f2bu((v.w - mu) * rs * gg.w + bb.w);
  *(ushort4*)(out + (size_t)t * 256 + lane * 4) = o;
}

// ---------- LDS-staged bf16 GEMM (m97 structure): C[M,N] = A[M,K] @ W[N,K]^T ----------
template <int BM, int BN, int KSTEPS, bool ADD>
__global__ __launch_bounds__(256) void k_sgemm(const unsigned short* __restrict__ A,
                                               const unsigned short* __restrict__ W,
                                               float* __restrict__ C,
                                               int N, int ntn) {
  constexpr int K = KSTEPS * 64;
  constexpr int MR = BM / 32;
  constexpr int NR = BN / 32;
  __shared__ __align__(16) unsigned short As[BM * 64];
  __shared__ __align__(16) unsigned short Bs[BN * 64];
  int bm = blockIdx.x / ntn, bn = blockIdx.x - bm * ntn;
  int lane = threadIdx.x & 63, wid = threadIdx.x >> 6;
  int wr = wid >> 1, wc = wid & 1;
  const int arow = lane >> 3, acol = (lane & 7) * 8;
  f32x4 acc[MR][NR] = {};
  const unsigned short* Abase = A + (size_t)(bm * BM) * K;
  const unsigned short* Wbase = W + (size_t)(bn * BN) * K;
  for (int t = 0; t < KSTEPS; ++t) {
    int k0 = t * 64;
#pragma unroll
    for (int i = 0; i < BM / 32; ++i) {
      int chunk = wid * (BM / 32) + i;
      gld16(Abase + (size_t)(chunk * 8 + arow) * K + k0 + acol, &As[chunk * 512 + lane * 8]);
    }
#pragma unroll
    for (int i = 0; i < BN / 32; ++i) {
      int chunk = wid * (BN / 32) + i;
      gld16(Wbase + (size_t)(chunk * 8 + arow) * K + k0 + acol, &Bs[chunk * 512 + lane * 8]);
    }
    __syncthreads();
#pragma unroll
    for (int kk = 0; kk < 2; ++kk) {
      bf16x8 af[MR], bfr[NR];
#pragma unroll
      for (int mi = 0; mi < MR; ++mi)
        af[mi] = *(const bf16x8*)&As[(wr * (BM / 2) + mi * 16 + (lane & 15)) * 64 + kk * 32 + (lane >> 4) * 8];
#pragma unroll
      for (int nj = 0; nj < NR; ++nj)
        bfr[nj] = *(const bf16x8*)&Bs[(wc * (BN / 2) + nj * 16 + (lane & 15)) * 64 + kk * 32 + (lane >> 4) * 8];
#pragma unroll
      for (int mi = 0; mi < MR; ++mi)
#pragma unroll
        for (int nj = 0; nj < NR; ++nj)
          acc[mi][nj] = __builtin_amdgcn_mfma_f32_16x16x32_bf16(af[mi], bfr[nj], acc[mi][nj], 0, 0, 0);
    }
    __syncthreads();
  }
  int rr = (lane >> 4) * 4, rc = lane & 15;
#pragma unroll
  for (int mi = 0; mi < MR; ++mi)
#pragma unroll
    for (int nj = 0; nj < NR; ++nj) {
      int row = bm * BM + wr * (BM / 2) + mi * 16 + rr;
      int col = bn * BN + wc * (BN / 2) + nj * 16 + rc;
#pragma unroll
      for (int r = 0; r < 4; ++r) {
        float v = acc[mi][nj][r];
        if (ADD) v += C[(size_t)(row + r) * N + col];
        C[(size_t)(row + r) * N + col] = v;
      }
    }
}

// ---------- direct bf16 GEMM (small N): C[M,N] = A[M,K] @ W[N,K]^T ----------
template <bool ADD_RES>
__global__ __launch_bounds__(256) void k_gemm(const unsigned short* __restrict__ A,
                                              const unsigned short* __restrict__ W,
                                              float* __restrict__ C, int M, int N,
                                              int K, int ntn) {
  int bm = blockIdx.x / ntn, bn = blockIdx.x - bm * ntn;
  int lane = threadIdx.x & 63, wid = threadIdx.x >> 6;
  int wr = wid >> 1, wc = wid & 1;
  int r0 = bm * 64 + wr * 32 + (lane & 15);
  int c0 = bn * 64 + wc * 32 + (lane & 15);
  int koff = (lane >> 4) << 3;
  int cc0 = (c0 < N) ? c0 : (N - 1);
  int cc1 = (c0 + 16 < N) ? (c0 + 16) : (N - 1);
  const unsigned short* pa0 = A + (size_t)r0 * K + koff;
  const unsigned short* pa1 = A + (size_t)(r0 + 16) * K + koff;
  const unsigned short* pb0 = W + (size_t)cc0 * K + koff;
  const unsigned short* pb1 = W + (size_t)cc1 * K + koff;
  f32x4 acc[2][2] = {};
  for (int k0 = 0; k0 < K; k0 += 32) {
    bf16x8 a0 = *(const bf16x8*)(pa0 + k0);
    bf16x8 a1 = *(const bf16x8*)(pa1 + k0);
    bf16x8 b0 = *(const bf16x8*)(pb0 + k0);
    bf16x8 b1 = *(const bf16x8*)(pb1 + k0);
    acc[0][0] = __builtin_amdgcn_mfma_f32_16x16x32_bf16(a0, b0, acc[0][0], 0, 0, 0);
    acc[0][1] = __builtin_amdgcn_mfma_f32_16x16x32_bf16(a0, b1, acc[0][1], 0, 0, 0);
    acc[1][0] = __builtin_amdgcn_mfma_f32_16x16x32_bf16(a1, b0, acc[1][0], 0, 0, 0);
    acc[1][1] = __builtin_amdgcn_mfma_f32_16x16x32_bf16(a1, b1, acc[1][1], 0, 0, 0);
  }
  int rr = (lane >> 4) * 4, rc = lane & 15;
#pragma unroll
  for (int ti = 0; ti < 2; ++ti)
#pragma unroll
    for (int tj = 0; tj < 2; ++tj) {
      int col = bn * 64 + wc * 32 + tj * 16 + rc;
      if (col >= N) continue;
      int row = bm * 64 + wr * 32 + ti * 16 + rr;
#pragma unroll
      for (int r = 0; r < 4; ++r) {
        float v = acc[ti][tj][r];
        if (ADD_RES) v += C[(size_t)(row + r) * N + col];
        C[(size_t)(row + r) * N + col] = v;
      }
    }
}

// ---------- depthwise causal conv + silu; LDS transpose; writes xcT[b][d][l] + xcb[bl][d] ----------
// grid: (lt=4, dt=8, b=32), 256 threads. Tile: 64 d x 49 l.
__global__ __launch_bounds__(256) void k_dwconvT(const float* __restrict__ xz,
                                                 const float* __restrict__ cw,
                                                 const float* __restrict__ cb,
                                                 float* __restrict__ xcT,
                                                 unsigned short* __restrict__ xcb) {
  __shared__ float sxz[52][67];
  __shared__ float sxc[49][67];
  int tid = threadIdx.x;
  int l0 = blockIdx.x * 49, d0 = blockIdx.y * 64, b = blockIdx.z;
  // stage xz rows l0-3 .. l0+48 (zero-fill l<0), 64 d's
  for (int i = tid; i < 52 * 64; i += 256) {
    int row = i >> 6, dd = i & 63;
    int gl = l0 - 3 + row;
    float v = 0.f;
    if (gl >= 0) v = xz[((size_t)(b * 196 + gl)) * 1024 + d0 + dd];
    sxz[row][dd] = v;
  }
  __syncthreads();
  int lane = tid & 63, wv = tid >> 6;
  // wave wv handles 16 d's; lane = l (0..48 active)
#pragma unroll
  for (int i = 0; i < 16; ++i) {
    int dl = wv * 16 + i;
    int d = d0 + dl;
    float4 c4 = *(const float4*)(cw + d * 4);
    float acc = cb[d];
    acc = fmaf(sxz[lane + 0][dl], c4.x, acc);
    acc = fmaf(sxz[lane + 1][dl], c4.y, acc);
    acc = fmaf(sxz[lane + 2][dl], c4.z, acc);
    acc = fmaf(sxz[lane + 3][dl], c4.w, acc);
    float s = acc / (1.f + __expf(-acc));
    if (lane < 49) {
      xcT[((size_t)(b * 512 + d)) * 196 + l0 + lane] = s;
      sxc[lane][dl] = s;
    }
  }
  __syncthreads();
  // write xcb[bl][d] coalesced from LDS
  for (int i = tid; i < 49 * 64; i += 256) {
    int row = i >> 6, dd = i & 63;
    xcb[((size_t)(b * 196 + l0 + row)) * 512 + d0 + dd] = f2bu(sxc[row][dd]);
  }
}

// ---------- dt = softplus(dbl[:, :16] @ w_dt^T + b_dt) -> dtT[b][d][l] ----------
// grid: (lt=4, dt=8, b=32), 256 threads. Tile: 64 d x 49 l.
__global__ __launch_bounds__(256) void k_dtT(const float* __restrict__ dbl,
                                             const float* __restrict__ wt,
                                             const float* __restrict__ bdt,
                                             float* __restrict__ dtT) {
  __shared__ float sdbl[49][17];
  __shared__ float swdt[16][64];
  __shared__ float sbdt[64];
  int tid = threadIdx.x;
  int l0 = blockIdx.x * 49, d0 = blockIdx.y * 64, b = blockIdx.z;
  for (int i = tid; i < 49 * 16; i += 256) {
    int row = i >> 4, r = i & 15;
    sdbl[row][r] = dbl[((size_t)(b * 196 + l0 + row)) * 144 + r];
  }
  for (int i = tid; i < 16 * 64; i += 256) {
    int r = i >> 6, dd = i & 63;
    swdt[r][dd] = wt[r * 512 + d0 + dd];
  }
  if (tid < 64) sbdt[tid] = bdt[d0 + tid];
  __syncthreads();
  int lane = tid & 63, wv = tid >> 6;
#pragma unroll
  for (int i = 0; i < 16; ++i) {
    int dl = wv * 16 + i;
    float acc = sbdt[dl];
#pragma unroll
    for (int r = 0; r < 16; ++r) acc = fmaf(sdbl[lane < 49 ? lane : 0][r], swdt[r][dl], acc);
    float sp = fmaxf(acc, 0.f) + log1pf(__expf(-fabsf(acc)));
    if (lane < 49)
      dtT[((size_t)(b * 512 + d0 + dl)) * 196 + l0 + lane] = sp;
  }
}

// ---------- selective scan v4: transposed dt/xc (f32x4 uniform loads), 16 waves/block ----------
__global__ __launch_bounds__(1024) void k_scan(
    const float* __restrict__ dtT, const float* __restrict__ xcT,
    const float* __restrict__ dbl, const float* __restrict__ xz,
    const float* __restrict__ a_log, const float* __restrict__ d_skip,
    unsigned short* __restrict__ y) {
  __shared__ float lds[16][584];
  int lane = threadIdx.x & 63, wid = threadIdx.x >> 6;  // wid 0..15
  int bid = blockIdx.x;                        // 1024 blocks
  int nbid = (bid & 7) * 128 + (bid >> 3);     // bijective [0,1024)
  int wgid = nbid * 16 + wid;                  // 0..16383
  int b = wgid >> 9, d = wgid & 511;
  float A = -__expf(a_log[d * 64 + lane]);
  float dsk = d_skip[d];
  const float* dtr = dtT + (size_t)(b * 512 + d) * 196;
  const float* xcr = xcT + (size_t)(b * 512 + d) * 196;
  const float* z_p = xz + (size_t)(b * 196) * 1024 + 512 + d;
  const float* bc_p = dbl + (size_t)(b * 196) * 144 + 16 + lane;
  unsigned short* y_p = y + (size_t)(b * 196) * 512 + d;
  float* L = lds[wid];
  float h = 0.f;
  int g = lane >> 3, j = lane & 7;
  const float* bc_c = bc_p;
  // 24 unguarded tiles of 8 steps (l = 0..191)
  for (int t = 0; t < 24; ++t) {
    int l0 = t * 8;
    f32x4 dq0 = *(const f32x4*)(dtr + l0);
    f32x4 dq1 = *(const f32x4*)(dtr + l0 + 4);
    f32x4 xq0 = *(const f32x4*)(xcr + l0);
    f32x4 xq1 = *(const f32x4*)(xcr + l0 + 4);
    float dtv[8] = {dq0[0], dq0[1], dq0[2], dq0[3], dq1[0], dq1[1], dq1[2], dq1[3]};
    float xvv[8] = {xq0[0], xq0[1], xq0[2], xq0[3], xq1[0], xq1[1], xq1[2], xq1[3]};
    float p[8];
#pragma unroll
    for (int li = 0; li < 8; ++li) {
      float Bv = bc_c[li * 144];
      float Cv = bc_c[li * 144 + 64];
      float dA = __expf(dtv[li] * A);
      h = fmaf(dA, h, (dtv[li] * xvv[li]) * Bv);
      p[li] = h * Cv;
    }
#pragma unroll
    for (int li = 0; li < 8; ++li) L[lane * 9 + li] = p[li];
    __builtin_amdgcn_wave_barrier();
    float s = 0.f;
#pragma unroll
    for (int k = 0; k < 8; ++k) s += L[(j * 8 + k) * 9 + g];
    __builtin_amdgcn_wave_barrier();
    s += __shfl_xor(s, 1);
    s += __shfl_xor(s, 2);
    s += __shfl_xor(s, 4);
    if (j == 0) {
      int l = l0 + g;
      float xv = xcr[l];
      float zv = z_p[(size_t)l * 1024];
      float sig = 1.f / (1.f + __expf(-zv));
      y_p[(size_t)l * 512] = f2bu((s + dsk * xv) * (zv * sig));
    }
    bc_c += 8 * 144;
  }
  // tail tile: l = 192..195 (4 valid steps)
  {
    f32x4 dq0 = *(const f32x4*)(dtr + 192);
    f32x4 xq0 = *(const f32x4*)(xcr + 192);
    float dtv[8] = {dq0[0], dq0[1], dq0[2], dq0[3], 0.f, 0.f, 0.f, 0.f};
    float xvv[8] = {xq0[0], xq0[1], xq0[2], xq0[3], 0.f, 0.f, 0.f, 0.f};
    float p[8];
#pragma unroll
    for (int li = 0; li < 8; ++li) {
      bool ok = (li < 4);
      float Bv = ok ? bc_c[li * 144] : 0.f;
      float Cv = ok ? bc_c[li * 144 + 64] : 0.f;
      float dA = __expf(dtv[li] * A);
      h = fmaf(dA, h, (dtv[li] * xvv[li]) * Bv);
      p[li] = h * Cv;
    }
#pragma unroll
    for (int li = 0; li < 8; ++li) L[lane * 9 + li] = p[li];
    __builtin_amdgcn_wave_barrier();
    float s = 0.f;
#pragma unroll
    for (int k = 0; k < 8; ++k) s += L[(j * 8 + k) * 9 + g];
    __builtin_amdgcn_wave_barrier();
    s += __shfl_xor(s, 1);
    s += __shfl_xor(s, 2);
    s += __shfl_xor(s, 4);
    int l = 192 + g;
    if (j == 0 && l < 196) {
      float xv = xcr[l];
      float zv = z_p[(size_t)l * 1024];
      float sig = 1.f / (1.f + __expf(-zv));
      y_p[(size_t)l * 512] = f2bu((s + dsk * xv) * (zv * sig));
    }
  }
}

// ---------- head: partial mean (4 chunks of 49 rows) then fused reduce+FC ----------
__global__ __launch_bounds__(256) void k_mean2(const float* __restrict__ h,
                                               float* __restrict__ part) {
  int b = blockIdx.x >> 2, q = blockIdx.x & 3;
  int e = threadIdx.x;
  const float* hb = h + ((size_t)b * 196 + q * 49) * 256 + e;
  float s = 0.f;
  for (int l = 0; l < 49; ++l) s += hb[(size_t)l * 256];
  part[((size_t)b * 4 + q) * 256 + e] = s;
}

__global__ __launch_bounds__(256) void k_head(const float* __restrict__ part,
                                              const float* __restrict__ fw,
                                              const float* __restrict__ fb,
                                              float* __restrict__ out) {
  __shared__ float sp[256];
  int b = blockIdx.x;
  int tid = threadIdx.x, lane = tid & 63, w = tid >> 6;
  const float* pb = part + (size_t)b * 4 * 256;
  sp[tid] = (pb[tid] + pb[256 + tid] + pb[512 + tid] + pb[768 + tid]) * (1.f / 196.f);
  __syncthreads();
  for (int n = w; n < 10; n += 4) {
    float s = 0.f;
#pragma unroll
    for (int i = 0; i < 4; ++i) {
      int e = lane * 4 + i;
      e = e & 255;
      s += sp[e] * fw[n * 256 + e];
    }
    s += __shfl_xor(s, 1); s += __shfl_xor(s, 2); s += __shfl_xor(s, 4);
    s += __shfl_xor(s, 8); s += __shfl_xor(s, 16); s += __shfl_xor(s, 32);
    if (lane == 0) out[b * 10 + n] = s + fb[n];
  }
}

// ---------- launcher ----------
static inline unsigned cdiv(unsigned a, unsigned b) { return (a + b - 1) / b; }

extern "C" void kernel_launch(void* const* d_in, const int* in_sizes, int n_in,
                              void* d_out, int out_size, void* d_ws, size_t ws_size,
                              hipStream_t stream) {
  const float* x = (const float*)d_in[0];
  const float* c1w = (const float*)d_in[1]; const float* c1b = (const float*)d_in[2];
  const float* b1g = (const float*)d_in[3]; const float* b1b = (const float*)d_in[4];
  const float* b1m = (const float*)d_in[5]; const float* b1v = (const float*)d_in[6];
  const float* c2w = (const float*)d_in[7]; const float* c2b = (const float*)d_in[8];
  const float* b2g = (const float*)d_in[9]; const float* b2b = (const float*)d_in[10];
  const float* b2m = (const float*)d_in[11]; const float* b2v = (const float*)d_in[12];
  const float* c3w = (const float*)d_in[13]; const float* c3b = (const float*)d_in[14];
  const float* b3g = (const float*)d_in[15]; const float* b3b = (const float*)d_in[16];
  const float* b3m = (const float*)d_in[17]; const float* b3v = (const float*)d_in[18];
  const float* ln_g = (const float*)d_in[19]; const float* ln_b = (const float*)d_in[20];
  const float* w_in = (const float*)d_in[21];
  const float* cw = (const float*)d_in[22]; const float* cbv = (const float*)d_in[23];
  const float* w_x = (const float*)d_in[24];
  const float* w_dt = (const float*)d_in[25]; const float* b_dt = (const float*)d_in[26];
  const float* a_log = (const float*)d_in[27]; const float* d_skip = (const float*)d_in[28];
  const float* w_out = (const float*)d_in[29];
  const float* fc_w = (const float*)d_in[30]; const float* fc_b = (const float*)d_in[31];

  char* ws = (char*)d_ws;
  size_t off = 0;
  auto take = [&](size_t bytes) { size_t o = off; off += bytes; return o; };
  // scratch region S: stem buffers (phase 1) union mamba buffers (phase 2)
  size_t S = take(67837952);
  // stem phase 1
  unsigned short* c1o = (unsigned short*)(ws + S + 0);          // 51.38 MB
  unsigned short* t1 = (unsigned short*)(ws + S + 51380224);    // 12.85 MB
  // stem phase 2
  unsigned short* t2 = (unsigned short*)(ws + S + 0);           // 25.69 MB
  unsigned short* t3 = (unsigned short*)(ws + S + 25690112);    // 6.42 MB
  unsigned short* t4 = (unsigned short*)(ws + S + 32112640);    // 12.85 MB
  // mamba phase
  float* xz = (float*)(ws + S + 0);
  float* xcT = (float*)(ws + S + 25690112);     // [b][d][l] f32 12.85MB
  unsigned short* xcb = (unsigned short*)(ws + S + 38535168);
  float* dbl = (float*)(ws + S + 44957696);
  float* dtT = (float*)(ws + S + 48570368);     // [b][d][l] f32 12.85MB
  unsigned short* ybf = (unsigned short*)(ws + S + 61415424);
  float* h = (float*)(ws + take(6422528));
  unsigned short* hbf = (unsigned short*)(ws + take(3211264));
  unsigned short* w_in_bf = (unsigned short*)(ws + take(3145728));
  unsigned short* w_x_bf = (unsigned short*)(ws + take(884736));
  unsigned short* w_out_bf = (unsigned short*)(ws + take(1572864));
  unsigned short* w2p = (unsigned short*)(ws + take(147456));
  unsigned short* w3p = (unsigned short*)(ws + take(589824));
  float* wdt_t = (float*)(ws + take(196608));
  float* part = (float*)(ws + take(131072));
  (void)ws_size; (void)in_sizes; (void)n_in; (void)out_size;

  // fused weight conversion / repack / transpose
  k_prep<<<12576, 256, 0, stream>>>(w_in, w_in_bf, w_x, w_x_bf, w_out, w_out_bf,
                                    c2w, w2p, c3w, w3p, w_dt, wdt_t);

  // stem
  k_conv1a<<<3584, 256, 0, stream>>>(x, c1w, c1b, b1g, b1b, b1m, b1v, c1o);
  k_pool3<<<25088, 256, 0, stream>>>(c1o, t1);
  k_convgemm<56, 56, 64, 128><<<1568 * 2, 256, 0, stream>>>(t1, w2p, c2b, b2g, b2b, b2m, b2v, t2);
  k_pool<56, 56, 128, false><<<12544, 256, 0, stream>>>(t2, t3);
  k_convgemm<28, 28, 128, 256><<<392 * 4, 256, 0, stream>>>(t3, w3p, c3b, b3g, b3b, b3m, b3v, t4);
  k_pool<28, 28, 256, true><<<6272, 256, 0, stream>>>(t4, h);

  // mamba blocks
  for (int blk = 0; blk < 6; ++blk) {
    k_ln<<<1568, 256, 0, stream>>>(h, ln_g + blk * 256, ln_b + blk * 256, hbf);
    k_sgemm<128, 128, 4, false><<<49 * 8, 256, 0, stream>>>(
        hbf, w_in_bf + (size_t)blk * 1024 * 256, xz, 1024, 8);
    k_dwconvT<<<dim3(4, 8, 32), 256, 0, stream>>>(xz, cw + blk * 512 * 4, cbv + blk * 512,
                                                  xcT, xcb);
    k_gemm<false><<<98 * 3, 256, 0, stream>>>(xcb, w_x_bf + (size_t)blk * 144 * 512, dbl,
                                              6272, 144, 512, 3);
    k_dtT<<<dim3(4, 8, 32), 256, 0, stream>>>(dbl, wdt_t + blk * 8192, b_dt + blk * 512, dtT);
    k_scan<<<1024, 1024, 0, stream>>>(dtT, xcT, dbl, xz, a_log + blk * 512 * 64,
                                      d_skip + blk * 512, ybf);
    k_sgemm<64, 64, 8, true><<<98 * 4, 256, 0, stream>>>(
        ybf, w_out_bf + (size_t)blk * 256 * 512, h, 256, 4);
  }

  // head
  k_mean2<<<128, 256, 0, stream>>>(h, part);
  k_head<<<32, 256, 0, stream>>>(part, fc_w, fc_b, (float*)d_out);
}